// Round 5
// baseline (13092.943 us; speedup 1.0000x reference)
//
#include <hip/hip_runtime.h>
#include <math.h>

#define C_ 3
#define T_ 30
#define V_ 14
#define E_ 64
#define H_ 4
#define D_ 16
#define NC_ 7

#define EP_ 68   // padded row stride for [*,E] LDS tiles (16B-aligned rows)
#define SCV_ 15  // sc/adj row stride, spatial

__device__ __forceinline__ float4 f4_load(const float* p) {
    return *reinterpret_cast<const float4*>(p);
}
__device__ __forceinline__ float4 f4_zero() { return make_float4(0.f, 0.f, 0.f, 0.f); }
__device__ __forceinline__ float4 f4_add(float4 a, float4 b) {
    return make_float4(a.x + b.x, a.y + b.y, a.z + b.z, a.w + b.w);
}
__device__ __forceinline__ float4 f4_fma(float a, float4 b, float4 c) {
    c.x = fmaf(a, b.x, c.x); c.y = fmaf(a, b.y, c.y);
    c.z = fmaf(a, b.z, c.z); c.w = fmaf(a, b.w, c.w); return c;
}
__device__ __forceinline__ float f4_dot(float4 a, float4 b) {
    return a.x * b.x + a.y * b.y + a.z * b.z + a.w * b.w;
}
__device__ __forceinline__ float4 f4_relu(float4 a) {
    return make_float4(fmaxf(a.x, 0.f), fmaxf(a.y, 0.f), fmaxf(a.z, 0.f), fmaxf(a.w, 0.f));
}

// ---------------------------------------------------------------------------
// Setup: collapse the linear front-end into small tables in ws.
// ---------------------------------------------------------------------------
__global__ void k_setup(const float* __restrict__ je_w, const float* __restrict__ je_b,
                        const float* __restrict__ ve_w, const float* __restrict__ ve_b,
                        const float* __restrict__ joint_emb, const float* __restrict__ frame_emb,
                        const float* __restrict__ proj_w, const float* __restrict__ proj_b,
                        float* __restrict__ tab) {
    int e = threadIdx.x;  // 64 threads
    for (int c = 0; c < C_; ++c) {
        float aj = 0.f, av = 0.f;
        for (int i = 0; i < E_; ++i) {
            float p0 = proj_w[i * E_ + e];
            aj += je_w[c * E_ + i] * p0;
            av += ve_w[c * E_ + i] * p0;
        }
        tab[c * E_ + e] = aj;
        tab[192 + c * E_ + e] = av;
    }
    for (int v = 0; v < V_; ++v) {
        float s = 0.f;
        for (int i = 0; i < E_; ++i) s += joint_emb[v * E_ + i] * proj_w[(64 + i) * E_ + e];
        tab[384 + v * E_ + e] = s;
    }
    float bias = proj_b[e];
    for (int i = 0; i < E_; ++i) bias += (je_b[i] + ve_b[i]) * proj_w[i * E_ + e];
    for (int t = 0; t < T_; ++t) {
        float s = bias;
        for (int i = 0; i < E_; ++i) s += frame_emb[t * E_ + i] * proj_w[(128 + i) * E_ + e];
        tab[1280 + t * E_ + e] = s;
    }
}

// ---------------------------------------------------------------------------
// Kernel 1: ONE WAVE per (n,t) tile (unchanged from R3 — proven).
// ---------------------------------------------------------------------------
__global__ __launch_bounds__(64) void k_spatial(
    const float* __restrict__ xj, const float* __restrict__ xv,
    const float* __restrict__ tab,
    const float* __restrict__ w1, const float* __restrict__ b1,
    const float* __restrict__ w2, const float* __restrict__ b2,
    const float* __restrict__ wq, const float* __restrict__ bq,
    const float* __restrict__ wk, const float* __restrict__ bk,
    const float* __restrict__ wv, const float* __restrict__ bv,
    const float* __restrict__ wo, const float* __restrict__ bo,
    float* __restrict__ feat1) {
    int nt = blockIdx.x;
    int n = nt / T_;
    int t = nt % T_;
    int tid = threadIdx.x;      // 0..63
    int l16 = tid & 15;
    int e4 = l16 << 2;
    int r4 = tid >> 4;          // 0..3

    int qr[4], qc[4];
#pragma unroll
    for (int j = 0; j < 4; ++j) {
        qr[j] = r4 + 4 * j;
        qc[j] = (qr[j] < V_) ? qr[j] : 0;
    }

    __shared__ __align__(16) float feat[V_][EP_];
    __shared__ __align__(16) float bufA[V_][EP_];
    __shared__ __align__(16) float bufB[V_][EP_];
    __shared__ float sc[H_][V_][SCV_];
    __shared__ float adj[V_][SCV_];
    __shared__ float xs[2][C_][V_];
    __shared__ float inv_nrm[V_];

    for (int o = tid; o < 2 * C_ * V_; o += 64) {
        int s = o / (C_ * V_);
        int rem = o % (C_ * V_);
        int c = rem / V_, v = rem % V_;
        const float* src = s ? xv : xj;
        xs[s][c][v] = src[((size_t)(n * C_ + c) * T_ + t) * V_ + v];
    }
    __syncthreads();

    // feat build
    {
        float4 F = f4_load(tab + 1280 + t * E_ + e4);
        float4 AJ[C_], AV[C_];
#pragma unroll
        for (int c = 0; c < C_; ++c) {
            AJ[c] = f4_load(tab + c * E_ + e4);
            AV[c] = f4_load(tab + 192 + c * E_ + e4);
        }
#pragma unroll
        for (int j = 0; j < 4; ++j) {
            int q = qr[j];
            if (q < V_) {
                float4 s = f4_add(F, f4_load(tab + 384 + q * E_ + e4));
#pragma unroll
                for (int c = 0; c < C_; ++c) {
                    s = f4_fma(xs[0][c][q], AJ[c], s);
                    s = f4_fma(xs[1][c][q], AV[c], s);
                }
                *(float4*)&feat[q][e4] = s;
            }
        }
    }
    __syncthreads();

    if (tid < V_) {
        float ss = 0.f;
#pragma unroll
        for (int j = 0; j < 16; ++j) { float4 f = f4_load(&feat[tid][4 * j]); ss += f4_dot(f, f); }
        inv_nrm[tid] = 1.0f / fmaxf(sqrtf(ss), 1e-12f);
    }
    __syncthreads();

    for (int o = tid; o < V_ * V_; o += 64) {
        int q = o / V_, k = o % V_;
        float s = 0.f;
#pragma unroll
        for (int j = 0; j < 16; ++j) s += f4_dot(f4_load(&feat[q][4 * j]), f4_load(&feat[k][4 * j]));
        adj[q][k] = s * inv_nrm[q] * inv_nrm[k];
    }
    __syncthreads();
    if (tid < V_) {
        float m = -1e30f;
        for (int k = 0; k < V_; ++k) m = fmaxf(m, adj[tid][k]);
        float sum = 0.f;
        for (int k = 0; k < V_; ++k) { float ex = expf(adj[tid][k] - m); adj[tid][k] = ex; sum += ex; }
        float inv = 1.0f / sum;
        for (int k = 0; k < V_; ++k) adj[tid][k] *= inv;
    }
    __syncthreads();

    {
        float4 acc[4] = {f4_zero(), f4_zero(), f4_zero(), f4_zero()};
#pragma unroll
        for (int k = 0; k < V_; ++k) {
            float4 fv = f4_load(&feat[k][e4]);
#pragma unroll
            for (int j = 0; j < 4; ++j) acc[j] = f4_fma(adj[qc[j]][k], fv, acc[j]);
        }
#pragma unroll
        for (int j = 0; j < 4; ++j) if (qr[j] < V_) *(float4*)&bufA[qr[j]][e4] = acc[j];
    }
    __syncthreads();

    {
        float4 acc[4];
        float4 bb = f4_load(b1 + e4);
#pragma unroll
        for (int j = 0; j < 4; ++j) acc[j] = bb;
        for (int i = 0; i < E_; ++i) {
            float4 w4 = f4_load(w1 + i * E_ + e4);
#pragma unroll
            for (int j = 0; j < 4; ++j) acc[j] = f4_fma(bufA[qc[j]][i], w4, acc[j]);
        }
#pragma unroll
        for (int j = 0; j < 4; ++j) if (qr[j] < V_) *(float4*)&bufB[qr[j]][e4] = f4_relu(acc[j]);
    }
    __syncthreads();

    {
        float4 acc[4];
        float4 bb = f4_load(b2 + e4);
#pragma unroll
        for (int j = 0; j < 4; ++j) acc[j] = bb;
        for (int i = 0; i < E_; ++i) {
            float4 w4 = f4_load(w2 + i * E_ + e4);
#pragma unroll
            for (int j = 0; j < 4; ++j) acc[j] = f4_fma(bufB[qc[j]][i], w4, acc[j]);
        }
#pragma unroll
        for (int j = 0; j < 4; ++j) if (qr[j] < V_) *(float4*)&feat[qr[j]][e4] = acc[j];
    }
    __syncthreads();

    {
        float4 aq[4], ak[4];
        float4 bq4 = f4_load(bq + e4), bk4 = f4_load(bk + e4);
#pragma unroll
        for (int j = 0; j < 4; ++j) { aq[j] = bq4; ak[j] = bk4; }
        for (int i = 0; i < E_; ++i) {
            float4 wq4 = f4_load(wq + i * E_ + e4);
            float4 wk4 = f4_load(wk + i * E_ + e4);
#pragma unroll
            for (int j = 0; j < 4; ++j) {
                float f = feat[qc[j]][i];
                aq[j] = f4_fma(f, wq4, aq[j]);
                ak[j] = f4_fma(f, wk4, ak[j]);
            }
        }
#pragma unroll
        for (int j = 0; j < 4; ++j)
            if (qr[j] < V_) { *(float4*)&bufA[qr[j]][e4] = aq[j]; *(float4*)&bufB[qr[j]][e4] = ak[j]; }
    }
    __syncthreads();

    for (int o = tid; o < H_ * V_ * V_; o += 64) {
        int h = o / (V_ * V_); int r = o % (V_ * V_); int q = r / V_, k = r % V_;
        float s = 0.f;
#pragma unroll
        for (int j = 0; j < 4; ++j)
            s += f4_dot(f4_load(&bufA[q][h * 16 + 4 * j]), f4_load(&bufB[k][h * 16 + 4 * j]));
        sc[h][q][k] = s * 0.25f;  // 1/sqrt(16)
    }
    __syncthreads();
    if (tid < H_ * V_) {
        int h = tid / V_, q = tid % V_;
        float m = -1e30f;
        for (int k = 0; k < V_; ++k) m = fmaxf(m, sc[h][q][k]);
        float sum = 0.f;
        for (int k = 0; k < V_; ++k) { float ex = expf(sc[h][q][k] - m); sc[h][q][k] = ex; sum += ex; }
        float inv = 1.0f / sum;
        for (int k = 0; k < V_; ++k) sc[h][q][k] *= inv;
    }
    __syncthreads();

    {
        float4 av[4];
        float4 bv4 = f4_load(bv + e4);
#pragma unroll
        for (int j = 0; j < 4; ++j) av[j] = bv4;
        for (int i = 0; i < E_; ++i) {
            float4 wv4 = f4_load(wv + i * E_ + e4);
#pragma unroll
            for (int j = 0; j < 4; ++j) av[j] = f4_fma(feat[qc[j]][i], wv4, av[j]);
        }
#pragma unroll
        for (int j = 0; j < 4; ++j) if (qr[j] < V_) *(float4*)&bufA[qr[j]][e4] = av[j];
    }
    __syncthreads();

    {
        int h = l16 >> 2;
        float4 acc[4] = {f4_zero(), f4_zero(), f4_zero(), f4_zero()};
#pragma unroll
        for (int k = 0; k < V_; ++k) {
            float4 v4 = f4_load(&bufA[k][e4]);
#pragma unroll
            for (int j = 0; j < 4; ++j) acc[j] = f4_fma(sc[h][qc[j]][k], v4, acc[j]);
        }
#pragma unroll
        for (int j = 0; j < 4; ++j) if (qr[j] < V_) *(float4*)&bufB[qr[j]][e4] = acc[j];
    }
    __syncthreads();

    {
        float4 acc[4];
        float4 bo4 = f4_load(bo + e4);
#pragma unroll
        for (int j = 0; j < 4; ++j) acc[j] = bo4;
        for (int i = 0; i < E_; ++i) {
            float4 w4 = f4_load(wo + i * E_ + e4);
#pragma unroll
            for (int j = 0; j < 4; ++j) acc[j] = f4_fma(bufB[qc[j]][i], w4, acc[j]);
        }
#pragma unroll
        for (int j = 0; j < 4; ++j)
            if (qr[j] < V_) {
                float4 r = f4_add(acc[j], f4_load(&feat[qr[j]][e4]));
                *(float4*)(feat1 + (size_t)nt * (V_ * E_) + qr[j] * E_ + e4) = r;
            }
    }
}

// ---------------------------------------------------------------------------
// Kernel 2: ONE WAVE per (n,v) tile. LDS = ft + one overlay buffer (K->V->attn).
// Scores/softmax/PV in registers: lane<60 owns (row = tid%30, headpair = tid/30).
// ---------------------------------------------------------------------------
__global__ __launch_bounds__(64) void k_temporal(
    const float* __restrict__ feat1,
    const float* __restrict__ wq, const float* __restrict__ bq,
    const float* __restrict__ wk, const float* __restrict__ bk,
    const float* __restrict__ wv, const float* __restrict__ bv,
    const float* __restrict__ wo, const float* __restrict__ bo,
    float* __restrict__ tmax) {
    int nv = blockIdx.x;
    int n = nv / V_;
    int v = nv % V_;
    int tid = threadIdx.x;      // 0..63
    int l16 = tid & 15;
    int e4 = l16 << 2;
    int r4 = tid >> 4;          // 0..3

    __shared__ __align__(16) float ft[T_][EP_];   // residual + projection input
    __shared__ __align__(16) float kv[T_][EP_];   // K, then V, then attn-out

    // cooperative row ownership: rows r4+4j, j=0..7 (30 rows -> 7-8 each)
    int tr[8], tc[8];
#pragma unroll
    for (int j = 0; j < 8; ++j) { tr[j] = r4 + 4 * j; tc[j] = (tr[j] < T_) ? tr[j] : 0; }

    // 1) load ft
#pragma unroll
    for (int j = 0; j < 8; ++j)
        if (tr[j] < T_)
            *(float4*)&ft[tr[j]][e4] =
                f4_load(feat1 + (((size_t)n * T_ + tr[j]) * V_ + v) * E_ + e4);
    __syncthreads();

    // 2) K projection -> kv   (i0-blocked: ds_read_b128 of ft + 4 weight f4s)
    {
        float4 acc[8];
        float4 b4 = f4_load(bk + e4);
#pragma unroll
        for (int j = 0; j < 8; ++j) acc[j] = b4;
#pragma unroll
        for (int i0 = 0; i0 < 16; ++i0) {
            float4 w0 = f4_load(wk + (4 * i0 + 0) * E_ + e4);
            float4 w1 = f4_load(wk + (4 * i0 + 1) * E_ + e4);
            float4 w2 = f4_load(wk + (4 * i0 + 2) * E_ + e4);
            float4 w3 = f4_load(wk + (4 * i0 + 3) * E_ + e4);
#pragma unroll
            for (int j = 0; j < 8; ++j) {
                float4 f = f4_load(&ft[tc[j]][4 * i0]);
                acc[j] = f4_fma(f.x, w0, acc[j]);
                acc[j] = f4_fma(f.y, w1, acc[j]);
                acc[j] = f4_fma(f.z, w2, acc[j]);
                acc[j] = f4_fma(f.w, w3, acc[j]);
            }
        }
#pragma unroll
        for (int j = 0; j < 8; ++j)
            if (tr[j] < T_) *(float4*)&kv[tr[j]][e4] = acc[j];
    }
    __syncthreads();

    // 3) q in registers + scores + in-lane softmax.
    // lane<60: row = tid%30, headpair hp = tid/30 -> dims [hp*32, hp*32+32)
    bool act = (tid < 60);
    int rowq = act ? (tid % 30) : 0;
    int hd   = act ? ((tid / 30) * 32) : 0;
    float p0[T_], p1[T_];
    {
        float4 q8[8];
#pragma unroll
        for (int c = 0; c < 8; ++c) q8[c] = f4_load(bq + hd + 4 * c);
#pragma unroll
        for (int i0 = 0; i0 < 16; ++i0) {
            float4 f = f4_load(&ft[rowq][4 * i0]);
#pragma unroll
            for (int c = 0; c < 8; ++c) {
                q8[c] = f4_fma(f.x, f4_load(wq + (4 * i0 + 0) * E_ + hd + 4 * c), q8[c]);
                q8[c] = f4_fma(f.y, f4_load(wq + (4 * i0 + 1) * E_ + hd + 4 * c), q8[c]);
                q8[c] = f4_fma(f.z, f4_load(wq + (4 * i0 + 2) * E_ + hd + 4 * c), q8[c]);
                q8[c] = f4_fma(f.w, f4_load(wq + (4 * i0 + 3) * E_ + hd + 4 * c), q8[c]);
            }
        }
#pragma unroll
        for (int k = 0; k < T_; ++k) {
            float s0 = 0.f, s1 = 0.f;
#pragma unroll
            for (int c = 0; c < 4; ++c) {
                s0 += f4_dot(q8[c],     f4_load(&kv[k][hd + 4 * c]));
                s1 += f4_dot(q8[c + 4], f4_load(&kv[k][hd + 16 + 4 * c]));
            }
            p0[k] = s0 * 0.25f;   // 1/sqrt(16)
            p1[k] = s1 * 0.25f;
        }
        float m0 = -1e30f, m1 = -1e30f;
#pragma unroll
        for (int k = 0; k < T_; ++k) { m0 = fmaxf(m0, p0[k]); m1 = fmaxf(m1, p1[k]); }
        float su0 = 0.f, su1 = 0.f;
#pragma unroll
        for (int k = 0; k < T_; ++k) {
            p0[k] = __expf(p0[k] - m0); su0 += p0[k];
            p1[k] = __expf(p1[k] - m1); su1 += p1[k];
        }
        float iv0 = 1.f / su0, iv1 = 1.f / su1;
#pragma unroll
        for (int k = 0; k < T_; ++k) { p0[k] *= iv0; p1[k] *= iv1; }
    }
    __syncthreads();   // all K reads done

    // 4) V projection -> kv (overwrite K)
    {
        float4 acc[8];
        float4 b4 = f4_load(bv + e4);
#pragma unroll
        for (int j = 0; j < 8; ++j) acc[j] = b4;
#pragma unroll
        for (int i0 = 0; i0 < 16; ++i0) {
            float4 w0 = f4_load(wv + (4 * i0 + 0) * E_ + e4);
            float4 w1 = f4_load(wv + (4 * i0 + 1) * E_ + e4);
            float4 w2 = f4_load(wv + (4 * i0 + 2) * E_ + e4);
            float4 w3 = f4_load(wv + (4 * i0 + 3) * E_ + e4);
#pragma unroll
            for (int j = 0; j < 8; ++j) {
                float4 f = f4_load(&ft[tc[j]][4 * i0]);
                acc[j] = f4_fma(f.x, w0, acc[j]);
                acc[j] = f4_fma(f.y, w1, acc[j]);
                acc[j] = f4_fma(f.z, w2, acc[j]);
                acc[j] = f4_fma(f.w, w3, acc[j]);
            }
        }
#pragma unroll
        for (int j = 0; j < 8; ++j)
            if (tr[j] < T_) *(float4*)&kv[tr[j]][e4] = acc[j];
    }
    __syncthreads();

    // 5) PV in registers: out[row][hd..hd+31]
    {
        float4 o8[8];
#pragma unroll
        for (int c = 0; c < 8; ++c) o8[c] = f4_zero();
#pragma unroll
        for (int k = 0; k < T_; ++k) {
#pragma unroll
            for (int c = 0; c < 4; ++c) {
                o8[c]     = f4_fma(p0[k], f4_load(&kv[k][hd + 4 * c]), o8[c]);
                o8[c + 4] = f4_fma(p1[k], f4_load(&kv[k][hd + 16 + 4 * c]), o8[c + 4]);
            }
        }
        __syncthreads();   // all V reads done
        if (act) {
#pragma unroll
            for (int c = 0; c < 8; ++c) *(float4*)&kv[rowq][hd + 4 * c] = o8[c];
        }
    }
    __syncthreads();

    // 6) O projection + residual + T-max (registers + cross-lane reduce)
    {
        float4 acc[8];
        float4 b4 = f4_load(bo + e4);
#pragma unroll
        for (int j = 0; j < 8; ++j) acc[j] = b4;
#pragma unroll
        for (int i0 = 0; i0 < 16; ++i0) {
            float4 w0 = f4_load(wo + (4 * i0 + 0) * E_ + e4);
            float4 w1 = f4_load(wo + (4 * i0 + 1) * E_ + e4);
            float4 w2 = f4_load(wo + (4 * i0 + 2) * E_ + e4);
            float4 w3 = f4_load(wo + (4 * i0 + 3) * E_ + e4);
#pragma unroll
            for (int j = 0; j < 8; ++j) {
                float4 f = f4_load(&kv[tc[j]][4 * i0]);
                acc[j] = f4_fma(f.x, w0, acc[j]);
                acc[j] = f4_fma(f.y, w1, acc[j]);
                acc[j] = f4_fma(f.z, w2, acc[j]);
                acc[j] = f4_fma(f.w, w3, acc[j]);
            }
        }
        float4 mx = make_float4(-1e30f, -1e30f, -1e30f, -1e30f);
#pragma unroll
        for (int j = 0; j < 8; ++j) {
            if (tr[j] < T_) {
                float4 r = f4_add(acc[j], f4_load(&ft[tr[j]][e4]));
                mx.x = fmaxf(mx.x, r.x); mx.y = fmaxf(mx.y, r.y);
                mx.z = fmaxf(mx.z, r.z); mx.w = fmaxf(mx.w, r.w);
            }
        }
        // reduce across the 4 row-groups (lanes xor 16, 32)
        mx.x = fmaxf(mx.x, __shfl_xor(mx.x, 16));
        mx.y = fmaxf(mx.y, __shfl_xor(mx.y, 16));
        mx.z = fmaxf(mx.z, __shfl_xor(mx.z, 16));
        mx.w = fmaxf(mx.w, __shfl_xor(mx.w, 16));
        mx.x = fmaxf(mx.x, __shfl_xor(mx.x, 32));
        mx.y = fmaxf(mx.y, __shfl_xor(mx.y, 32));
        mx.z = fmaxf(mx.z, __shfl_xor(mx.z, 32));
        mx.w = fmaxf(mx.w, __shfl_xor(mx.w, 32));
        if (r4 == 0) *(float4*)(tmax + (size_t)nv * E_ + e4) = mx;
    }
}

// ---------------------------------------------------------------------------
// Kernel 3: per n — max over V, then FC to 7 classes.
// ---------------------------------------------------------------------------
__global__ void k_pool_fc(const float* __restrict__ tmax,
                          const float* __restrict__ fc_w, const float* __restrict__ fc_b,
                          float* __restrict__ out) {
    int n = blockIdx.x;
    int tid = threadIdx.x;  // 64
    __shared__ float pooled[E_];
    float m = -1e30f;
    for (int v = 0; v < V_; ++v) m = fmaxf(m, tmax[((size_t)n * V_ + v) * E_ + tid]);
    pooled[tid] = m;
    __syncthreads();
    if (tid < NC_) {
        float s = fc_b[tid];
        for (int e = 0; e < E_; ++e) s += pooled[e] * fc_w[e * NC_ + tid];
        out[n * NC_ + tid] = s;
    }
}

extern "C" void kernel_launch(void* const* d_in, const int* in_sizes, int n_in,
                              void* d_out, int out_size, void* d_ws, size_t ws_size,
                              hipStream_t stream) {
    const float* xj        = (const float*)d_in[0];
    const float* xv        = (const float*)d_in[1];
    const float* je_w      = (const float*)d_in[2];
    const float* je_b      = (const float*)d_in[3];
    const float* ve_w      = (const float*)d_in[4];
    const float* ve_b      = (const float*)d_in[5];
    const float* joint_emb = (const float*)d_in[6];
    const float* frame_emb = (const float*)d_in[7];
    const float* proj_w    = (const float*)d_in[8];
    const float* proj_b    = (const float*)d_in[9];
    const float* gcn_w1    = (const float*)d_in[10];
    const float* gcn_b1    = (const float*)d_in[11];
    const float* gcn_w2    = (const float*)d_in[12];
    const float* gcn_b2    = (const float*)d_in[13];
    const float* sa_wq     = (const float*)d_in[14];
    const float* sa_bq     = (const float*)d_in[15];
    const float* sa_wk     = (const float*)d_in[16];
    const float* sa_bk     = (const float*)d_in[17];
    const float* sa_wv     = (const float*)d_in[18];
    const float* sa_bv     = (const float*)d_in[19];
    const float* sa_wo     = (const float*)d_in[20];
    const float* sa_bo     = (const float*)d_in[21];
    const float* ta_wq     = (const float*)d_in[22];
    const float* ta_bq     = (const float*)d_in[23];
    const float* ta_wk     = (const float*)d_in[24];
    const float* ta_bk     = (const float*)d_in[25];
    const float* ta_wv     = (const float*)d_in[26];
    const float* ta_bv     = (const float*)d_in[27];
    const float* ta_wo     = (const float*)d_in[28];
    const float* ta_bo     = (const float*)d_in[29];
    const float* fc_w      = (const float*)d_in[30];
    const float* fc_b      = (const float*)d_in[31];
    float* out = (float*)d_out;

    int N = in_sizes[0] / (C_ * T_ * V_);

    // ws layout (floats): tab[3200] | tmax[N*V*E] | feat1[N*T*V*E]
    float* ws    = (float*)d_ws;
    float* tab   = ws;
    float* tmax  = ws + 3200;
    float* feat1 = tmax + (size_t)N * V_ * E_;

    k_setup<<<1, 64, 0, stream>>>(je_w, je_b, ve_w, ve_b, joint_emb, frame_emb,
                                  proj_w, proj_b, tab);
    k_spatial<<<N * T_, 64, 0, stream>>>(xj, xv, tab,
                                         gcn_w1, gcn_b1, gcn_w2, gcn_b2,
                                         sa_wq, sa_bq, sa_wk, sa_bk,
                                         sa_wv, sa_bv, sa_wo, sa_bo, feat1);
    k_temporal<<<N * V_, 64, 0, stream>>>(feat1,
                                          ta_wq, ta_bq, ta_wk, ta_bk,
                                          ta_wv, ta_bv, ta_wo, ta_bo, tmax);
    k_pool_fc<<<N, 64, 0, stream>>>(tmax, fc_w, fc_b, out);
}

// Round 6
// 9324.456 us; speedup vs baseline: 1.4042x; 1.4042x over previous
//
#include <hip/hip_runtime.h>
#include <math.h>

#define C_ 3
#define T_ 30
#define V_ 14
#define E_ 64
#define H_ 4
#define D_ 16
#define NC_ 7

#define EP_ 68   // padded row stride for [*,E] LDS tiles (16B-aligned rows)
#define SCV_ 15  // sc/adj row stride, spatial

__device__ __forceinline__ float4 f4_load(const float* p) {
    return *reinterpret_cast<const float4*>(p);
}
__device__ __forceinline__ float4 f4_zero() { return make_float4(0.f, 0.f, 0.f, 0.f); }
__device__ __forceinline__ float4 f4_add(float4 a, float4 b) {
    return make_float4(a.x + b.x, a.y + b.y, a.z + b.z, a.w + b.w);
}
__device__ __forceinline__ float4 f4_fma(float a, float4 b, float4 c) {
    c.x = fmaf(a, b.x, c.x); c.y = fmaf(a, b.y, c.y);
    c.z = fmaf(a, b.z, c.z); c.w = fmaf(a, b.w, c.w); return c;
}
__device__ __forceinline__ float f4_dot(float4 a, float4 b) {
    return a.x * b.x + a.y * b.y + a.z * b.z + a.w * b.w;
}
__device__ __forceinline__ float4 f4_relu(float4 a) {
    return make_float4(fmaxf(a.x, 0.f), fmaxf(a.y, 0.f), fmaxf(a.z, 0.f), fmaxf(a.w, 0.f));
}

// ---------------------------------------------------------------------------
// Setup: collapse the linear front-end into small tables in ws.
// ---------------------------------------------------------------------------
__global__ void k_setup(const float* __restrict__ je_w, const float* __restrict__ je_b,
                        const float* __restrict__ ve_w, const float* __restrict__ ve_b,
                        const float* __restrict__ joint_emb, const float* __restrict__ frame_emb,
                        const float* __restrict__ proj_w, const float* __restrict__ proj_b,
                        float* __restrict__ tab) {
    int e = threadIdx.x;  // 64 threads
    for (int c = 0; c < C_; ++c) {
        float aj = 0.f, av = 0.f;
        for (int i = 0; i < E_; ++i) {
            float p0 = proj_w[i * E_ + e];
            aj += je_w[c * E_ + i] * p0;
            av += ve_w[c * E_ + i] * p0;
        }
        tab[c * E_ + e] = aj;
        tab[192 + c * E_ + e] = av;
    }
    for (int v = 0; v < V_; ++v) {
        float s = 0.f;
        for (int i = 0; i < E_; ++i) s += joint_emb[v * E_ + i] * proj_w[(64 + i) * E_ + e];
        tab[384 + v * E_ + e] = s;
    }
    float bias = proj_b[e];
    for (int i = 0; i < E_; ++i) bias += (je_b[i] + ve_b[i]) * proj_w[i * E_ + e];
    for (int t = 0; t < T_; ++t) {
        float s = bias;
        for (int i = 0; i < E_; ++i) s += frame_emb[t * E_ + i] * proj_w[(128 + i) * E_ + e];
        tab[1280 + t * E_ + e] = s;
    }
}

// ---------------------------------------------------------------------------
// Kernel 1: ONE WAVE per (n,t) tile (unchanged from R3 — proven ~430 us).
// ---------------------------------------------------------------------------
__global__ __launch_bounds__(64) void k_spatial(
    const float* __restrict__ xj, const float* __restrict__ xv,
    const float* __restrict__ tab,
    const float* __restrict__ w1, const float* __restrict__ b1,
    const float* __restrict__ w2, const float* __restrict__ b2,
    const float* __restrict__ wq, const float* __restrict__ bq,
    const float* __restrict__ wk, const float* __restrict__ bk,
    const float* __restrict__ wv, const float* __restrict__ bv,
    const float* __restrict__ wo, const float* __restrict__ bo,
    float* __restrict__ feat1) {
    int nt = blockIdx.x;
    int n = nt / T_;
    int t = nt % T_;
    int tid = threadIdx.x;      // 0..63
    int l16 = tid & 15;
    int e4 = l16 << 2;
    int r4 = tid >> 4;          // 0..3

    int qr[4], qc[4];
#pragma unroll
    for (int j = 0; j < 4; ++j) {
        qr[j] = r4 + 4 * j;
        qc[j] = (qr[j] < V_) ? qr[j] : 0;
    }

    __shared__ __align__(16) float feat[V_][EP_];
    __shared__ __align__(16) float bufA[V_][EP_];
    __shared__ __align__(16) float bufB[V_][EP_];
    __shared__ float sc[H_][V_][SCV_];
    __shared__ float adj[V_][SCV_];
    __shared__ float xs[2][C_][V_];
    __shared__ float inv_nrm[V_];

    for (int o = tid; o < 2 * C_ * V_; o += 64) {
        int s = o / (C_ * V_);
        int rem = o % (C_ * V_);
        int c = rem / V_, v = rem % V_;
        const float* src = s ? xv : xj;
        xs[s][c][v] = src[((size_t)(n * C_ + c) * T_ + t) * V_ + v];
    }
    __syncthreads();

    // feat build
    {
        float4 F = f4_load(tab + 1280 + t * E_ + e4);
        float4 AJ[C_], AV[C_];
#pragma unroll
        for (int c = 0; c < C_; ++c) {
            AJ[c] = f4_load(tab + c * E_ + e4);
            AV[c] = f4_load(tab + 192 + c * E_ + e4);
        }
#pragma unroll
        for (int j = 0; j < 4; ++j) {
            int q = qr[j];
            if (q < V_) {
                float4 s = f4_add(F, f4_load(tab + 384 + q * E_ + e4));
#pragma unroll
                for (int c = 0; c < C_; ++c) {
                    s = f4_fma(xs[0][c][q], AJ[c], s);
                    s = f4_fma(xs[1][c][q], AV[c], s);
                }
                *(float4*)&feat[q][e4] = s;
            }
        }
    }
    __syncthreads();

    if (tid < V_) {
        float ss = 0.f;
#pragma unroll
        for (int j = 0; j < 16; ++j) { float4 f = f4_load(&feat[tid][4 * j]); ss += f4_dot(f, f); }
        inv_nrm[tid] = 1.0f / fmaxf(sqrtf(ss), 1e-12f);
    }
    __syncthreads();

    for (int o = tid; o < V_ * V_; o += 64) {
        int q = o / V_, k = o % V_;
        float s = 0.f;
#pragma unroll
        for (int j = 0; j < 16; ++j) s += f4_dot(f4_load(&feat[q][4 * j]), f4_load(&feat[k][4 * j]));
        adj[q][k] = s * inv_nrm[q] * inv_nrm[k];
    }
    __syncthreads();
    if (tid < V_) {
        float m = -1e30f;
        for (int k = 0; k < V_; ++k) m = fmaxf(m, adj[tid][k]);
        float sum = 0.f;
        for (int k = 0; k < V_; ++k) { float ex = expf(adj[tid][k] - m); adj[tid][k] = ex; sum += ex; }
        float inv = 1.0f / sum;
        for (int k = 0; k < V_; ++k) adj[tid][k] *= inv;
    }
    __syncthreads();

    {
        float4 acc[4] = {f4_zero(), f4_zero(), f4_zero(), f4_zero()};
#pragma unroll
        for (int k = 0; k < V_; ++k) {
            float4 fv = f4_load(&feat[k][e4]);
#pragma unroll
            for (int j = 0; j < 4; ++j) acc[j] = f4_fma(adj[qc[j]][k], fv, acc[j]);
        }
#pragma unroll
        for (int j = 0; j < 4; ++j) if (qr[j] < V_) *(float4*)&bufA[qr[j]][e4] = acc[j];
    }
    __syncthreads();

    {
        float4 acc[4];
        float4 bb = f4_load(b1 + e4);
#pragma unroll
        for (int j = 0; j < 4; ++j) acc[j] = bb;
        for (int i = 0; i < E_; ++i) {
            float4 w4 = f4_load(w1 + i * E_ + e4);
#pragma unroll
            for (int j = 0; j < 4; ++j) acc[j] = f4_fma(bufA[qc[j]][i], w4, acc[j]);
        }
#pragma unroll
        for (int j = 0; j < 4; ++j) if (qr[j] < V_) *(float4*)&bufB[qr[j]][e4] = f4_relu(acc[j]);
    }
    __syncthreads();

    {
        float4 acc[4];
        float4 bb = f4_load(b2 + e4);
#pragma unroll
        for (int j = 0; j < 4; ++j) acc[j] = bb;
        for (int i = 0; i < E_; ++i) {
            float4 w4 = f4_load(w2 + i * E_ + e4);
#pragma unroll
            for (int j = 0; j < 4; ++j) acc[j] = f4_fma(bufB[qc[j]][i], w4, acc[j]);
        }
#pragma unroll
        for (int j = 0; j < 4; ++j) if (qr[j] < V_) *(float4*)&feat[qr[j]][e4] = acc[j];
    }
    __syncthreads();

    {
        float4 aq[4], ak[4];
        float4 bq4 = f4_load(bq + e4), bk4 = f4_load(bk + e4);
#pragma unroll
        for (int j = 0; j < 4; ++j) { aq[j] = bq4; ak[j] = bk4; }
        for (int i = 0; i < E_; ++i) {
            float4 wq4 = f4_load(wq + i * E_ + e4);
            float4 wk4 = f4_load(wk + i * E_ + e4);
#pragma unroll
            for (int j = 0; j < 4; ++j) {
                float f = feat[qc[j]][i];
                aq[j] = f4_fma(f, wq4, aq[j]);
                ak[j] = f4_fma(f, wk4, ak[j]);
            }
        }
#pragma unroll
        for (int j = 0; j < 4; ++j)
            if (qr[j] < V_) { *(float4*)&bufA[qr[j]][e4] = aq[j]; *(float4*)&bufB[qr[j]][e4] = ak[j]; }
    }
    __syncthreads();

    for (int o = tid; o < H_ * V_ * V_; o += 64) {
        int h = o / (V_ * V_); int r = o % (V_ * V_); int q = r / V_, k = r % V_;
        float s = 0.f;
#pragma unroll
        for (int j = 0; j < 4; ++j)
            s += f4_dot(f4_load(&bufA[q][h * 16 + 4 * j]), f4_load(&bufB[k][h * 16 + 4 * j]));
        sc[h][q][k] = s * 0.25f;  // 1/sqrt(16)
    }
    __syncthreads();
    if (tid < H_ * V_) {
        int h = tid / V_, q = tid % V_;
        float m = -1e30f;
        for (int k = 0; k < V_; ++k) m = fmaxf(m, sc[h][q][k]);
        float sum = 0.f;
        for (int k = 0; k < V_; ++k) { float ex = expf(sc[h][q][k] - m); sc[h][q][k] = ex; sum += ex; }
        float inv = 1.0f / sum;
        for (int k = 0; k < V_; ++k) sc[h][q][k] *= inv;
    }
    __syncthreads();

    {
        float4 av[4];
        float4 bv4 = f4_load(bv + e4);
#pragma unroll
        for (int j = 0; j < 4; ++j) av[j] = bv4;
        for (int i = 0; i < E_; ++i) {
            float4 wv4 = f4_load(wv + i * E_ + e4);
#pragma unroll
            for (int j = 0; j < 4; ++j) av[j] = f4_fma(feat[qc[j]][i], wv4, av[j]);
        }
#pragma unroll
        for (int j = 0; j < 4; ++j) if (qr[j] < V_) *(float4*)&bufA[qr[j]][e4] = av[j];
    }
    __syncthreads();

    {
        int h = l16 >> 2;
        float4 acc[4] = {f4_zero(), f4_zero(), f4_zero(), f4_zero()};
#pragma unroll
        for (int k = 0; k < V_; ++k) {
            float4 v4 = f4_load(&bufA[k][e4]);
#pragma unroll
            for (int j = 0; j < 4; ++j) acc[j] = f4_fma(sc[h][qc[j]][k], v4, acc[j]);
        }
#pragma unroll
        for (int j = 0; j < 4; ++j) if (qr[j] < V_) *(float4*)&bufB[qr[j]][e4] = acc[j];
    }
    __syncthreads();

    {
        float4 acc[4];
        float4 bo4 = f4_load(bo + e4);
#pragma unroll
        for (int j = 0; j < 4; ++j) acc[j] = bo4;
        for (int i = 0; i < E_; ++i) {
            float4 w4 = f4_load(wo + i * E_ + e4);
#pragma unroll
            for (int j = 0; j < 4; ++j) acc[j] = f4_fma(bufB[qc[j]][i], w4, acc[j]);
        }
#pragma unroll
        for (int j = 0; j < 4; ++j)
            if (qr[j] < V_) {
                float4 r = f4_add(acc[j], f4_load(&feat[qr[j]][e4]));
                *(float4*)(feat1 + (size_t)nt * (V_ * E_) + qr[j] * E_ + e4) = r;
            }
    }
}

// ---------------------------------------------------------------------------
// Kernel 2: ONE WAVE per (n,v) tile. LDS: ft + K + V (24.5 KB -> 6 blocks/CU).
// Attention per lane in TWO head-rounds to keep VGPR low:
//   lane<60: row = tid%30, h2 = tid/30; round A head=h2, round B head=2+h2.
// Per round: q(4xf4) + p[30] + o(4xf4)  -> no spill.
// ---------------------------------------------------------------------------
__global__ __launch_bounds__(64) void k_temporal(
    const float* __restrict__ feat1,
    const float* __restrict__ wq, const float* __restrict__ bq,
    const float* __restrict__ wk, const float* __restrict__ bk,
    const float* __restrict__ wv, const float* __restrict__ bv,
    const float* __restrict__ wo, const float* __restrict__ bo,
    float* __restrict__ tmax) {
    int nv = blockIdx.x;
    int n = nv / V_;
    int v = nv % V_;
    int tid = threadIdx.x;      // 0..63
    int l16 = tid & 15;
    int e4 = l16 << 2;
    int r4 = tid >> 4;          // 0..3

    __shared__ __align__(16) float ft[T_][EP_];   // residual + projection input
    __shared__ __align__(16) float kb[T_][EP_];   // K, later attn-out
    __shared__ __align__(16) float vb[T_][EP_];   // V

    int tr[8], tc[8];
#pragma unroll
    for (int j = 0; j < 8; ++j) { tr[j] = r4 + 4 * j; tc[j] = (tr[j] < T_) ? tr[j] : 0; }

    // 1) load ft
#pragma unroll
    for (int j = 0; j < 8; ++j)
        if (tr[j] < T_)
            *(float4*)&ft[tr[j]][e4] =
                f4_load(feat1 + (((size_t)n * T_ + tr[j]) * V_ + v) * E_ + e4);
    __syncthreads();

    // 2) K projection -> kb (cooperative, i0-blocked)
    {
        float4 acc[8];
        float4 b4 = f4_load(bk + e4);
#pragma unroll
        for (int j = 0; j < 8; ++j) acc[j] = b4;
        for (int i0 = 0; i0 < 16; ++i0) {
            float4 w0 = f4_load(wk + (4 * i0 + 0) * E_ + e4);
            float4 w1 = f4_load(wk + (4 * i0 + 1) * E_ + e4);
            float4 w2 = f4_load(wk + (4 * i0 + 2) * E_ + e4);
            float4 w3 = f4_load(wk + (4 * i0 + 3) * E_ + e4);
#pragma unroll
            for (int j = 0; j < 8; ++j) {
                float4 f = f4_load(&ft[tc[j]][4 * i0]);
                acc[j] = f4_fma(f.x, w0, acc[j]);
                acc[j] = f4_fma(f.y, w1, acc[j]);
                acc[j] = f4_fma(f.z, w2, acc[j]);
                acc[j] = f4_fma(f.w, w3, acc[j]);
            }
        }
#pragma unroll
        for (int j = 0; j < 8; ++j)
            if (tr[j] < T_) *(float4*)&kb[tr[j]][e4] = acc[j];
    }

    // 3) V projection -> vb (cooperative)
    {
        float4 acc[8];
        float4 b4 = f4_load(bv + e4);
#pragma unroll
        for (int j = 0; j < 8; ++j) acc[j] = b4;
        for (int i0 = 0; i0 < 16; ++i0) {
            float4 w0 = f4_load(wv + (4 * i0 + 0) * E_ + e4);
            float4 w1 = f4_load(wv + (4 * i0 + 1) * E_ + e4);
            float4 w2 = f4_load(wv + (4 * i0 + 2) * E_ + e4);
            float4 w3 = f4_load(wv + (4 * i0 + 3) * E_ + e4);
#pragma unroll
            for (int j = 0; j < 8; ++j) {
                float4 f = f4_load(&ft[tc[j]][4 * i0]);
                acc[j] = f4_fma(f.x, w0, acc[j]);
                acc[j] = f4_fma(f.y, w1, acc[j]);
                acc[j] = f4_fma(f.z, w2, acc[j]);
                acc[j] = f4_fma(f.w, w3, acc[j]);
            }
        }
#pragma unroll
        for (int j = 0; j < 8; ++j)
            if (tr[j] < T_) *(float4*)&vb[tr[j]][e4] = acc[j];
    }
    __syncthreads();

    // 4) per-lane attention in two head-rounds
    bool act = (tid < 60);
    int rowq = act ? (tid % 30) : 0;
    int h2   = act ? (tid / 30) : 0;    // 0 or 1
    float4 oA[4], oB[4];

#pragma unroll
    for (int rnd = 0; rnd < 2; ++rnd) {
        int hd = (rnd * 2 + h2) * D_;   // head dim offset: 0/16 or 32/48
        // q projection for this head (16 dims, in regs)
        float4 q4[4];
#pragma unroll
        for (int c = 0; c < 4; ++c) q4[c] = f4_load(bq + hd + 4 * c);
        for (int i0 = 0; i0 < 16; ++i0) {
            float4 f = f4_load(&ft[rowq][4 * i0]);
#pragma unroll
            for (int c = 0; c < 4; ++c) {
                q4[c] = f4_fma(f.x, f4_load(wq + (4 * i0 + 0) * E_ + hd + 4 * c), q4[c]);
                q4[c] = f4_fma(f.y, f4_load(wq + (4 * i0 + 1) * E_ + hd + 4 * c), q4[c]);
                q4[c] = f4_fma(f.z, f4_load(wq + (4 * i0 + 2) * E_ + hd + 4 * c), q4[c]);
                q4[c] = f4_fma(f.w, f4_load(wq + (4 * i0 + 3) * E_ + hd + 4 * c), q4[c]);
            }
        }
        // scores + softmax (in-lane; kb reads broadcast across lanes)
        float p[T_];
#pragma unroll
        for (int k = 0; k < T_; ++k) {
            float s = 0.f;
#pragma unroll
            for (int c = 0; c < 4; ++c) s += f4_dot(q4[c], f4_load(&kb[k][hd + 4 * c]));
            p[k] = s * 0.25f;   // 1/sqrt(16)
        }
        float m = -1e30f;
#pragma unroll
        for (int k = 0; k < T_; ++k) m = fmaxf(m, p[k]);
        float su = 0.f;
#pragma unroll
        for (int k = 0; k < T_; ++k) { p[k] = __expf(p[k] - m); su += p[k]; }
        float iv = 1.f / su;
        // PV
        float4 o4[4] = {f4_zero(), f4_zero(), f4_zero(), f4_zero()};
#pragma unroll
        for (int k = 0; k < T_; ++k) {
#pragma unroll
            for (int c = 0; c < 4; ++c) o4[c] = f4_fma(p[k], f4_load(&vb[k][hd + 4 * c]), o4[c]);
        }
#pragma unroll
        for (int c = 0; c < 4; ++c) {
            o4[c].x *= iv; o4[c].y *= iv; o4[c].z *= iv; o4[c].w *= iv;
            if (rnd == 0) oA[c] = o4[c]; else oB[c] = o4[c];
        }
    }
    __syncthreads();   // all kb/vb reads complete

    // 5) attn-out overlay into kb
    if (act) {
        int hdA = h2 * D_, hdB = (2 + h2) * D_;
#pragma unroll
        for (int c = 0; c < 4; ++c) {
            *(float4*)&kb[rowq][hdA + 4 * c] = oA[c];
            *(float4*)&kb[rowq][hdB + 4 * c] = oB[c];
        }
    }
    __syncthreads();

    // 6) O projection + residual + T-max (cooperative + shfl reduce)
    {
        float4 acc[8];
        float4 b4 = f4_load(bo + e4);
#pragma unroll
        for (int j = 0; j < 8; ++j) acc[j] = b4;
        for (int i0 = 0; i0 < 16; ++i0) {
            float4 w0 = f4_load(wo + (4 * i0 + 0) * E_ + e4);
            float4 w1 = f4_load(wo + (4 * i0 + 1) * E_ + e4);
            float4 w2 = f4_load(wo + (4 * i0 + 2) * E_ + e4);
            float4 w3 = f4_load(wo + (4 * i0 + 3) * E_ + e4);
#pragma unroll
            for (int j = 0; j < 8; ++j) {
                float4 f = f4_load(&kb[tc[j]][4 * i0]);
                acc[j] = f4_fma(f.x, w0, acc[j]);
                acc[j] = f4_fma(f.y, w1, acc[j]);
                acc[j] = f4_fma(f.z, w2, acc[j]);
                acc[j] = f4_fma(f.w, w3, acc[j]);
            }
        }
        float4 mx = make_float4(-1e30f, -1e30f, -1e30f, -1e30f);
#pragma unroll
        for (int j = 0; j < 8; ++j) {
            if (tr[j] < T_) {
                float4 r = f4_add(acc[j], f4_load(&ft[tr[j]][e4]));
                mx.x = fmaxf(mx.x, r.x); mx.y = fmaxf(mx.y, r.y);
                mx.z = fmaxf(mx.z, r.z); mx.w = fmaxf(mx.w, r.w);
            }
        }
        mx.x = fmaxf(mx.x, __shfl_xor(mx.x, 16));
        mx.y = fmaxf(mx.y, __shfl_xor(mx.y, 16));
        mx.z = fmaxf(mx.z, __shfl_xor(mx.z, 16));
        mx.w = fmaxf(mx.w, __shfl_xor(mx.w, 16));
        mx.x = fmaxf(mx.x, __shfl_xor(mx.x, 32));
        mx.y = fmaxf(mx.y, __shfl_xor(mx.y, 32));
        mx.z = fmaxf(mx.z, __shfl_xor(mx.z, 32));
        mx.w = fmaxf(mx.w, __shfl_xor(mx.w, 32));
        if (r4 == 0) *(float4*)(tmax + (size_t)nv * E_ + e4) = mx;
    }
}

// ---------------------------------------------------------------------------
// Kernel 3: per n — max over V, then FC to 7 classes.
// ---------------------------------------------------------------------------
__global__ void k_pool_fc(const float* __restrict__ tmax,
                          const float* __restrict__ fc_w, const float* __restrict__ fc_b,
                          float* __restrict__ out) {
    int n = blockIdx.x;
    int tid = threadIdx.x;  // 64
    __shared__ float pooled[E_];
    float m = -1e30f;
    for (int v = 0; v < V_; ++v) m = fmaxf(m, tmax[((size_t)n * V_ + v) * E_ + tid]);
    pooled[tid] = m;
    __syncthreads();
    if (tid < NC_) {
        float s = fc_b[tid];
        for (int e = 0; e < E_; ++e) s += pooled[e] * fc_w[e * NC_ + tid];
        out[n * NC_ + tid] = s;
    }
}

extern "C" void kernel_launch(void* const* d_in, const int* in_sizes, int n_in,
                              void* d_out, int out_size, void* d_ws, size_t ws_size,
                              hipStream_t stream) {
    const float* xj        = (const float*)d_in[0];
    const float* xv        = (const float*)d_in[1];
    const float* je_w      = (const float*)d_in[2];
    const float* je_b      = (const float*)d_in[3];
    const float* ve_w      = (const float*)d_in[4];
    const float* ve_b      = (const float*)d_in[5];
    const float* joint_emb = (const float*)d_in[6];
    const float* frame_emb = (const float*)d_in[7];
    const float* proj_w    = (const float*)d_in[8];
    const float* proj_b    = (const float*)d_in[9];
    const float* gcn_w1    = (const float*)d_in[10];
    const float* gcn_b1    = (const float*)d_in[11];
    const float* gcn_w2    = (const float*)d_in[12];
    const float* gcn_b2    = (const float*)d_in[13];
    const float* sa_wq     = (const float*)d_in[14];
    const float* sa_bq     = (const float*)d_in[15];
    const float* sa_wk     = (const float*)d_in[16];
    const float* sa_bk     = (const float*)d_in[17];
    const float* sa_wv     = (const float*)d_in[18];
    const float* sa_bv     = (const float*)d_in[19];
    const float* sa_wo     = (const float*)d_in[20];
    const float* sa_bo     = (const float*)d_in[21];
    const float* ta_wq     = (const float*)d_in[22];
    const float* ta_bq     = (const float*)d_in[23];
    const float* ta_wk     = (const float*)d_in[24];
    const float* ta_bk     = (const float*)d_in[25];
    const float* ta_wv     = (const float*)d_in[26];
    const float* ta_bv     = (const float*)d_in[27];
    const float* ta_wo     = (const float*)d_in[28];
    const float* ta_bo     = (const float*)d_in[29];
    const float* fc_w      = (const float*)d_in[30];
    const float* fc_b      = (const float*)d_in[31];
    float* out = (float*)d_out;

    int N = in_sizes[0] / (C_ * T_ * V_);

    // ws layout (floats): tab[3200] | tmax[N*V*E] | feat1[N*T*V*E]
    float* ws    = (float*)d_ws;
    float* tab   = ws;
    float* tmax  = ws + 3200;
    float* feat1 = tmax + (size_t)N * V_ * E_;

    k_setup<<<1, 64, 0, stream>>>(je_w, je_b, ve_w, ve_b, joint_emb, frame_emb,
                                  proj_w, proj_b, tab);
    k_spatial<<<N * T_, 64, 0, stream>>>(xj, xv, tab,
                                         gcn_w1, gcn_b1, gcn_w2, gcn_b2,
                                         sa_wq, sa_bq, sa_wk, sa_bk,
                                         sa_wv, sa_bv, sa_wo, sa_bo, feat1);
    k_temporal<<<N * V_, 64, 0, stream>>>(feat1,
                                          ta_wq, ta_bq, ta_wk, ta_bk,
                                          ta_wv, ta_bv, ta_wo, ta_bo, tmax);
    k_pool_fc<<<N, 64, 0, stream>>>(tmax, fc_w, fc_b, out);
}

// Round 7
// 4704.421 us; speedup vs baseline: 2.7831x; 1.9821x over previous
//
#include <hip/hip_runtime.h>
#include <math.h>

#define C_ 3
#define T_ 30
#define V_ 14
#define E_ 64
#define H_ 4
#define D_ 16
#define NC_ 7

#define EP_ 68   // padded row stride for [*,E] LDS tiles (16B-aligned rows)
#define SCV_ 15  // sc/adj row stride, spatial

__device__ __forceinline__ float4 f4_load(const float* p) {
    return *reinterpret_cast<const float4*>(p);
}
__device__ __forceinline__ float4 f4_zero() { return make_float4(0.f, 0.f, 0.f, 0.f); }
__device__ __forceinline__ float4 f4_add(float4 a, float4 b) {
    return make_float4(a.x + b.x, a.y + b.y, a.z + b.z, a.w + b.w);
}
__device__ __forceinline__ float4 f4_fma(float a, float4 b, float4 c) {
    c.x = fmaf(a, b.x, c.x); c.y = fmaf(a, b.y, c.y);
    c.z = fmaf(a, b.z, c.z); c.w = fmaf(a, b.w, c.w); return c;
}
__device__ __forceinline__ float f4_dot(float4 a, float4 b) {
    return a.x * b.x + a.y * b.y + a.z * b.z + a.w * b.w;
}
__device__ __forceinline__ float4 f4_relu(float4 a) {
    return make_float4(fmaxf(a.x, 0.f), fmaxf(a.y, 0.f), fmaxf(a.z, 0.f), fmaxf(a.w, 0.f));
}

// ---------------------------------------------------------------------------
// Setup: collapse the linear front-end into small tables in ws.
// ---------------------------------------------------------------------------
__global__ void k_setup(const float* __restrict__ je_w, const float* __restrict__ je_b,
                        const float* __restrict__ ve_w, const float* __restrict__ ve_b,
                        const float* __restrict__ joint_emb, const float* __restrict__ frame_emb,
                        const float* __restrict__ proj_w, const float* __restrict__ proj_b,
                        float* __restrict__ tab) {
    int e = threadIdx.x;  // 64 threads
    for (int c = 0; c < C_; ++c) {
        float aj = 0.f, av = 0.f;
        for (int i = 0; i < E_; ++i) {
            float p0 = proj_w[i * E_ + e];
            aj += je_w[c * E_ + i] * p0;
            av += ve_w[c * E_ + i] * p0;
        }
        tab[c * E_ + e] = aj;
        tab[192 + c * E_ + e] = av;
    }
    for (int v = 0; v < V_; ++v) {
        float s = 0.f;
        for (int i = 0; i < E_; ++i) s += joint_emb[v * E_ + i] * proj_w[(64 + i) * E_ + e];
        tab[384 + v * E_ + e] = s;
    }
    float bias = proj_b[e];
    for (int i = 0; i < E_; ++i) bias += (je_b[i] + ve_b[i]) * proj_w[i * E_ + e];
    for (int t = 0; t < T_; ++t) {
        float s = bias;
        for (int i = 0; i < E_; ++i) s += frame_emb[t * E_ + i] * proj_w[(128 + i) * E_ + e];
        tab[1280 + t * E_ + e] = s;
    }
}

// ---------------------------------------------------------------------------
// Kernel 1: ONE WAVE per (n,t) tile (unchanged — proven ~430 us, VGPR 76).
// ---------------------------------------------------------------------------
__global__ __launch_bounds__(64) void k_spatial(
    const float* __restrict__ xj, const float* __restrict__ xv,
    const float* __restrict__ tab,
    const float* __restrict__ w1, const float* __restrict__ b1,
    const float* __restrict__ w2, const float* __restrict__ b2,
    const float* __restrict__ wq, const float* __restrict__ bq,
    const float* __restrict__ wk, const float* __restrict__ bk,
    const float* __restrict__ wv, const float* __restrict__ bv,
    const float* __restrict__ wo, const float* __restrict__ bo,
    float* __restrict__ feat1) {
    int nt = blockIdx.x;
    int n = nt / T_;
    int t = nt % T_;
    int tid = threadIdx.x;      // 0..63
    int l16 = tid & 15;
    int e4 = l16 << 2;
    int r4 = tid >> 4;          // 0..3

    int qr[4], qc[4];
#pragma unroll
    for (int j = 0; j < 4; ++j) {
        qr[j] = r4 + 4 * j;
        qc[j] = (qr[j] < V_) ? qr[j] : 0;
    }

    __shared__ __align__(16) float feat[V_][EP_];
    __shared__ __align__(16) float bufA[V_][EP_];
    __shared__ __align__(16) float bufB[V_][EP_];
    __shared__ float sc[H_][V_][SCV_];
    __shared__ float adj[V_][SCV_];
    __shared__ float xs[2][C_][V_];
    __shared__ float inv_nrm[V_];

    for (int o = tid; o < 2 * C_ * V_; o += 64) {
        int s = o / (C_ * V_);
        int rem = o % (C_ * V_);
        int c = rem / V_, v = rem % V_;
        const float* src = s ? xv : xj;
        xs[s][c][v] = src[((size_t)(n * C_ + c) * T_ + t) * V_ + v];
    }
    __syncthreads();

    // feat build
    {
        float4 F = f4_load(tab + 1280 + t * E_ + e4);
        float4 AJ[C_], AV[C_];
#pragma unroll
        for (int c = 0; c < C_; ++c) {
            AJ[c] = f4_load(tab + c * E_ + e4);
            AV[c] = f4_load(tab + 192 + c * E_ + e4);
        }
#pragma unroll
        for (int j = 0; j < 4; ++j) {
            int q = qr[j];
            if (q < V_) {
                float4 s = f4_add(F, f4_load(tab + 384 + q * E_ + e4));
#pragma unroll
                for (int c = 0; c < C_; ++c) {
                    s = f4_fma(xs[0][c][q], AJ[c], s);
                    s = f4_fma(xs[1][c][q], AV[c], s);
                }
                *(float4*)&feat[q][e4] = s;
            }
        }
    }
    __syncthreads();

    if (tid < V_) {
        float ss = 0.f;
#pragma unroll
        for (int j = 0; j < 16; ++j) { float4 f = f4_load(&feat[tid][4 * j]); ss += f4_dot(f, f); }
        inv_nrm[tid] = 1.0f / fmaxf(sqrtf(ss), 1e-12f);
    }
    __syncthreads();

    for (int o = tid; o < V_ * V_; o += 64) {
        int q = o / V_, k = o % V_;
        float s = 0.f;
#pragma unroll
        for (int j = 0; j < 16; ++j) s += f4_dot(f4_load(&feat[q][4 * j]), f4_load(&feat[k][4 * j]));
        adj[q][k] = s * inv_nrm[q] * inv_nrm[k];
    }
    __syncthreads();
    if (tid < V_) {
        float m = -1e30f;
        for (int k = 0; k < V_; ++k) m = fmaxf(m, adj[tid][k]);
        float sum = 0.f;
        for (int k = 0; k < V_; ++k) { float ex = expf(adj[tid][k] - m); adj[tid][k] = ex; sum += ex; }
        float inv = 1.0f / sum;
        for (int k = 0; k < V_; ++k) adj[tid][k] *= inv;
    }
    __syncthreads();

    {
        float4 acc[4] = {f4_zero(), f4_zero(), f4_zero(), f4_zero()};
#pragma unroll
        for (int k = 0; k < V_; ++k) {
            float4 fv = f4_load(&feat[k][e4]);
#pragma unroll
            for (int j = 0; j < 4; ++j) acc[j] = f4_fma(adj[qc[j]][k], fv, acc[j]);
        }
#pragma unroll
        for (int j = 0; j < 4; ++j) if (qr[j] < V_) *(float4*)&bufA[qr[j]][e4] = acc[j];
    }
    __syncthreads();

    {
        float4 acc[4];
        float4 bb = f4_load(b1 + e4);
#pragma unroll
        for (int j = 0; j < 4; ++j) acc[j] = bb;
        for (int i = 0; i < E_; ++i) {
            float4 w4 = f4_load(w1 + i * E_ + e4);
#pragma unroll
            for (int j = 0; j < 4; ++j) acc[j] = f4_fma(bufA[qc[j]][i], w4, acc[j]);
        }
#pragma unroll
        for (int j = 0; j < 4; ++j) if (qr[j] < V_) *(float4*)&bufB[qr[j]][e4] = f4_relu(acc[j]);
    }
    __syncthreads();

    {
        float4 acc[4];
        float4 bb = f4_load(b2 + e4);
#pragma unroll
        for (int j = 0; j < 4; ++j) acc[j] = bb;
        for (int i = 0; i < E_; ++i) {
            float4 w4 = f4_load(w2 + i * E_ + e4);
#pragma unroll
            for (int j = 0; j < 4; ++j) acc[j] = f4_fma(bufB[qc[j]][i], w4, acc[j]);
        }
#pragma unroll
        for (int j = 0; j < 4; ++j) if (qr[j] < V_) *(float4*)&feat[qr[j]][e4] = acc[j];
    }
    __syncthreads();

    {
        float4 aq[4], ak[4];
        float4 bq4 = f4_load(bq + e4), bk4 = f4_load(bk + e4);
#pragma unroll
        for (int j = 0; j < 4; ++j) { aq[j] = bq4; ak[j] = bk4; }
        for (int i = 0; i < E_; ++i) {
            float4 wq4 = f4_load(wq + i * E_ + e4);
            float4 wk4 = f4_load(wk + i * E_ + e4);
#pragma unroll
            for (int j = 0; j < 4; ++j) {
                float f = feat[qc[j]][i];
                aq[j] = f4_fma(f, wq4, aq[j]);
                ak[j] = f4_fma(f, wk4, ak[j]);
            }
        }
#pragma unroll
        for (int j = 0; j < 4; ++j)
            if (qr[j] < V_) { *(float4*)&bufA[qr[j]][e4] = aq[j]; *(float4*)&bufB[qr[j]][e4] = ak[j]; }
    }
    __syncthreads();

    for (int o = tid; o < H_ * V_ * V_; o += 64) {
        int h = o / (V_ * V_); int r = o % (V_ * V_); int q = r / V_, k = r % V_;
        float s = 0.f;
#pragma unroll
        for (int j = 0; j < 4; ++j)
            s += f4_dot(f4_load(&bufA[q][h * 16 + 4 * j]), f4_load(&bufB[k][h * 16 + 4 * j]));
        sc[h][q][k] = s * 0.25f;  // 1/sqrt(16)
    }
    __syncthreads();
    if (tid < H_ * V_) {
        int h = tid / V_, q = tid % V_;
        float m = -1e30f;
        for (int k = 0; k < V_; ++k) m = fmaxf(m, sc[h][q][k]);
        float sum = 0.f;
        for (int k = 0; k < V_; ++k) { float ex = expf(sc[h][q][k] - m); sc[h][q][k] = ex; sum += ex; }
        float inv = 1.0f / sum;
        for (int k = 0; k < V_; ++k) sc[h][q][k] *= inv;
    }
    __syncthreads();

    {
        float4 av[4];
        float4 bv4 = f4_load(bv + e4);
#pragma unroll
        for (int j = 0; j < 4; ++j) av[j] = bv4;
        for (int i = 0; i < E_; ++i) {
            float4 wv4 = f4_load(wv + i * E_ + e4);
#pragma unroll
            for (int j = 0; j < 4; ++j) av[j] = f4_fma(feat[qc[j]][i], wv4, av[j]);
        }
#pragma unroll
        for (int j = 0; j < 4; ++j) if (qr[j] < V_) *(float4*)&bufA[qr[j]][e4] = av[j];
    }
    __syncthreads();

    {
        int h = l16 >> 2;
        float4 acc[4] = {f4_zero(), f4_zero(), f4_zero(), f4_zero()};
#pragma unroll
        for (int k = 0; k < V_; ++k) {
            float4 v4 = f4_load(&bufA[k][e4]);
#pragma unroll
            for (int j = 0; j < 4; ++j) acc[j] = f4_fma(sc[h][qc[j]][k], v4, acc[j]);
        }
#pragma unroll
        for (int j = 0; j < 4; ++j) if (qr[j] < V_) *(float4*)&bufB[qr[j]][e4] = acc[j];
    }
    __syncthreads();

    {
        float4 acc[4];
        float4 bo4 = f4_load(bo + e4);
#pragma unroll
        for (int j = 0; j < 4; ++j) acc[j] = bo4;
        for (int i = 0; i < E_; ++i) {
            float4 w4 = f4_load(wo + i * E_ + e4);
#pragma unroll
            for (int j = 0; j < 4; ++j) acc[j] = f4_fma(bufB[qc[j]][i], w4, acc[j]);
        }
#pragma unroll
        for (int j = 0; j < 4; ++j)
            if (qr[j] < V_) {
                float4 r = f4_add(acc[j], f4_load(&feat[qr[j]][e4]));
                *(float4*)(feat1 + (size_t)nt * (V_ * E_) + qr[j] * E_ + e4) = r;
            }
    }
}

// ---------------------------------------------------------------------------
// Kernel 2: ONE WAVE per (n,v) tile. LDS: ft + K + V (24.5 KB -> 6 blocks/CU).
// All GEMM phases in the PROVEN k_spatial loop shape: 64-trip, scalar LDS
// element x ONE float4 weight load per iter (prevents hipcc full-unroll
// load-hoist VGPR blowup seen in R5/R6). Attention per lane in 2 head-rounds.
// ---------------------------------------------------------------------------
__global__ __launch_bounds__(64) void k_temporal(
    const float* __restrict__ feat1,
    const float* __restrict__ wq, const float* __restrict__ bq,
    const float* __restrict__ wk, const float* __restrict__ bk,
    const float* __restrict__ wv, const float* __restrict__ bv,
    const float* __restrict__ wo, const float* __restrict__ bo,
    float* __restrict__ tmax) {
    int nv = blockIdx.x;
    int n = nv / V_;
    int v = nv % V_;
    int tid = threadIdx.x;      // 0..63
    int l16 = tid & 15;
    int e4 = l16 << 2;
    int r4 = tid >> 4;          // 0..3

    __shared__ __align__(16) float ft[T_][EP_];   // residual + projection input
    __shared__ __align__(16) float kb[T_][EP_];   // K, later attn-out
    __shared__ __align__(16) float vb[T_][EP_];   // V

    int tr[8], tc[8];
#pragma unroll
    for (int j = 0; j < 8; ++j) { tr[j] = r4 + 4 * j; tc[j] = (tr[j] < T_) ? tr[j] : 0; }

    // 1) load ft
#pragma unroll
    for (int j = 0; j < 8; ++j)
        if (tr[j] < T_)
            *(float4*)&ft[tr[j]][e4] =
                f4_load(feat1 + (((size_t)n * T_ + tr[j]) * V_ + v) * E_ + e4);
    __syncthreads();

    // 2) K projection -> kb (k_spatial loop shape: 1 f4 weight load / iter)
    {
        float4 acc[8];
        float4 b4 = f4_load(bk + e4);
#pragma unroll
        for (int j = 0; j < 8; ++j) acc[j] = b4;
        for (int i = 0; i < E_; ++i) {
            float4 w4 = f4_load(wk + i * E_ + e4);
#pragma unroll
            for (int j = 0; j < 8; ++j) acc[j] = f4_fma(ft[tc[j]][i], w4, acc[j]);
        }
#pragma unroll
        for (int j = 0; j < 8; ++j)
            if (tr[j] < T_) *(float4*)&kb[tr[j]][e4] = acc[j];
    }

    // 3) V projection -> vb
    {
        float4 acc[8];
        float4 b4 = f4_load(bv + e4);
#pragma unroll
        for (int j = 0; j < 8; ++j) acc[j] = b4;
        for (int i = 0; i < E_; ++i) {
            float4 w4 = f4_load(wv + i * E_ + e4);
#pragma unroll
            for (int j = 0; j < 8; ++j) acc[j] = f4_fma(ft[tc[j]][i], w4, acc[j]);
        }
#pragma unroll
        for (int j = 0; j < 8; ++j)
            if (tr[j] < T_) *(float4*)&vb[tr[j]][e4] = acc[j];
    }
    __syncthreads();

    // 4) per-lane attention in two head-rounds (low register footprint)
    bool act = (tid < 60);
    int rowq = tid % 30;                // 0..29 (garbage-safe for tid>=60)
    int h2   = act ? (tid / 30) : 0;    // 0 or 1
    float4 oA[4], oB[4];

#pragma unroll
    for (int rnd = 0; rnd < 2; ++rnd) {
        int hd = (rnd * 2 + h2) * D_;   // head dim offset: 0/16 or 32/48
        // q projection for this head (16 dims in regs); cap unroll to avoid
        // hoisting 4 VMEM loads x many iters.
        float4 q4[4];
#pragma unroll
        for (int c = 0; c < 4; ++c) q4[c] = f4_load(bq + hd + 4 * c);
#pragma unroll 2
        for (int i = 0; i < E_; ++i) {
            float f = ft[rowq][i];
#pragma unroll
            for (int c = 0; c < 4; ++c)
                q4[c] = f4_fma(f, f4_load(wq + i * E_ + hd + 4 * c), q4[c]);
        }
        // scores + softmax (in-lane; kb reads are 2-way broadcast = free)
        float p[T_];
#pragma unroll
        for (int k = 0; k < T_; ++k) {
            float s = 0.f;
#pragma unroll
            for (int c = 0; c < 4; ++c) s += f4_dot(q4[c], f4_load(&kb[k][hd + 4 * c]));
            p[k] = s * 0.25f;   // 1/sqrt(16)
        }
        float m = -1e30f;
#pragma unroll
        for (int k = 0; k < T_; ++k) m = fmaxf(m, p[k]);
        float su = 0.f;
#pragma unroll
        for (int k = 0; k < T_; ++k) { p[k] = __expf(p[k] - m); su += p[k]; }
        float iv = 1.f / su;
        // PV
        float4 o4[4] = {f4_zero(), f4_zero(), f4_zero(), f4_zero()};
#pragma unroll
        for (int k = 0; k < T_; ++k) {
#pragma unroll
            for (int c = 0; c < 4; ++c) o4[c] = f4_fma(p[k], f4_load(&vb[k][hd + 4 * c]), o4[c]);
        }
#pragma unroll
        for (int c = 0; c < 4; ++c) {
            o4[c].x *= iv; o4[c].y *= iv; o4[c].z *= iv; o4[c].w *= iv;
            if (rnd == 0) oA[c] = o4[c]; else oB[c] = o4[c];
        }
    }
    __syncthreads();   // all kb/vb reads complete

    // 5) attn-out overlay into kb
    if (act) {
        int hdA = h2 * D_, hdB = (2 + h2) * D_;
#pragma unroll
        for (int c = 0; c < 4; ++c) {
            *(float4*)&kb[rowq][hdA + 4 * c] = oA[c];
            *(float4*)&kb[rowq][hdB + 4 * c] = oB[c];
        }
    }
    __syncthreads();

    // 6) O projection + residual + T-max (cooperative + shfl reduce)
    {
        float4 acc[8];
        float4 b4 = f4_load(bo + e4);
#pragma unroll
        for (int j = 0; j < 8; ++j) acc[j] = b4;
        for (int i = 0; i < E_; ++i) {
            float4 w4 = f4_load(wo + i * E_ + e4);
#pragma unroll
            for (int j = 0; j < 8; ++j) acc[j] = f4_fma(kb[tc[j]][i], w4, acc[j]);
        }
        float4 mx = make_float4(-1e30f, -1e30f, -1e30f, -1e30f);
#pragma unroll
        for (int j = 0; j < 8; ++j) {
            if (tr[j] < T_) {
                float4 r = f4_add(acc[j], f4_load(&ft[tr[j]][e4]));
                mx.x = fmaxf(mx.x, r.x); mx.y = fmaxf(mx.y, r.y);
                mx.z = fmaxf(mx.z, r.z); mx.w = fmaxf(mx.w, r.w);
            }
        }
        mx.x = fmaxf(mx.x, __shfl_xor(mx.x, 16));
        mx.y = fmaxf(mx.y, __shfl_xor(mx.y, 16));
        mx.z = fmaxf(mx.z, __shfl_xor(mx.z, 16));
        mx.w = fmaxf(mx.w, __shfl_xor(mx.w, 16));
        mx.x = fmaxf(mx.x, __shfl_xor(mx.x, 32));
        mx.y = fmaxf(mx.y, __shfl_xor(mx.y, 32));
        mx.z = fmaxf(mx.z, __shfl_xor(mx.z, 32));
        mx.w = fmaxf(mx.w, __shfl_xor(mx.w, 32));
        if (r4 == 0) *(float4*)(tmax + (size_t)nv * E_ + e4) = mx;
    }
}

// ---------------------------------------------------------------------------
// Kernel 3: per n — max over V, then FC to 7 classes.
// ---------------------------------------------------------------------------
__global__ void k_pool_fc(const float* __restrict__ tmax,
                          const float* __restrict__ fc_w, const float* __restrict__ fc_b,
                          float* __restrict__ out) {
    int n = blockIdx.x;
    int tid = threadIdx.x;  // 64
    __shared__ float pooled[E_];
    float m = -1e30f;
    for (int v = 0; v < V_; ++v) m = fmaxf(m, tmax[((size_t)n * V_ + v) * E_ + tid]);
    pooled[tid] = m;
    __syncthreads();
    if (tid < NC_) {
        float s = fc_b[tid];
        for (int e = 0; e < E_; ++e) s += pooled[e] * fc_w[e * NC_ + tid];
        out[n * NC_ + tid] = s;
    }
}

extern "C" void kernel_launch(void* const* d_in, const int* in_sizes, int n_in,
                              void* d_out, int out_size, void* d_ws, size_t ws_size,
                              hipStream_t stream) {
    const float* xj        = (const float*)d_in[0];
    const float* xv        = (const float*)d_in[1];
    const float* je_w      = (const float*)d_in[2];
    const float* je_b      = (const float*)d_in[3];
    const float* ve_w      = (const float*)d_in[4];
    const float* ve_b      = (const float*)d_in[5];
    const float* joint_emb = (const float*)d_in[6];
    const float* frame_emb = (const float*)d_in[7];
    const float* proj_w    = (const float*)d_in[8];
    const float* proj_b    = (const float*)d_in[9];
    const float* gcn_w1    = (const float*)d_in[10];
    const float* gcn_b1    = (const float*)d_in[11];
    const float* gcn_w2    = (const float*)d_in[12];
    const float* gcn_b2    = (const float*)d_in[13];
    const float* sa_wq     = (const float*)d_in[14];
    const float* sa_bq     = (const float*)d_in[15];
    const float* sa_wk     = (const float*)d_in[16];
    const float* sa_bk     = (const float*)d_in[17];
    const float* sa_wv     = (const float*)d_in[18];
    const float* sa_bv     = (const float*)d_in[19];
    const float* sa_wo     = (const float*)d_in[20];
    const float* sa_bo     = (const float*)d_in[21];
    const float* ta_wq     = (const float*)d_in[22];
    const float* ta_bq     = (const float*)d_in[23];
    const float* ta_wk     = (const float*)d_in[24];
    const float* ta_bk     = (const float*)d_in[25];
    const float* ta_wv     = (const float*)d_in[26];
    const float* ta_bv     = (const float*)d_in[27];
    const float* ta_wo     = (const float*)d_in[28];
    const float* ta_bo     = (const float*)d_in[29];
    const float* fc_w      = (const float*)d_in[30];
    const float* fc_b      = (const float*)d_in[31];
    float* out = (float*)d_out;

    int N = in_sizes[0] / (C_ * T_ * V_);

    // ws layout (floats): tab[3200] | tmax[N*V*E] | feat1[N*T*V*E]
    float* ws    = (float*)d_ws;
    float* tab   = ws;
    float* tmax  = ws + 3200;
    float* feat1 = tmax + (size_t)N * V_ * E_;

    k_setup<<<1, 64, 0, stream>>>(je_w, je_b, ve_w, ve_b, joint_emb, frame_emb,
                                  proj_w, proj_b, tab);
    k_spatial<<<N * T_, 64, 0, stream>>>(xj, xv, tab,
                                         gcn_w1, gcn_b1, gcn_w2, gcn_b2,
                                         sa_wq, sa_bq, sa_wk, sa_bk,
                                         sa_wv, sa_bv, sa_wo, sa_bo, feat1);
    k_temporal<<<N * V_, 64, 0, stream>>>(feat1,
                                          ta_wq, ta_bq, ta_wk, ta_bk,
                                          ta_wv, ta_bv, ta_wo, ta_bo, tmax);
    k_pool_fc<<<N, 64, 0, stream>>>(tmax, fc_w, fc_b, out);
}

// Round 8
// 1236.780 us; speedup vs baseline: 10.5863x; 3.8038x over previous
//
#include <hip/hip_runtime.h>
#include <math.h>

#define C_ 3
#define T_ 30
#define V_ 14
#define E_ 64
#define H_ 4
#define D_ 16
#define NC_ 7

#define EP_ 68   // padded row stride for [*,E] LDS tiles (16B-aligned rows)
#define SCV_ 15  // sc/adj row stride, spatial

__device__ __forceinline__ float4 f4_load(const float* p) {
    return *reinterpret_cast<const float4*>(p);
}
__device__ __forceinline__ float4 f4_zero() { return make_float4(0.f, 0.f, 0.f, 0.f); }
__device__ __forceinline__ float4 f4_add(float4 a, float4 b) {
    return make_float4(a.x + b.x, a.y + b.y, a.z + b.z, a.w + b.w);
}
__device__ __forceinline__ float4 f4_fma(float a, float4 b, float4 c) {
    c.x = fmaf(a, b.x, c.x); c.y = fmaf(a, b.y, c.y);
    c.z = fmaf(a, b.z, c.z); c.w = fmaf(a, b.w, c.w); return c;
}
__device__ __forceinline__ float f4_dot(float4 a, float4 b) {
    return a.x * b.x + a.y * b.y + a.z * b.z + a.w * b.w;
}
__device__ __forceinline__ float4 f4_relu(float4 a) {
    return make_float4(fmaxf(a.x, 0.f), fmaxf(a.y, 0.f), fmaxf(a.z, 0.f), fmaxf(a.w, 0.f));
}

// ---------------------------------------------------------------------------
// Setup: collapse the linear front-end into small tables in ws.
// ---------------------------------------------------------------------------
__global__ void k_setup(const float* __restrict__ je_w, const float* __restrict__ je_b,
                        const float* __restrict__ ve_w, const float* __restrict__ ve_b,
                        const float* __restrict__ joint_emb, const float* __restrict__ frame_emb,
                        const float* __restrict__ proj_w, const float* __restrict__ proj_b,
                        float* __restrict__ tab) {
    int e = threadIdx.x;  // 64 threads
    for (int c = 0; c < C_; ++c) {
        float aj = 0.f, av = 0.f;
        for (int i = 0; i < E_; ++i) {
            float p0 = proj_w[i * E_ + e];
            aj += je_w[c * E_ + i] * p0;
            av += ve_w[c * E_ + i] * p0;
        }
        tab[c * E_ + e] = aj;
        tab[192 + c * E_ + e] = av;
    }
    for (int v = 0; v < V_; ++v) {
        float s = 0.f;
        for (int i = 0; i < E_; ++i) s += joint_emb[v * E_ + i] * proj_w[(64 + i) * E_ + e];
        tab[384 + v * E_ + e] = s;
    }
    float bias = proj_b[e];
    for (int i = 0; i < E_; ++i) bias += (je_b[i] + ve_b[i]) * proj_w[i * E_ + e];
    for (int t = 0; t < T_; ++t) {
        float s = bias;
        for (int i = 0; i < E_; ++i) s += frame_emb[t * E_ + i] * proj_w[(128 + i) * E_ + e];
        tab[1280 + t * E_ + e] = s;
    }
}

// ---------------------------------------------------------------------------
// Kernel 1: ONE WAVE per (n,t) tile (unchanged — proven ~430 us, VGPR 76).
// ---------------------------------------------------------------------------
__global__ __launch_bounds__(64) void k_spatial(
    const float* __restrict__ xj, const float* __restrict__ xv,
    const float* __restrict__ tab,
    const float* __restrict__ w1, const float* __restrict__ b1,
    const float* __restrict__ w2, const float* __restrict__ b2,
    const float* __restrict__ wq, const float* __restrict__ bq,
    const float* __restrict__ wk, const float* __restrict__ bk,
    const float* __restrict__ wv, const float* __restrict__ bv,
    const float* __restrict__ wo, const float* __restrict__ bo,
    float* __restrict__ feat1) {
    int nt = blockIdx.x;
    int n = nt / T_;
    int t = nt % T_;
    int tid = threadIdx.x;      // 0..63
    int l16 = tid & 15;
    int e4 = l16 << 2;
    int r4 = tid >> 4;          // 0..3

    int qr[4], qc[4];
#pragma unroll
    for (int j = 0; j < 4; ++j) {
        qr[j] = r4 + 4 * j;
        qc[j] = (qr[j] < V_) ? qr[j] : 0;
    }

    __shared__ __align__(16) float feat[V_][EP_];
    __shared__ __align__(16) float bufA[V_][EP_];
    __shared__ __align__(16) float bufB[V_][EP_];
    __shared__ float sc[H_][V_][SCV_];
    __shared__ float adj[V_][SCV_];
    __shared__ float xs[2][C_][V_];
    __shared__ float inv_nrm[V_];

    for (int o = tid; o < 2 * C_ * V_; o += 64) {
        int s = o / (C_ * V_);
        int rem = o % (C_ * V_);
        int c = rem / V_, v = rem % V_;
        const float* src = s ? xv : xj;
        xs[s][c][v] = src[((size_t)(n * C_ + c) * T_ + t) * V_ + v];
    }
    __syncthreads();

    // feat build
    {
        float4 F = f4_load(tab + 1280 + t * E_ + e4);
        float4 AJ[C_], AV[C_];
#pragma unroll
        for (int c = 0; c < C_; ++c) {
            AJ[c] = f4_load(tab + c * E_ + e4);
            AV[c] = f4_load(tab + 192 + c * E_ + e4);
        }
#pragma unroll
        for (int j = 0; j < 4; ++j) {
            int q = qr[j];
            if (q < V_) {
                float4 s = f4_add(F, f4_load(tab + 384 + q * E_ + e4));
#pragma unroll
                for (int c = 0; c < C_; ++c) {
                    s = f4_fma(xs[0][c][q], AJ[c], s);
                    s = f4_fma(xs[1][c][q], AV[c], s);
                }
                *(float4*)&feat[q][e4] = s;
            }
        }
    }
    __syncthreads();

    if (tid < V_) {
        float ss = 0.f;
#pragma unroll
        for (int j = 0; j < 16; ++j) { float4 f = f4_load(&feat[tid][4 * j]); ss += f4_dot(f, f); }
        inv_nrm[tid] = 1.0f / fmaxf(sqrtf(ss), 1e-12f);
    }
    __syncthreads();

    for (int o = tid; o < V_ * V_; o += 64) {
        int q = o / V_, k = o % V_;
        float s = 0.f;
#pragma unroll
        for (int j = 0; j < 16; ++j) s += f4_dot(f4_load(&feat[q][4 * j]), f4_load(&feat[k][4 * j]));
        adj[q][k] = s * inv_nrm[q] * inv_nrm[k];
    }
    __syncthreads();
    if (tid < V_) {
        float m = -1e30f;
        for (int k = 0; k < V_; ++k) m = fmaxf(m, adj[tid][k]);
        float sum = 0.f;
        for (int k = 0; k < V_; ++k) { float ex = expf(adj[tid][k] - m); adj[tid][k] = ex; sum += ex; }
        float inv = 1.0f / sum;
        for (int k = 0; k < V_; ++k) adj[tid][k] *= inv;
    }
    __syncthreads();

    {
        float4 acc[4] = {f4_zero(), f4_zero(), f4_zero(), f4_zero()};
#pragma unroll
        for (int k = 0; k < V_; ++k) {
            float4 fv = f4_load(&feat[k][e4]);
#pragma unroll
            for (int j = 0; j < 4; ++j) acc[j] = f4_fma(adj[qc[j]][k], fv, acc[j]);
        }
#pragma unroll
        for (int j = 0; j < 4; ++j) if (qr[j] < V_) *(float4*)&bufA[qr[j]][e4] = acc[j];
    }
    __syncthreads();

    {
        float4 acc[4];
        float4 bb = f4_load(b1 + e4);
#pragma unroll
        for (int j = 0; j < 4; ++j) acc[j] = bb;
        for (int i = 0; i < E_; ++i) {
            float4 w4 = f4_load(w1 + i * E_ + e4);
#pragma unroll
            for (int j = 0; j < 4; ++j) acc[j] = f4_fma(bufA[qc[j]][i], w4, acc[j]);
        }
#pragma unroll
        for (int j = 0; j < 4; ++j) if (qr[j] < V_) *(float4*)&bufB[qr[j]][e4] = f4_relu(acc[j]);
    }
    __syncthreads();

    {
        float4 acc[4];
        float4 bb = f4_load(b2 + e4);
#pragma unroll
        for (int j = 0; j < 4; ++j) acc[j] = bb;
        for (int i = 0; i < E_; ++i) {
            float4 w4 = f4_load(w2 + i * E_ + e4);
#pragma unroll
            for (int j = 0; j < 4; ++j) acc[j] = f4_fma(bufB[qc[j]][i], w4, acc[j]);
        }
#pragma unroll
        for (int j = 0; j < 4; ++j) if (qr[j] < V_) *(float4*)&feat[qr[j]][e4] = acc[j];
    }
    __syncthreads();

    {
        float4 aq[4], ak[4];
        float4 bq4 = f4_load(bq + e4), bk4 = f4_load(bk + e4);
#pragma unroll
        for (int j = 0; j < 4; ++j) { aq[j] = bq4; ak[j] = bk4; }
        for (int i = 0; i < E_; ++i) {
            float4 wq4 = f4_load(wq + i * E_ + e4);
            float4 wk4 = f4_load(wk + i * E_ + e4);
#pragma unroll
            for (int j = 0; j < 4; ++j) {
                float f = feat[qc[j]][i];
                aq[j] = f4_fma(f, wq4, aq[j]);
                ak[j] = f4_fma(f, wk4, ak[j]);
            }
        }
#pragma unroll
        for (int j = 0; j < 4; ++j)
            if (qr[j] < V_) { *(float4*)&bufA[qr[j]][e4] = aq[j]; *(float4*)&bufB[qr[j]][e4] = ak[j]; }
    }
    __syncthreads();

    for (int o = tid; o < H_ * V_ * V_; o += 64) {
        int h = o / (V_ * V_); int r = o % (V_ * V_); int q = r / V_, k = r % V_;
        float s = 0.f;
#pragma unroll
        for (int j = 0; j < 4; ++j)
            s += f4_dot(f4_load(&bufA[q][h * 16 + 4 * j]), f4_load(&bufB[k][h * 16 + 4 * j]));
        sc[h][q][k] = s * 0.25f;  // 1/sqrt(16)
    }
    __syncthreads();
    if (tid < H_ * V_) {
        int h = tid / V_, q = tid % V_;
        float m = -1e30f;
        for (int k = 0; k < V_; ++k) m = fmaxf(m, sc[h][q][k]);
        float sum = 0.f;
        for (int k = 0; k < V_; ++k) { float ex = expf(sc[h][q][k] - m); sc[h][q][k] = ex; sum += ex; }
        float inv = 1.0f / sum;
        for (int k = 0; k < V_; ++k) sc[h][q][k] *= inv;
    }
    __syncthreads();

    {
        float4 av[4];
        float4 bv4 = f4_load(bv + e4);
#pragma unroll
        for (int j = 0; j < 4; ++j) av[j] = bv4;
        for (int i = 0; i < E_; ++i) {
            float4 wv4 = f4_load(wv + i * E_ + e4);
#pragma unroll
            for (int j = 0; j < 4; ++j) av[j] = f4_fma(feat[qc[j]][i], wv4, av[j]);
        }
#pragma unroll
        for (int j = 0; j < 4; ++j) if (qr[j] < V_) *(float4*)&bufA[qr[j]][e4] = av[j];
    }
    __syncthreads();

    {
        int h = l16 >> 2;
        float4 acc[4] = {f4_zero(), f4_zero(), f4_zero(), f4_zero()};
#pragma unroll
        for (int k = 0; k < V_; ++k) {
            float4 v4 = f4_load(&bufA[k][e4]);
#pragma unroll
            for (int j = 0; j < 4; ++j) acc[j] = f4_fma(sc[h][qc[j]][k], v4, acc[j]);
        }
#pragma unroll
        for (int j = 0; j < 4; ++j) if (qr[j] < V_) *(float4*)&bufB[qr[j]][e4] = acc[j];
    }
    __syncthreads();

    {
        float4 acc[4];
        float4 bo4 = f4_load(bo + e4);
#pragma unroll
        for (int j = 0; j < 4; ++j) acc[j] = bo4;
        for (int i = 0; i < E_; ++i) {
            float4 w4 = f4_load(wo + i * E_ + e4);
#pragma unroll
            for (int j = 0; j < 4; ++j) acc[j] = f4_fma(bufB[qc[j]][i], w4, acc[j]);
        }
#pragma unroll
        for (int j = 0; j < 4; ++j)
            if (qr[j] < V_) {
                float4 r = f4_add(acc[j], f4_load(&feat[qr[j]][e4]));
                *(float4*)(feat1 + (size_t)nt * (V_ * E_) + qr[j] * E_ + e4) = r;
            }
    }
}

// ---------------------------------------------------------------------------
// Kernel 2: ONE WAVE per (n,v) tile, HEAD-AT-A-TIME attention, all phases
// cooperative with LDS-resident scores (no per-lane p[] arrays -> no spill).
// smem (floats): ft[30][68] | Qh[30][20] | KTh[16][32] | sc[30][36] | pvh[30][20]
// = 4832 floats = 19328 B -> 8 blocks (waves) per CU.
// O-projection folded into per-head partial accumulation in 8 persistent f4 regs.
// ---------------------------------------------------------------------------
__global__ __launch_bounds__(64) void k_temporal(
    const float* __restrict__ feat1,
    const float* __restrict__ wq, const float* __restrict__ bq,
    const float* __restrict__ wk, const float* __restrict__ bk,
    const float* __restrict__ wv, const float* __restrict__ bv,
    const float* __restrict__ wo, const float* __restrict__ bo,
    float* __restrict__ tmax) {
    int nv = blockIdx.x;
    int n = nv / V_;
    int v = nv % V_;
    int tid = threadIdx.x;      // 0..63
    int l16 = tid & 15;
    int e4 = l16 << 2;
    int r4 = tid >> 4;          // 0..3

    __shared__ __align__(16) float smem[4832];
    float* ftb = smem;          // [r*68 + c], residual + proj input
    float* Qh  = smem + 2040;   // [r*20 + c], Q rows of head h; later V
    float* KTh = smem + 2640;   // [d*32 + k], K^T of head h
    float* scb = smem + 3152;   // [q*36 + k], scores/probs
    float* pvh = smem + 4232;   // [q*20 + c], PV output of head h

    int tr[8], tc[8];
#pragma unroll
    for (int j = 0; j < 8; ++j) { tr[j] = r4 + 4 * j; tc[j] = (tr[j] < T_) ? tr[j] : 0; }

    // load ft
#pragma unroll
    for (int j = 0; j < 8; ++j)
        if (tr[j] < T_)
            *(float4*)&ftb[tr[j] * EP_ + e4] =
                f4_load(feat1 + (((size_t)n * T_ + tr[j]) * V_ + v) * E_ + e4);
    __syncthreads();

    // persistent O-proj accumulator (rows tr[j], cols e4..e4+3)
    float4 acc_out[8];
    {
        float4 bo4 = f4_load(bo + e4);
#pragma unroll
        for (int j = 0; j < 8; ++j) acc_out[j] = bo4;
    }

    // per-lane mapping for projection phases: (c4 = col-f4 within head, 2 rows)
    int c4 = tid & 3;
    int rs = tid >> 2;          // 0..15
    int row0 = rs, row1 = rs + 16;
    bool r1ok = (row1 < T_);
    int row1c = r1ok ? row1 : 0;

    for (int h = 0; h < H_; ++h) {
        int hb = h * D_ + 4 * c4;   // global col base for this lane's head slice

        // Q-proj -> Qh (rows row0,row1 x 4 cols)
        {
            float4 a0 = f4_load(bq + hb), a1 = a0;
            for (int i = 0; i < E_; ++i) {
                float4 w4 = f4_load(wq + i * E_ + hb);
                a0 = f4_fma(ftb[row0 * EP_ + i], w4, a0);
                a1 = f4_fma(ftb[row1c * EP_ + i], w4, a1);
            }
            *(float4*)&Qh[row0 * 20 + 4 * c4] = a0;
            if (r1ok) *(float4*)&Qh[row1 * 20 + 4 * c4] = a1;
        }
        // K-proj -> KTh transposed
        {
            float4 a0 = f4_load(bk + hb), a1 = a0;
            for (int i = 0; i < E_; ++i) {
                float4 w4 = f4_load(wk + i * E_ + hb);
                a0 = f4_fma(ftb[row0 * EP_ + i], w4, a0);
                a1 = f4_fma(ftb[row1c * EP_ + i], w4, a1);
            }
            KTh[(4 * c4 + 0) * 32 + row0] = a0.x;
            KTh[(4 * c4 + 1) * 32 + row0] = a0.y;
            KTh[(4 * c4 + 2) * 32 + row0] = a0.z;
            KTh[(4 * c4 + 3) * 32 + row0] = a0.w;
            if (r1ok) {
                KTh[(4 * c4 + 0) * 32 + row1] = a1.x;
                KTh[(4 * c4 + 1) * 32 + row1] = a1.y;
                KTh[(4 * c4 + 2) * 32 + row1] = a1.z;
                KTh[(4 * c4 + 3) * 32 + row1] = a1.w;
            }
        }
        __syncthreads();

        // scores: sc[q][k] = 0.25 * Q[q]·K[k]  (f4 GEMM vs K^T; cols 30,31 garbage, unread)
        for (int o = tid; o < 240; o += 64) {
            int q = o >> 3, k4 = o & 7;
            float4 a = f4_zero();
            for (int d = 0; d < D_; ++d)
                a = f4_fma(Qh[q * 20 + d], f4_load(&KTh[d * 32 + 4 * k4]), a);
            a.x *= 0.25f; a.y *= 0.25f; a.z *= 0.25f; a.w *= 0.25f;
            *(float4*)&scb[q * 36 + 4 * k4] = a;
        }
        __syncthreads();

        // softmax rows (lanes 0..29), k < 30 only
        if (tid < T_) {
            float m = -1e30f;
            for (int k = 0; k < T_; ++k) m = fmaxf(m, scb[tid * 36 + k]);
            float su = 0.f;
            for (int k = 0; k < T_; ++k) {
                float ex = __expf(scb[tid * 36 + k] - m);
                scb[tid * 36 + k] = ex; su += ex;
            }
            float iv = 1.f / su;
            for (int k = 0; k < T_; ++k) scb[tid * 36 + k] *= iv;
        }
        // V-proj -> Qh (Q dead after scores barrier)
        {
            float4 a0 = f4_load(bv + hb), a1 = a0;
            for (int i = 0; i < E_; ++i) {
                float4 w4 = f4_load(wv + i * E_ + hb);
                a0 = f4_fma(ftb[row0 * EP_ + i], w4, a0);
                a1 = f4_fma(ftb[row1c * EP_ + i], w4, a1);
            }
            *(float4*)&Qh[row0 * 20 + 4 * c4] = a0;
            if (r1ok) *(float4*)&Qh[row1 * 20 + 4 * c4] = a1;
        }
        __syncthreads();

        // PV -> pvh: out[q][cc4] = sum_k P[q][k] * V[k][cc4]
        for (int o = tid; o < 120; o += 64) {
            int q = o >> 2, cc = o & 3;
            float4 a = f4_zero();
            for (int k = 0; k < T_; ++k)
                a = f4_fma(scb[q * 36 + k], f4_load(&Qh[k * 20 + 4 * cc]), a);
            *(float4*)&pvh[q * 20 + 4 * cc] = a;
        }
        __syncthreads();

        // partial O-proj: acc_out[j] += sum_hc pvh[tc[j]][hc] * Wo[h*16+hc][e4]
        for (int hc = 0; hc < D_; ++hc) {
            float4 w4 = f4_load(wo + (h * D_ + hc) * E_ + e4);
#pragma unroll
            for (int j = 0; j < 8; ++j)
                acc_out[j] = f4_fma(pvh[tc[j] * 20 + hc], w4, acc_out[j]);
        }
        __syncthreads();   // pvh/Qh/sc reused next round
    }

    // residual + T-max + cross-lane reduce + write
    {
        float4 mx = make_float4(-1e30f, -1e30f, -1e30f, -1e30f);
#pragma unroll
        for (int j = 0; j < 8; ++j) {
            if (tr[j] < T_) {
                float4 r = f4_add(acc_out[j], f4_load(&ftb[tr[j] * EP_ + e4]));
                mx.x = fmaxf(mx.x, r.x); mx.y = fmaxf(mx.y, r.y);
                mx.z = fmaxf(mx.z, r.z); mx.w = fmaxf(mx.w, r.w);
            }
        }
        mx.x = fmaxf(mx.x, __shfl_xor(mx.x, 16));
        mx.y = fmaxf(mx.y, __shfl_xor(mx.y, 16));
        mx.z = fmaxf(mx.z, __shfl_xor(mx.z, 16));
        mx.w = fmaxf(mx.w, __shfl_xor(mx.w, 16));
        mx.x = fmaxf(mx.x, __shfl_xor(mx.x, 32));
        mx.y = fmaxf(mx.y, __shfl_xor(mx.y, 32));
        mx.z = fmaxf(mx.z, __shfl_xor(mx.z, 32));
        mx.w = fmaxf(mx.w, __shfl_xor(mx.w, 32));
        if (r4 == 0) *(float4*)(tmax + (size_t)nv * E_ + e4) = mx;
    }
}

// ---------------------------------------------------------------------------
// Kernel 3: per n — max over V, then FC to 7 classes.
// ---------------------------------------------------------------------------
__global__ void k_pool_fc(const float* __restrict__ tmax,
                          const float* __restrict__ fc_w, const float* __restrict__ fc_b,
                          float* __restrict__ out) {
    int n = blockIdx.x;
    int tid = threadIdx.x;  // 64
    __shared__ float pooled[E_];
    float m = -1e30f;
    for (int v = 0; v < V_; ++v) m = fmaxf(m, tmax[((size_t)n * V_ + v) * E_ + tid]);
    pooled[tid] = m;
    __syncthreads();
    if (tid < NC_) {
        float s = fc_b[tid];
        for (int e = 0; e < E_; ++e) s += pooled[e] * fc_w[e * NC_ + tid];
        out[n * NC_ + tid] = s;
    }
}

extern "C" void kernel_launch(void* const* d_in, const int* in_sizes, int n_in,
                              void* d_out, int out_size, void* d_ws, size_t ws_size,
                              hipStream_t stream) {
    const float* xj        = (const float*)d_in[0];
    const float* xv        = (const float*)d_in[1];
    const float* je_w      = (const float*)d_in[2];
    const float* je_b      = (const float*)d_in[3];
    const float* ve_w      = (const float*)d_in[4];
    const float* ve_b      = (const float*)d_in[5];
    const float* joint_emb = (const float*)d_in[6];
    const float* frame_emb = (const float*)d_in[7];
    const float* proj_w    = (const float*)d_in[8];
    const float* proj_b    = (const float*)d_in[9];
    const float* gcn_w1    = (const float*)d_in[10];
    const float* gcn_b1    = (const float*)d_in[11];
    const float* gcn_w2    = (const float*)d_in[12];
    const float* gcn_b2    = (const float*)d_in[13];
    const float* sa_wq     = (const float*)d_in[14];
    const float* sa_bq     = (const float*)d_in[15];
    const float* sa_wk     = (const float*)d_in[16];
    const float* sa_bk     = (const float*)d_in[17];
    const float* sa_wv     = (const float*)d_in[18];
    const float* sa_bv     = (const float*)d_in[19];
    const float* sa_wo     = (const float*)d_in[20];
    const float* sa_bo     = (const float*)d_in[21];
    const float* ta_wq     = (const float*)d_in[22];
    const float* ta_bq     = (const float*)d_in[23];
    const float* ta_wk     = (const float*)d_in[24];
    const float* ta_bk     = (const float*)d_in[25];
    const float* ta_wv     = (const float*)d_in[26];
    const float* ta_bv     = (const float*)d_in[27];
    const float* ta_wo     = (const float*)d_in[28];
    const float* ta_bo     = (const float*)d_in[29];
    const float* fc_w      = (const float*)d_in[30];
    const float* fc_b      = (const float*)d_in[31];
    float* out = (float*)d_out;

    int N = in_sizes[0] / (C_ * T_ * V_);

    // ws layout (floats): tab[3200] | tmax[N*V*E] | feat1[N*T*V*E]
    float* ws    = (float*)d_ws;
    float* tab   = ws;
    float* tmax  = ws + 3200;
    float* feat1 = tmax + (size_t)N * V_ * E_;

    k_setup<<<1, 64, 0, stream>>>(je_w, je_b, ve_w, ve_b, joint_emb, frame_emb,
                                  proj_w, proj_b, tab);
    k_spatial<<<N * T_, 64, 0, stream>>>(xj, xv, tab,
                                         gcn_w1, gcn_b1, gcn_w2, gcn_b2,
                                         sa_wq, sa_bq, sa_wk, sa_bk,
                                         sa_wv, sa_bv, sa_wo, sa_bo, feat1);
    k_temporal<<<N * V_, 64, 0, stream>>>(feat1,
                                          ta_wq, ta_bq, ta_wk, ta_bk,
                                          ta_wv, ta_bv, ta_wo, ta_bo, tmax);
    k_pool_fc<<<N, 64, 0, stream>>>(tmax, fc_w, fc_b, out);
}

// Round 9
// 1148.569 us; speedup vs baseline: 11.3994x; 1.0768x over previous
//
#include <hip/hip_runtime.h>
#include <math.h>

#define C_ 3
#define T_ 30
#define V_ 14
#define E_ 64
#define H_ 4
#define D_ 16
#define NC_ 7

#define EP_ 68   // padded row stride for [*,E] LDS tiles (16B-aligned rows)
#define SCV_ 15  // sc/adj row stride, spatial

__device__ __forceinline__ float4 f4_load(const float* p) {
    return *reinterpret_cast<const float4*>(p);
}
__device__ __forceinline__ float4 f4_zero() { return make_float4(0.f, 0.f, 0.f, 0.f); }
__device__ __forceinline__ float4 f4_add(float4 a, float4 b) {
    return make_float4(a.x + b.x, a.y + b.y, a.z + b.z, a.w + b.w);
}
__device__ __forceinline__ float4 f4_fma(float a, float4 b, float4 c) {
    c.x = fmaf(a, b.x, c.x); c.y = fmaf(a, b.y, c.y);
    c.z = fmaf(a, b.z, c.z); c.w = fmaf(a, b.w, c.w); return c;
}
__device__ __forceinline__ float f4_dot(float4 a, float4 b) {
    return a.x * b.x + a.y * b.y + a.z * b.z + a.w * b.w;
}
__device__ __forceinline__ float4 f4_relu(float4 a) {
    return make_float4(fmaxf(a.x, 0.f), fmaxf(a.y, 0.f), fmaxf(a.z, 0.f), fmaxf(a.w, 0.f));
}

// ---------------------------------------------------------------------------
// Setup: collapse the linear front-end into small tables in ws.
// ---------------------------------------------------------------------------
__global__ void k_setup(const float* __restrict__ je_w, const float* __restrict__ je_b,
                        const float* __restrict__ ve_w, const float* __restrict__ ve_b,
                        const float* __restrict__ joint_emb, const float* __restrict__ frame_emb,
                        const float* __restrict__ proj_w, const float* __restrict__ proj_b,
                        float* __restrict__ tab) {
    int e = threadIdx.x;  // 64 threads
    for (int c = 0; c < C_; ++c) {
        float aj = 0.f, av = 0.f;
        for (int i = 0; i < E_; ++i) {
            float p0 = proj_w[i * E_ + e];
            aj += je_w[c * E_ + i] * p0;
            av += ve_w[c * E_ + i] * p0;
        }
        tab[c * E_ + e] = aj;
        tab[192 + c * E_ + e] = av;
    }
    for (int v = 0; v < V_; ++v) {
        float s = 0.f;
        for (int i = 0; i < E_; ++i) s += joint_emb[v * E_ + i] * proj_w[(64 + i) * E_ + e];
        tab[384 + v * E_ + e] = s;
    }
    float bias = proj_b[e];
    for (int i = 0; i < E_; ++i) bias += (je_b[i] + ve_b[i]) * proj_w[i * E_ + e];
    for (int t = 0; t < T_; ++t) {
        float s = bias;
        for (int i = 0; i < E_; ++i) s += frame_emb[t * E_ + i] * proj_w[(128 + i) * E_ + e];
        tab[1280 + t * E_ + e] = s;
    }
}

// ---------------------------------------------------------------------------
// Kernel 1: ONE WAVE per (n,t) tile (unchanged — proven, VGPR 76).
// ---------------------------------------------------------------------------
__global__ __launch_bounds__(64) void k_spatial(
    const float* __restrict__ xj, const float* __restrict__ xv,
    const float* __restrict__ tab,
    const float* __restrict__ w1, const float* __restrict__ b1,
    const float* __restrict__ w2, const float* __restrict__ b2,
    const float* __restrict__ wq, const float* __restrict__ bq,
    const float* __restrict__ wk, const float* __restrict__ bk,
    const float* __restrict__ wv, const float* __restrict__ bv,
    const float* __restrict__ wo, const float* __restrict__ bo,
    float* __restrict__ feat1) {
    int nt = blockIdx.x;
    int n = nt / T_;
    int t = nt % T_;
    int tid = threadIdx.x;      // 0..63
    int l16 = tid & 15;
    int e4 = l16 << 2;
    int r4 = tid >> 4;          // 0..3

    int qr[4], qc[4];
#pragma unroll
    for (int j = 0; j < 4; ++j) {
        qr[j] = r4 + 4 * j;
        qc[j] = (qr[j] < V_) ? qr[j] : 0;
    }

    __shared__ __align__(16) float feat[V_][EP_];
    __shared__ __align__(16) float bufA[V_][EP_];
    __shared__ __align__(16) float bufB[V_][EP_];
    __shared__ float sc[H_][V_][SCV_];
    __shared__ float adj[V_][SCV_];
    __shared__ float xs[2][C_][V_];
    __shared__ float inv_nrm[V_];

    for (int o = tid; o < 2 * C_ * V_; o += 64) {
        int s = o / (C_ * V_);
        int rem = o % (C_ * V_);
        int c = rem / V_, v = rem % V_;
        const float* src = s ? xv : xj;
        xs[s][c][v] = src[((size_t)(n * C_ + c) * T_ + t) * V_ + v];
    }
    __syncthreads();

    // feat build
    {
        float4 F = f4_load(tab + 1280 + t * E_ + e4);
        float4 AJ[C_], AV[C_];
#pragma unroll
        for (int c = 0; c < C_; ++c) {
            AJ[c] = f4_load(tab + c * E_ + e4);
            AV[c] = f4_load(tab + 192 + c * E_ + e4);
        }
#pragma unroll
        for (int j = 0; j < 4; ++j) {
            int q = qr[j];
            if (q < V_) {
                float4 s = f4_add(F, f4_load(tab + 384 + q * E_ + e4));
#pragma unroll
                for (int c = 0; c < C_; ++c) {
                    s = f4_fma(xs[0][c][q], AJ[c], s);
                    s = f4_fma(xs[1][c][q], AV[c], s);
                }
                *(float4*)&feat[q][e4] = s;
            }
        }
    }
    __syncthreads();

    if (tid < V_) {
        float ss = 0.f;
#pragma unroll
        for (int j = 0; j < 16; ++j) { float4 f = f4_load(&feat[tid][4 * j]); ss += f4_dot(f, f); }
        inv_nrm[tid] = 1.0f / fmaxf(sqrtf(ss), 1e-12f);
    }
    __syncthreads();

    for (int o = tid; o < V_ * V_; o += 64) {
        int q = o / V_, k = o % V_;
        float s = 0.f;
#pragma unroll
        for (int j = 0; j < 16; ++j) s += f4_dot(f4_load(&feat[q][4 * j]), f4_load(&feat[k][4 * j]));
        adj[q][k] = s * inv_nrm[q] * inv_nrm[k];
    }
    __syncthreads();
    if (tid < V_) {
        float m = -1e30f;
        for (int k = 0; k < V_; ++k) m = fmaxf(m, adj[tid][k]);
        float sum = 0.f;
        for (int k = 0; k < V_; ++k) { float ex = expf(adj[tid][k] - m); adj[tid][k] = ex; sum += ex; }
        float inv = 1.0f / sum;
        for (int k = 0; k < V_; ++k) adj[tid][k] *= inv;
    }
    __syncthreads();

    {
        float4 acc[4] = {f4_zero(), f4_zero(), f4_zero(), f4_zero()};
#pragma unroll
        for (int k = 0; k < V_; ++k) {
            float4 fv = f4_load(&feat[k][e4]);
#pragma unroll
            for (int j = 0; j < 4; ++j) acc[j] = f4_fma(adj[qc[j]][k], fv, acc[j]);
        }
#pragma unroll
        for (int j = 0; j < 4; ++j) if (qr[j] < V_) *(float4*)&bufA[qr[j]][e4] = acc[j];
    }
    __syncthreads();

    {
        float4 acc[4];
        float4 bb = f4_load(b1 + e4);
#pragma unroll
        for (int j = 0; j < 4; ++j) acc[j] = bb;
        for (int i = 0; i < E_; ++i) {
            float4 w4 = f4_load(w1 + i * E_ + e4);
#pragma unroll
            for (int j = 0; j < 4; ++j) acc[j] = f4_fma(bufA[qc[j]][i], w4, acc[j]);
        }
#pragma unroll
        for (int j = 0; j < 4; ++j) if (qr[j] < V_) *(float4*)&bufB[qr[j]][e4] = f4_relu(acc[j]);
    }
    __syncthreads();

    {
        float4 acc[4];
        float4 bb = f4_load(b2 + e4);
#pragma unroll
        for (int j = 0; j < 4; ++j) acc[j] = bb;
        for (int i = 0; i < E_; ++i) {
            float4 w4 = f4_load(w2 + i * E_ + e4);
#pragma unroll
            for (int j = 0; j < 4; ++j) acc[j] = f4_fma(bufB[qc[j]][i], w4, acc[j]);
        }
#pragma unroll
        for (int j = 0; j < 4; ++j) if (qr[j] < V_) *(float4*)&feat[qr[j]][e4] = acc[j];
    }
    __syncthreads();

    {
        float4 aq[4], ak[4];
        float4 bq4 = f4_load(bq + e4), bk4 = f4_load(bk + e4);
#pragma unroll
        for (int j = 0; j < 4; ++j) { aq[j] = bq4; ak[j] = bk4; }
        for (int i = 0; i < E_; ++i) {
            float4 wq4 = f4_load(wq + i * E_ + e4);
            float4 wk4 = f4_load(wk + i * E_ + e4);
#pragma unroll
            for (int j = 0; j < 4; ++j) {
                float f = feat[qc[j]][i];
                aq[j] = f4_fma(f, wq4, aq[j]);
                ak[j] = f4_fma(f, wk4, ak[j]);
            }
        }
#pragma unroll
        for (int j = 0; j < 4; ++j)
            if (qr[j] < V_) { *(float4*)&bufA[qr[j]][e4] = aq[j]; *(float4*)&bufB[qr[j]][e4] = ak[j]; }
    }
    __syncthreads();

    for (int o = tid; o < H_ * V_ * V_; o += 64) {
        int h = o / (V_ * V_); int r = o % (V_ * V_); int q = r / V_, k = r % V_;
        float s = 0.f;
#pragma unroll
        for (int j = 0; j < 4; ++j)
            s += f4_dot(f4_load(&bufA[q][h * 16 + 4 * j]), f4_load(&bufB[k][h * 16 + 4 * j]));
        sc[h][q][k] = s * 0.25f;  // 1/sqrt(16)
    }
    __syncthreads();
    if (tid < H_ * V_) {
        int h = tid / V_, q = tid % V_;
        float m = -1e30f;
        for (int k = 0; k < V_; ++k) m = fmaxf(m, sc[h][q][k]);
        float sum = 0.f;
        for (int k = 0; k < V_; ++k) { float ex = expf(sc[h][q][k] - m); sc[h][q][k] = ex; sum += ex; }
        float inv = 1.0f / sum;
        for (int k = 0; k < V_; ++k) sc[h][q][k] *= inv;
    }
    __syncthreads();

    {
        float4 av[4];
        float4 bv4 = f4_load(bv + e4);
#pragma unroll
        for (int j = 0; j < 4; ++j) av[j] = bv4;
        for (int i = 0; i < E_; ++i) {
            float4 wv4 = f4_load(wv + i * E_ + e4);
#pragma unroll
            for (int j = 0; j < 4; ++j) av[j] = f4_fma(feat[qc[j]][i], wv4, av[j]);
        }
#pragma unroll
        for (int j = 0; j < 4; ++j) if (qr[j] < V_) *(float4*)&bufA[qr[j]][e4] = av[j];
    }
    __syncthreads();

    {
        int h = l16 >> 2;
        float4 acc[4] = {f4_zero(), f4_zero(), f4_zero(), f4_zero()};
#pragma unroll
        for (int k = 0; k < V_; ++k) {
            float4 v4 = f4_load(&bufA[k][e4]);
#pragma unroll
            for (int j = 0; j < 4; ++j) acc[j] = f4_fma(sc[h][qc[j]][k], v4, acc[j]);
        }
#pragma unroll
        for (int j = 0; j < 4; ++j) if (qr[j] < V_) *(float4*)&bufB[qr[j]][e4] = acc[j];
    }
    __syncthreads();

    {
        float4 acc[4];
        float4 bo4 = f4_load(bo + e4);
#pragma unroll
        for (int j = 0; j < 4; ++j) acc[j] = bo4;
        for (int i = 0; i < E_; ++i) {
            float4 w4 = f4_load(wo + i * E_ + e4);
#pragma unroll
            for (int j = 0; j < 4; ++j) acc[j] = f4_fma(bufB[qc[j]][i], w4, acc[j]);
        }
#pragma unroll
        for (int j = 0; j < 4; ++j)
            if (qr[j] < V_) {
                float4 r = f4_add(acc[j], f4_load(&feat[qr[j]][e4]));
                *(float4*)(feat1 + (size_t)nt * (V_ * E_) + qr[j] * E_ + e4) = r;
            }
    }
}

// ---------------------------------------------------------------------------
// Kernel 2: ONE WAVE per (n,v) tile, head-at-a-time attention (R7 structure),
// plus: merged Q+K projection (4 indep FMA chains, half the ftb LDS reads),
// parallel softmax (2 lanes/row, shfl_xor combine), 1/sqrt(d) folded into exp.
// LDS unchanged: 19328 B -> 8 blocks/CU.
// ---------------------------------------------------------------------------
__global__ __launch_bounds__(64) void k_temporal(
    const float* __restrict__ feat1,
    const float* __restrict__ wq, const float* __restrict__ bq,
    const float* __restrict__ wk, const float* __restrict__ bk,
    const float* __restrict__ wv, const float* __restrict__ bv,
    const float* __restrict__ wo, const float* __restrict__ bo,
    float* __restrict__ tmax) {
    int nv = blockIdx.x;
    int n = nv / V_;
    int v = nv % V_;
    int tid = threadIdx.x;      // 0..63
    int l16 = tid & 15;
    int e4 = l16 << 2;
    int r4 = tid >> 4;          // 0..3

    __shared__ __align__(16) float smem[4832];
    float* ftb = smem;          // [r*68 + c], residual + proj input
    float* Qh  = smem + 2040;   // [r*20 + c], Q rows of head h; later V
    float* KTh = smem + 2640;   // [d*32 + k], K^T of head h
    float* scb = smem + 3152;   // [q*36 + k], scores/probs
    float* pvh = smem + 4232;   // [q*20 + c], PV output of head h

    int tr[8], tc[8];
#pragma unroll
    for (int j = 0; j < 8; ++j) { tr[j] = r4 + 4 * j; tc[j] = (tr[j] < T_) ? tr[j] : 0; }

    // load ft
#pragma unroll
    for (int j = 0; j < 8; ++j)
        if (tr[j] < T_)
            *(float4*)&ftb[tr[j] * EP_ + e4] =
                f4_load(feat1 + (((size_t)n * T_ + tr[j]) * V_ + v) * E_ + e4);
    __syncthreads();

    // persistent O-proj accumulator (rows tr[j], cols e4..e4+3)
    float4 acc_out[8];
    {
        float4 bo4 = f4_load(bo + e4);
#pragma unroll
        for (int j = 0; j < 8; ++j) acc_out[j] = bo4;
    }

    // per-lane mapping for projection phases: (c4 = col-f4 within head, 2 rows)
    int c4 = tid & 3;
    int rs = tid >> 2;          // 0..15
    int row0 = rs, row1 = rs + 16;
    bool r1ok = (row1 < T_);
    int row1c = r1ok ? row1 : 0;

    // softmax mapping: 2 lanes per row, halves of 15
    bool sact = (tid < 2 * T_);
    int sq = sact ? (tid >> 1) : 0;
    int kbase = (tid & 1) * 15;

    for (int h = 0; h < H_; ++h) {
        int hb = h * D_ + 4 * c4;   // global col base for this lane's head slice

        // merged Q+K proj -> Qh, KTh (4 independent chains)
        {
            float4 qa0 = f4_load(bq + hb), qa1 = qa0;
            float4 ka0 = f4_load(bk + hb), ka1 = ka0;
            for (int i = 0; i < E_; ++i) {
                float f0 = ftb[row0 * EP_ + i];
                float f1 = ftb[row1c * EP_ + i];
                float4 wq4 = f4_load(wq + i * E_ + hb);
                float4 wk4 = f4_load(wk + i * E_ + hb);
                qa0 = f4_fma(f0, wq4, qa0); qa1 = f4_fma(f1, wq4, qa1);
                ka0 = f4_fma(f0, wk4, ka0); ka1 = f4_fma(f1, wk4, ka1);
            }
            *(float4*)&Qh[row0 * 20 + 4 * c4] = qa0;
            KTh[(4 * c4 + 0) * 32 + row0] = ka0.x;
            KTh[(4 * c4 + 1) * 32 + row0] = ka0.y;
            KTh[(4 * c4 + 2) * 32 + row0] = ka0.z;
            KTh[(4 * c4 + 3) * 32 + row0] = ka0.w;
            if (r1ok) {
                *(float4*)&Qh[row1 * 20 + 4 * c4] = qa1;
                KTh[(4 * c4 + 0) * 32 + row1] = ka1.x;
                KTh[(4 * c4 + 1) * 32 + row1] = ka1.y;
                KTh[(4 * c4 + 2) * 32 + row1] = ka1.z;
                KTh[(4 * c4 + 3) * 32 + row1] = ka1.w;
            }
        }
        __syncthreads();

        // scores (raw): sc[q][k] = Q[q]·K[k]  (cols 30,31 garbage, never read)
        for (int o = tid; o < 240; o += 64) {
            int q = o >> 3, k4 = o & 7;
            float4 a = f4_zero();
            for (int d = 0; d < D_; ++d)
                a = f4_fma(Qh[q * 20 + d], f4_load(&KTh[d * 32 + 4 * k4]), a);
            *(float4*)&scb[q * 36 + 4 * k4] = a;
        }
        __syncthreads();

        // parallel softmax: 2 lanes per row (halves of 15), 0.25 scale in exp
        {
            float m = -1e30f;
#pragma unroll
            for (int k = 0; k < 15; ++k) m = fmaxf(m, scb[sq * 36 + kbase + k]);
            m = fmaxf(m, __shfl_xor(m, 1));
            float ex[15];
            float su = 0.f;
#pragma unroll
            for (int k = 0; k < 15; ++k) {
                ex[k] = __expf((scb[sq * 36 + kbase + k] - m) * 0.25f);
                su += ex[k];
            }
            su += __shfl_xor(su, 1);
            float iv = 1.f / su;
            if (sact) {
#pragma unroll
                for (int k = 0; k < 15; ++k) scb[sq * 36 + kbase + k] = ex[k] * iv;
            }
        }
        // V-proj -> Qh (Q dead after scores barrier)
        {
            float4 a0 = f4_load(bv + hb), a1 = a0;
            for (int i = 0; i < E_; ++i) {
                float4 w4 = f4_load(wv + i * E_ + hb);
                a0 = f4_fma(ftb[row0 * EP_ + i], w4, a0);
                a1 = f4_fma(ftb[row1c * EP_ + i], w4, a1);
            }
            *(float4*)&Qh[row0 * 20 + 4 * c4] = a0;
            if (r1ok) *(float4*)&Qh[row1 * 20 + 4 * c4] = a1;
        }
        __syncthreads();

        // PV -> pvh: out[q][cc4] = sum_k P[q][k] * V[k][cc4]
        for (int o = tid; o < 120; o += 64) {
            int q = o >> 2, cc = o & 3;
            float4 a = f4_zero();
            for (int k = 0; k < T_; ++k)
                a = f4_fma(scb[q * 36 + k], f4_load(&Qh[k * 20 + 4 * cc]), a);
            *(float4*)&pvh[q * 20 + 4 * cc] = a;
        }
        __syncthreads();

        // partial O-proj: acc_out[j] += sum_hc pvh[tc[j]][hc] * Wo[h*16+hc][e4]
        for (int hc = 0; hc < D_; ++hc) {
            float4 w4 = f4_load(wo + (h * D_ + hc) * E_ + e4);
#pragma unroll
            for (int j = 0; j < 8; ++j)
                acc_out[j] = f4_fma(pvh[tc[j] * 20 + hc], w4, acc_out[j]);
        }
        __syncthreads();   // pvh/Qh/sc reused next round
    }

    // residual + T-max + cross-lane reduce + write
    {
        float4 mx = make_float4(-1e30f, -1e30f, -1e30f, -1e30f);
#pragma unroll
        for (int j = 0; j < 8; ++j) {
            if (tr[j] < T_) {
                float4 r = f4_add(acc_out[j], f4_load(&ftb[tr[j] * EP_ + e4]));
                mx.x = fmaxf(mx.x, r.x); mx.y = fmaxf(mx.y, r.y);
                mx.z = fmaxf(mx.z, r.z); mx.w = fmaxf(mx.w, r.w);
            }
        }
        mx.x = fmaxf(mx.x, __shfl_xor(mx.x, 16));
        mx.y = fmaxf(mx.y, __shfl_xor(mx.y, 16));
        mx.z = fmaxf(mx.z, __shfl_xor(mx.z, 16));
        mx.w = fmaxf(mx.w, __shfl_xor(mx.w, 16));
        mx.x = fmaxf(mx.x, __shfl_xor(mx.x, 32));
        mx.y = fmaxf(mx.y, __shfl_xor(mx.y, 32));
        mx.z = fmaxf(mx.z, __shfl_xor(mx.z, 32));
        mx.w = fmaxf(mx.w, __shfl_xor(mx.w, 32));
        if (r4 == 0) *(float4*)(tmax + (size_t)nv * E_ + e4) = mx;
    }
}

// ---------------------------------------------------------------------------
// Kernel 3: per n — max over V, then FC to 7 classes.
// ---------------------------------------------------------------------------
__global__ void k_pool_fc(const float* __restrict__ tmax,
                          const float* __restrict__ fc_w, const float* __restrict__ fc_b,
                          float* __restrict__ out) {
    int n = blockIdx.x;
    int tid = threadIdx.x;  // 64
    __shared__ float pooled[E_];
    float m = -1e30f;
    for (int v = 0; v < V_; ++v) m = fmaxf(m, tmax[((size_t)n * V_ + v) * E_ + tid]);
    pooled[tid] = m;
    __syncthreads();
    if (tid < NC_) {
        float s = fc_b[tid];
        for (int e = 0; e < E_; ++e) s += pooled[e] * fc_w[e * NC_ + tid];
        out[n * NC_ + tid] = s;
    }
}

extern "C" void kernel_launch(void* const* d_in, const int* in_sizes, int n_in,
                              void* d_out, int out_size, void* d_ws, size_t ws_size,
                              hipStream_t stream) {
    const float* xj        = (const float*)d_in[0];
    const float* xv        = (const float*)d_in[1];
    const float* je_w      = (const float*)d_in[2];
    const float* je_b      = (const float*)d_in[3];
    const float* ve_w      = (const float*)d_in[4];
    const float* ve_b      = (const float*)d_in[5];
    const float* joint_emb = (const float*)d_in[6];
    const float* frame_emb = (const float*)d_in[7];
    const float* proj_w    = (const float*)d_in[8];
    const float* proj_b    = (const float*)d_in[9];
    const float* gcn_w1    = (const float*)d_in[10];
    const float* gcn_b1    = (const float*)d_in[11];
    const float* gcn_w2    = (const float*)d_in[12];
    const float* gcn_b2    = (const float*)d_in[13];
    const float* sa_wq     = (const float*)d_in[14];
    const float* sa_bq     = (const float*)d_in[15];
    const float* sa_wk     = (const float*)d_in[16];
    const float* sa_bk     = (const float*)d_in[17];
    const float* sa_wv     = (const float*)d_in[18];
    const float* sa_bv     = (const float*)d_in[19];
    const float* sa_wo     = (const float*)d_in[20];
    const float* sa_bo     = (const float*)d_in[21];
    const float* ta_wq     = (const float*)d_in[22];
    const float* ta_bq     = (const float*)d_in[23];
    const float* ta_wk     = (const float*)d_in[24];
    const float* ta_bk     = (const float*)d_in[25];
    const float* ta_wv     = (const float*)d_in[26];
    const float* ta_bv     = (const float*)d_in[27];
    const float* ta_wo     = (const float*)d_in[28];
    const float* ta_bo     = (const float*)d_in[29];
    const float* fc_w      = (const float*)d_in[30];
    const float* fc_b      = (const float*)d_in[31];
    float* out = (float*)d_out;

    int N = in_sizes[0] / (C_ * T_ * V_);

    // ws layout (floats): tab[3200] | tmax[N*V*E] | feat1[N*T*V*E]
    float* ws    = (float*)d_ws;
    float* tab   = ws;
    float* tmax  = ws + 3200;
    float* feat1 = tmax + (size_t)N * V_ * E_;

    k_setup<<<1, 64, 0, stream>>>(je_w, je_b, ve_w, ve_b, joint_emb, frame_emb,
                                  proj_w, proj_b, tab);
    k_spatial<<<N * T_, 64, 0, stream>>>(xj, xv, tab,
                                         gcn_w1, gcn_b1, gcn_w2, gcn_b2,
                                         sa_wq, sa_bq, sa_wk, sa_bk,
                                         sa_wv, sa_bv, sa_wo, sa_bo, feat1);
    k_temporal<<<N * V_, 64, 0, stream>>>(feat1,
                                          ta_wq, ta_bq, ta_wk, ta_bk,
                                          ta_wv, ta_bv, ta_wo, ta_bo, tmax);
    k_pool_fc<<<N, 64, 0, stream>>>(tmax, fc_w, fc_b, out);
}

// Round 10
// 843.597 us; speedup vs baseline: 15.5204x; 1.3615x over previous
//
#include <hip/hip_runtime.h>
#include <math.h>

#define C_ 3
#define T_ 30
#define V_ 14
#define E_ 64
#define H_ 4
#define D_ 16
#define NC_ 7

#define EP_ 68   // padded row stride for [*,E] f32 LDS tiles (k_spatial)
#define SCV_ 15  // sc/adj row stride, spatial

typedef unsigned short u16;
typedef __attribute__((ext_vector_type(8))) short bf16x8;   // 8 bf16 = 4 VGPR
typedef __attribute__((ext_vector_type(4))) float f32x4;

__device__ __forceinline__ float4 f4_load(const float* p) {
    return *reinterpret_cast<const float4*>(p);
}
__device__ __forceinline__ float4 f4_zero() { return make_float4(0.f, 0.f, 0.f, 0.f); }
__device__ __forceinline__ float4 f4_add(float4 a, float4 b) {
    return make_float4(a.x + b.x, a.y + b.y, a.z + b.z, a.w + b.w);
}
__device__ __forceinline__ float4 f4_fma(float a, float4 b, float4 c) {
    c.x = fmaf(a, b.x, c.x); c.y = fmaf(a, b.y, c.y);
    c.z = fmaf(a, b.z, c.z); c.w = fmaf(a, b.w, c.w); return c;
}
__device__ __forceinline__ float f4_dot(float4 a, float4 b) {
    return a.x * b.x + a.y * b.y + a.z * b.z + a.w * b.w;
}
__device__ __forceinline__ float4 f4_relu(float4 a) {
    return make_float4(fmaxf(a.x, 0.f), fmaxf(a.y, 0.f), fmaxf(a.z, 0.f), fmaxf(a.w, 0.f));
}
__device__ __forceinline__ u16 f2bf(float x) {   // RTNE f32 -> bf16
    unsigned u = __float_as_uint(x);
    return (u16)((u + 0x7FFFu + ((u >> 16) & 1u)) >> 16);
}

// ---------------------------------------------------------------------------
// Setup: front-end tables + transposed bf16 weights for temporal MHSA.
// ws layout (floats): tab[3200] | wt16: 4 x [64][64] u16 (= 8192 f32 slots)
//   wt16[m][col][i] = bf16(W_m[i][col])  (m: 0=q,1=k,2=v,3=o)
// ---------------------------------------------------------------------------
__global__ void k_setup(const float* __restrict__ je_w, const float* __restrict__ je_b,
                        const float* __restrict__ ve_w, const float* __restrict__ ve_b,
                        const float* __restrict__ joint_emb, const float* __restrict__ frame_emb,
                        const float* __restrict__ proj_w, const float* __restrict__ proj_b,
                        const float* __restrict__ twq, const float* __restrict__ twk,
                        const float* __restrict__ twv, const float* __restrict__ two,
                        float* __restrict__ tab) {
    int e = threadIdx.x;  // 64 threads
    for (int c = 0; c < C_; ++c) {
        float aj = 0.f, av = 0.f;
        for (int i = 0; i < E_; ++i) {
            float p0 = proj_w[i * E_ + e];
            aj += je_w[c * E_ + i] * p0;
            av += ve_w[c * E_ + i] * p0;
        }
        tab[c * E_ + e] = aj;
        tab[192 + c * E_ + e] = av;
    }
    for (int v = 0; v < V_; ++v) {
        float s = 0.f;
        for (int i = 0; i < E_; ++i) s += joint_emb[v * E_ + i] * proj_w[(64 + i) * E_ + e];
        tab[384 + v * E_ + e] = s;
    }
    float bias = proj_b[e];
    for (int i = 0; i < E_; ++i) bias += (je_b[i] + ve_b[i]) * proj_w[i * E_ + e];
    for (int t = 0; t < T_; ++t) {
        float s = bias;
        for (int i = 0; i < E_; ++i) s += frame_emb[t * E_ + i] * proj_w[(128 + i) * E_ + e];
        tab[1280 + t * E_ + e] = s;
    }
    // transposed bf16 weights for MFMA B-fragments
    u16* wt = (u16*)(tab + 3200);
    const float* Ws[4] = {twq, twk, twv, two};
    for (int m = 0; m < 4; ++m) {
        const float* W = Ws[m];
        for (int i = 0; i < E_; ++i)
            wt[m * 4096 + e * 64 + i] = f2bf(W[i * E_ + e]);
    }
}

// ---------------------------------------------------------------------------
// Kernel 1: ONE WAVE per (n,t) tile (unchanged — proven, VGPR 76).
// ---------------------------------------------------------------------------
__global__ __launch_bounds__(64) void k_spatial(
    const float* __restrict__ xj, const float* __restrict__ xv,
    const float* __restrict__ tab,
    const float* __restrict__ w1, const float* __restrict__ b1,
    const float* __restrict__ w2, const float* __restrict__ b2,
    const float* __restrict__ wq, const float* __restrict__ bq,
    const float* __restrict__ wk, const float* __restrict__ bk,
    const float* __restrict__ wv, const float* __restrict__ bv,
    const float* __restrict__ wo, const float* __restrict__ bo,
    float* __restrict__ feat1) {
    int nt = blockIdx.x;
    int n = nt / T_;
    int t = nt % T_;
    int tid = threadIdx.x;      // 0..63
    int l16 = tid & 15;
    int e4 = l16 << 2;
    int r4 = tid >> 4;          // 0..3

    int qr[4], qc[4];
#pragma unroll
    for (int j = 0; j < 4; ++j) {
        qr[j] = r4 + 4 * j;
        qc[j] = (qr[j] < V_) ? qr[j] : 0;
    }

    __shared__ __align__(16) float feat[V_][EP_];
    __shared__ __align__(16) float bufA[V_][EP_];
    __shared__ __align__(16) float bufB[V_][EP_];
    __shared__ float sc[H_][V_][SCV_];
    __shared__ float adj[V_][SCV_];
    __shared__ float xs[2][C_][V_];
    __shared__ float inv_nrm[V_];

    for (int o = tid; o < 2 * C_ * V_; o += 64) {
        int s = o / (C_ * V_);
        int rem = o % (C_ * V_);
        int c = rem / V_, v = rem % V_;
        const float* src = s ? xv : xj;
        xs[s][c][v] = src[((size_t)(n * C_ + c) * T_ + t) * V_ + v];
    }
    __syncthreads();

    // feat build
    {
        float4 F = f4_load(tab + 1280 + t * E_ + e4);
        float4 AJ[C_], AV[C_];
#pragma unroll
        for (int c = 0; c < C_; ++c) {
            AJ[c] = f4_load(tab + c * E_ + e4);
            AV[c] = f4_load(tab + 192 + c * E_ + e4);
        }
#pragma unroll
        for (int j = 0; j < 4; ++j) {
            int q = qr[j];
            if (q < V_) {
                float4 s = f4_add(F, f4_load(tab + 384 + q * E_ + e4));
#pragma unroll
                for (int c = 0; c < C_; ++c) {
                    s = f4_fma(xs[0][c][q], AJ[c], s);
                    s = f4_fma(xs[1][c][q], AV[c], s);
                }
                *(float4*)&feat[q][e4] = s;
            }
        }
    }
    __syncthreads();

    if (tid < V_) {
        float ss = 0.f;
#pragma unroll
        for (int j = 0; j < 16; ++j) { float4 f = f4_load(&feat[tid][4 * j]); ss += f4_dot(f, f); }
        inv_nrm[tid] = 1.0f / fmaxf(sqrtf(ss), 1e-12f);
    }
    __syncthreads();

    for (int o = tid; o < V_ * V_; o += 64) {
        int q = o / V_, k = o % V_;
        float s = 0.f;
#pragma unroll
        for (int j = 0; j < 16; ++j) s += f4_dot(f4_load(&feat[q][4 * j]), f4_load(&feat[k][4 * j]));
        adj[q][k] = s * inv_nrm[q] * inv_nrm[k];
    }
    __syncthreads();
    if (tid < V_) {
        float m = -1e30f;
        for (int k = 0; k < V_; ++k) m = fmaxf(m, adj[tid][k]);
        float sum = 0.f;
        for (int k = 0; k < V_; ++k) { float ex = expf(adj[tid][k] - m); adj[tid][k] = ex; sum += ex; }
        float inv = 1.0f / sum;
        for (int k = 0; k < V_; ++k) adj[tid][k] *= inv;
    }
    __syncthreads();

    {
        float4 acc[4] = {f4_zero(), f4_zero(), f4_zero(), f4_zero()};
#pragma unroll
        for (int k = 0; k < V_; ++k) {
            float4 fv = f4_load(&feat[k][e4]);
#pragma unroll
            for (int j = 0; j < 4; ++j) acc[j] = f4_fma(adj[qc[j]][k], fv, acc[j]);
        }
#pragma unroll
        for (int j = 0; j < 4; ++j) if (qr[j] < V_) *(float4*)&bufA[qr[j]][e4] = acc[j];
    }
    __syncthreads();

    {
        float4 acc[4];
        float4 bb = f4_load(b1 + e4);
#pragma unroll
        for (int j = 0; j < 4; ++j) acc[j] = bb;
        for (int i = 0; i < E_; ++i) {
            float4 w4 = f4_load(w1 + i * E_ + e4);
#pragma unroll
            for (int j = 0; j < 4; ++j) acc[j] = f4_fma(bufA[qc[j]][i], w4, acc[j]);
        }
#pragma unroll
        for (int j = 0; j < 4; ++j) if (qr[j] < V_) *(float4*)&bufB[qr[j]][e4] = f4_relu(acc[j]);
    }
    __syncthreads();

    {
        float4 acc[4];
        float4 bb = f4_load(b2 + e4);
#pragma unroll
        for (int j = 0; j < 4; ++j) acc[j] = bb;
        for (int i = 0; i < E_; ++i) {
            float4 w4 = f4_load(w2 + i * E_ + e4);
#pragma unroll
            for (int j = 0; j < 4; ++j) acc[j] = f4_fma(bufB[qc[j]][i], w4, acc[j]);
        }
#pragma unroll
        for (int j = 0; j < 4; ++j) if (qr[j] < V_) *(float4*)&feat[qr[j]][e4] = acc[j];
    }
    __syncthreads();

    {
        float4 aq[4], ak[4];
        float4 bq4 = f4_load(bq + e4), bk4 = f4_load(bk + e4);
#pragma unroll
        for (int j = 0; j < 4; ++j) { aq[j] = bq4; ak[j] = bk4; }
        for (int i = 0; i < E_; ++i) {
            float4 wq4 = f4_load(wq + i * E_ + e4);
            float4 wk4 = f4_load(wk + i * E_ + e4);
#pragma unroll
            for (int j = 0; j < 4; ++j) {
                float f = feat[qc[j]][i];
                aq[j] = f4_fma(f, wq4, aq[j]);
                ak[j] = f4_fma(f, wk4, ak[j]);
            }
        }
#pragma unroll
        for (int j = 0; j < 4; ++j)
            if (qr[j] < V_) { *(float4*)&bufA[qr[j]][e4] = aq[j]; *(float4*)&bufB[qr[j]][e4] = ak[j]; }
    }
    __syncthreads();

    for (int o = tid; o < H_ * V_ * V_; o += 64) {
        int h = o / (V_ * V_); int r = o % (V_ * V_); int q = r / V_, k = r % V_;
        float s = 0.f;
#pragma unroll
        for (int j = 0; j < 4; ++j)
            s += f4_dot(f4_load(&bufA[q][h * 16 + 4 * j]), f4_load(&bufB[k][h * 16 + 4 * j]));
        sc[h][q][k] = s * 0.25f;  // 1/sqrt(16)
    }
    __syncthreads();
    if (tid < H_ * V_) {
        int h = tid / V_, q = tid % V_;
        float m = -1e30f;
        for (int k = 0; k < V_; ++k) m = fmaxf(m, sc[h][q][k]);
        float sum = 0.f;
        for (int k = 0; k < V_; ++k) { float ex = expf(sc[h][q][k] - m); sc[h][q][k] = ex; sum += ex; }
        float inv = 1.0f / sum;
        for (int k = 0; k < V_; ++k) sc[h][q][k] *= inv;
    }
    __syncthreads();

    {
        float4 av[4];
        float4 bv4 = f4_load(bv + e4);
#pragma unroll
        for (int j = 0; j < 4; ++j) av[j] = bv4;
        for (int i = 0; i < E_; ++i) {
            float4 wv4 = f4_load(wv + i * E_ + e4);
#pragma unroll
            for (int j = 0; j < 4; ++j) av[j] = f4_fma(feat[qc[j]][i], wv4, av[j]);
        }
#pragma unroll
        for (int j = 0; j < 4; ++j) if (qr[j] < V_) *(float4*)&bufA[qr[j]][e4] = av[j];
    }
    __syncthreads();

    {
        int h = l16 >> 2;
        float4 acc[4] = {f4_zero(), f4_zero(), f4_zero(), f4_zero()};
#pragma unroll
        for (int k = 0; k < V_; ++k) {
            float4 v4 = f4_load(&bufA[k][e4]);
#pragma unroll
            for (int j = 0; j < 4; ++j) acc[j] = f4_fma(sc[h][qc[j]][k], v4, acc[j]);
        }
#pragma unroll
        for (int j = 0; j < 4; ++j) if (qr[j] < V_) *(float4*)&bufB[qr[j]][e4] = acc[j];
    }
    __syncthreads();

    {
        float4 acc[4];
        float4 bo4 = f4_load(bo + e4);
#pragma unroll
        for (int j = 0; j < 4; ++j) acc[j] = bo4;
        for (int i = 0; i < E_; ++i) {
            float4 w4 = f4_load(wo + i * E_ + e4);
#pragma unroll
            for (int j = 0; j < 4; ++j) acc[j] = f4_fma(bufB[qc[j]][i], w4, acc[j]);
        }
#pragma unroll
        for (int j = 0; j < 4; ++j)
            if (qr[j] < V_) {
                float4 r = f4_add(acc[j], f4_load(&feat[qr[j]][e4]));
                *(float4*)(feat1 + (size_t)nt * (V_ * E_) + qr[j] * E_ + e4) = r;
            }
    }
}

// ---------------------------------------------------------------------------
// Kernel 2: ONE WAVE per (n,v) tile. Q/K/V/O projections via MFMA bf16
// (16x16x32), scores/softmax/PV stay f32 in LDS (R9-proven).
// LDS (floats): ft16 bf16[32][72] (1152) | ao16 bf16[32][72] (1152) |
//   Qh[30][20] (600) | KTh[16][36] (576) | Vh[30][16] (480) | scb[30][36] (1080)
// = 5040 floats = 20160 B -> 8 blocks/CU.
// A/B frag layout: A row=l%16, k=(l/16)*8+j (contig); B col=l%16, same k
// (via pre-transposed bf16 weights). C/D: col=l&15, row=(l>>4)*4+reg [m89].
// ---------------------------------------------------------------------------
__global__ __launch_bounds__(64) void k_temporal(
    const float* __restrict__ feat1,
    const u16* __restrict__ wt16,
    const float* __restrict__ bq, const float* __restrict__ bk,
    const float* __restrict__ bv, const float* __restrict__ bo,
    float* __restrict__ tmax) {
    int nv = blockIdx.x;
    int n = nv / V_;
    int v = nv % V_;
    int tid = threadIdx.x;      // 0..63
    int dcol = tid & 15;        // C/D column; also frag row/col select
    int kgrp = tid >> 4;        // 0..3: k-block of A/B frags; C row-group
    int trow4 = kgrp * 4;       // C row base within 16-tile

    const u16* wtq = wt16;
    const u16* wtk = wt16 + 4096;
    const u16* wtv = wt16 + 8192;
    const u16* wto = wt16 + 12288;

    __shared__ __align__(16) float smem[5040];
    u16*  ft16 = (u16*)&smem[0];       // [32][72] bf16 (rows 30,31 garbage, discarded)
    u16*  ao16 = (u16*)&smem[1152];    // [32][72] bf16 attn-out
    float* Qh  = &smem[2304];          // [30][20]
    float* KTh = &smem[2904];          // [16][36] (K transposed)
    float* Vh  = &smem[3480];          // [30][16]
    float* scb = &smem[3960];          // [30][36]

    const float* fsrc = feat1 + ((size_t)n * T_ * V_ + v) * E_;   // row t at +t*V_*E_

    // 1) build ft16 (bf16 copy of this tile's feat rows)
    for (int o = tid; o < T_ * 16; o += 64) {
        int t = o >> 4, c4i = (o & 15) << 2;
        float4 f = f4_load(fsrc + (size_t)t * V_ * E_ + c4i);
        unsigned lo = (unsigned)f2bf(f.x) | ((unsigned)f2bf(f.y) << 16);
        unsigned hi = (unsigned)f2bf(f.z) | ((unsigned)f2bf(f.w) << 16);
        *(uint2*)&ft16[t * 72 + c4i] = make_uint2(lo, hi);
    }
    __syncthreads();

    // 2) A-fragments of ft (persistent; same for all heads)
    bf16x8 af[2][2];
#pragma unroll
    for (int mt = 0; mt < 2; ++mt)
#pragma unroll
        for (int ks = 0; ks < 2; ++ks)
            af[mt][ks] = *(bf16x8*)&ft16[(mt * 16 + dcol) * 72 + ks * 32 + kgrp * 8];

    // softmax mapping: 2 lanes per row, halves of 15
    bool sact = (tid < 2 * T_);
    int sq = sact ? (tid >> 1) : 0;
    int kbase = (tid & 1) * 15;

    for (int h = 0; h < H_; ++h) {
        // --- Q/K/V projections via MFMA ---
        {
            float bqs = bq[h * D_ + dcol];
            float bks = bk[h * D_ + dcol];
            float bvs = bv[h * D_ + dcol];
            f32x4 qacc[2], kacc[2], vacc[2];
#pragma unroll
            for (int mt = 0; mt < 2; ++mt) {
                qacc[mt] = (f32x4){bqs, bqs, bqs, bqs};
                kacc[mt] = (f32x4){bks, bks, bks, bks};
                vacc[mt] = (f32x4){bvs, bvs, bvs, bvs};
            }
#pragma unroll
            for (int ks = 0; ks < 2; ++ks) {
                int boff = (h * D_ + dcol) * 64 + ks * 32 + kgrp * 8;
                bf16x8 b_q = *(const bf16x8*)&wtq[boff];
                bf16x8 b_k = *(const bf16x8*)&wtk[boff];
                bf16x8 b_v = *(const bf16x8*)&wtv[boff];
#pragma unroll
                for (int mt = 0; mt < 2; ++mt) {
                    qacc[mt] = __builtin_amdgcn_mfma_f32_16x16x32_bf16(af[mt][ks], b_q, qacc[mt], 0, 0, 0);
                    kacc[mt] = __builtin_amdgcn_mfma_f32_16x16x32_bf16(af[mt][ks], b_k, kacc[mt], 0, 0, 0);
                    vacc[mt] = __builtin_amdgcn_mfma_f32_16x16x32_bf16(af[mt][ks], b_v, vacc[mt], 0, 0, 0);
                }
            }
#pragma unroll
            for (int mt = 0; mt < 2; ++mt)
#pragma unroll
                for (int r = 0; r < 4; ++r) {
                    int t = mt * 16 + trow4 + r;
                    if (t < T_) {
                        Qh[t * 20 + dcol] = qacc[mt][r];
                        KTh[dcol * 36 + t] = kacc[mt][r];
                        Vh[t * 16 + dcol] = vacc[mt][r];
                    }
                }
        }
        __syncthreads();

        // --- scores (raw): scb[q][k] = Q[q]·K[k] ---
        for (int o = tid; o < 240; o += 64) {
            int q = o >> 3, k4 = o & 7;
            float4 a = f4_zero();
#pragma unroll
            for (int d = 0; d < D_; ++d)
                a = f4_fma(Qh[q * 20 + d], f4_load(&KTh[d * 36 + 4 * k4]), a);
            *(float4*)&scb[q * 36 + 4 * k4] = a;
        }
        __syncthreads();

        // --- parallel softmax (0.25 scale folded into exp) ---
        {
            float m = -1e30f;
#pragma unroll
            for (int k = 0; k < 15; ++k) m = fmaxf(m, scb[sq * 36 + kbase + k]);
            m = fmaxf(m, __shfl_xor(m, 1));
            float ex[15];
            float su = 0.f;
#pragma unroll
            for (int k = 0; k < 15; ++k) {
                ex[k] = __expf((scb[sq * 36 + kbase + k] - m) * 0.25f);
                su += ex[k];
            }
            su += __shfl_xor(su, 1);
            float iv = 1.f / su;
            if (sact) {
#pragma unroll
                for (int k = 0; k < 15; ++k) scb[sq * 36 + kbase + k] = ex[k] * iv;
            }
        }
        __syncthreads();

        // --- PV -> ao16 (bf16) ---
        for (int o = tid; o < 120; o += 64) {
            int q = o >> 2, cc = o & 3;
            float4 a = f4_zero();
#pragma unroll
            for (int k = 0; k < T_; ++k)
                a = f4_fma(scb[q * 36 + k], f4_load(&Vh[k * 16 + 4 * cc]), a);
            unsigned lo = (unsigned)f2bf(a.x) | ((unsigned)f2bf(a.y) << 16);
            unsigned hi = (unsigned)f2bf(a.z) | ((unsigned)f2bf(a.w) << 16);
            *(uint2*)&ao16[q * 72 + h * D_ + 4 * cc] = make_uint2(lo, hi);
        }
        __syncthreads();   // next head reuses Qh/KTh/Vh; ao16 slice done
    }

    // --- O projection via MFMA + residual + T-max ---
    {
        bf16x8 oa[2][2];
#pragma unroll
        for (int mt = 0; mt < 2; ++mt)
#pragma unroll
            for (int ks = 0; ks < 2; ++ks)
                oa[mt][ks] = *(bf16x8*)&ao16[(mt * 16 + dcol) * 72 + ks * 32 + kgrp * 8];

        float mxc[4];
#pragma unroll
        for (int nt = 0; nt < 4; ++nt) {
            float bos = bo[nt * 16 + dcol];
            f32x4 oacc[2];
            oacc[0] = (f32x4){bos, bos, bos, bos};
            oacc[1] = oacc[0];
#pragma unroll
            for (int ks = 0; ks < 2; ++ks) {
                bf16x8 bb = *(const bf16x8*)&wto[(nt * 16 + dcol) * 64 + ks * 32 + kgrp * 8];
#pragma unroll
                for (int mt = 0; mt < 2; ++mt)
                    oacc[mt] = __builtin_amdgcn_mfma_f32_16x16x32_bf16(oa[mt][ks], bb, oacc[mt], 0, 0, 0);
            }
            float m = -1e30f;
#pragma unroll
            for (int mt = 0; mt < 2; ++mt)
#pragma unroll
                for (int r = 0; r < 4; ++r) {
                    int t = mt * 16 + trow4 + r;
                    if (t < T_) {
                        float rr = oacc[mt][r] +
                                   fsrc[(size_t)t * V_ * E_ + nt * 16 + dcol];
                        m = fmaxf(m, rr);
                    }
                }
            mxc[nt] = m;
        }
#pragma unroll
        for (int nt = 0; nt < 4; ++nt) {
            mxc[nt] = fmaxf(mxc[nt], __shfl_xor(mxc[nt], 16));
            mxc[nt] = fmaxf(mxc[nt], __shfl_xor(mxc[nt], 32));
        }
        if (tid < 16) {
#pragma unroll
            for (int nt = 0; nt < 4; ++nt)
                tmax[(size_t)nv * E_ + nt * 16 + tid] = mxc[nt];
        }
    }
}

// ---------------------------------------------------------------------------
// Kernel 3: per n — max over V, then FC to 7 classes.
// ---------------------------------------------------------------------------
__global__ void k_pool_fc(const float* __restrict__ tmax,
                          const float* __restrict__ fc_w, const float* __restrict__ fc_b,
                          float* __restrict__ out) {
    int n = blockIdx.x;
    int tid = threadIdx.x;  // 64
    __shared__ float pooled[E_];
    float m = -1e30f;
    for (int v = 0; v < V_; ++v) m = fmaxf(m, tmax[((size_t)n * V_ + v) * E_ + tid]);
    pooled[tid] = m;
    __syncthreads();
    if (tid < NC_) {
        float s = fc_b[tid];
        for (int e = 0; e < E_; ++e) s += pooled[e] * fc_w[e * NC_ + tid];
        out[n * NC_ + tid] = s;
    }
}

extern "C" void kernel_launch(void* const* d_in, const int* in_sizes, int n_in,
                              void* d_out, int out_size, void* d_ws, size_t ws_size,
                              hipStream_t stream) {
    const float* xj        = (const float*)d_in[0];
    const float* xv        = (const float*)d_in[1];
    const float* je_w      = (const float*)d_in[2];
    const float* je_b      = (const float*)d_in[3];
    const float* ve_w      = (const float*)d_in[4];
    const float* ve_b      = (const float*)d_in[5];
    const float* joint_emb = (const float*)d_in[6];
    const float* frame_emb = (const float*)d_in[7];
    const float* proj_w    = (const float*)d_in[8];
    const float* proj_b    = (const float*)d_in[9];
    const float* gcn_w1    = (const float*)d_in[10];
    const float* gcn_b1    = (const float*)d_in[11];
    const float* gcn_w2    = (const float*)d_in[12];
    const float* gcn_b2    = (const float*)d_in[13];
    const float* sa_wq     = (const float*)d_in[14];
    const float* sa_bq     = (const float*)d_in[15];
    const float* sa_wk     = (const float*)d_in[16];
    const float* sa_bk     = (const float*)d_in[17];
    const float* sa_wv     = (const float*)d_in[18];
    const float* sa_bv     = (const float*)d_in[19];
    const float* sa_wo     = (const float*)d_in[20];
    const float* sa_bo     = (const float*)d_in[21];
    const float* ta_wq     = (const float*)d_in[22];
    const float* ta_bq     = (const float*)d_in[23];
    const float* ta_wk     = (const float*)d_in[24];
    const float* ta_bk     = (const float*)d_in[25];
    const float* ta_wv     = (const float*)d_in[26];
    const float* ta_bv     = (const float*)d_in[27];
    const float* ta_wo     = (const float*)d_in[28];
    const float* ta_bo     = (const float*)d_in[29];
    const float* fc_w      = (const float*)d_in[30];
    const float* fc_b      = (const float*)d_in[31];
    float* out = (float*)d_out;

    int N = in_sizes[0] / (C_ * T_ * V_);

    // ws layout (floats): tab[3200] | wt16 (8192 f32 slots) | tmax[N*V*E] | feat1[N*T*V*E]
    float* ws    = (float*)d_ws;
    float* tab   = ws;
    u16*   wt16  = (u16*)(ws + 3200);
    float* tmax  = ws + 3200 + 8192;
    float* feat1 = tmax + (size_t)N * V_ * E_;

    k_setup<<<1, 64, 0, stream>>>(je_w, je_b, ve_w, ve_b, joint_emb, frame_emb,
                                  proj_w, proj_b, ta_wq, ta_wk, ta_wv, ta_wo, tab);
    k_spatial<<<N * T_, 64, 0, stream>>>(xj, xv, tab,
                                         gcn_w1, gcn_b1, gcn_w2, gcn_b2,
                                         sa_wq, sa_bq, sa_wk, sa_bk,
                                         sa_wv, sa_bv, sa_wo, sa_bo, feat1);
    k_temporal<<<N * V_, 64, 0, stream>>>(feat1, wt16,
                                          ta_bq, ta_bk, ta_bv, ta_bo, tmax);
    k_pool_fc<<<N, 64, 0, stream>>>(tmax, fc_w, fc_b, out);
}

// Round 11
// 697.436 us; speedup vs baseline: 18.7730x; 1.2096x over previous
//
#include <hip/hip_runtime.h>
#include <math.h>

#define C_ 3
#define T_ 30
#define V_ 14
#define E_ 64
#define H_ 4
#define D_ 16
#define NC_ 7

#define EP_ 68   // padded row stride for [*,E] f32 LDS tiles
#define SCV_ 15  // sc/adj row stride, spatial
#define SW_ 72   // u16 row stride of bf16 staging tiles

typedef unsigned short u16;
typedef __attribute__((ext_vector_type(8))) short bf16x8;   // 8 bf16 = 4 VGPR
typedef __attribute__((ext_vector_type(4))) float f32x4;

__device__ __forceinline__ float4 f4_load(const float* p) {
    return *reinterpret_cast<const float4*>(p);
}
__device__ __forceinline__ float4 f4_zero() { return make_float4(0.f, 0.f, 0.f, 0.f); }
__device__ __forceinline__ float4 f4_add(float4 a, float4 b) {
    return make_float4(a.x + b.x, a.y + b.y, a.z + b.z, a.w + b.w);
}
__device__ __forceinline__ float4 f4_fma(float a, float4 b, float4 c) {
    c.x = fmaf(a, b.x, c.x); c.y = fmaf(a, b.y, c.y);
    c.z = fmaf(a, b.z, c.z); c.w = fmaf(a, b.w, c.w); return c;
}
__device__ __forceinline__ float f4_dot(float4 a, float4 b) {
    return a.x * b.x + a.y * b.y + a.z * b.z + a.w * b.w;
}
__device__ __forceinline__ u16 f2bf(float x) {   // RTNE f32 -> bf16
    unsigned u = __float_as_uint(x);
    return (u16)((u + 0x7FFFu + ((u >> 16) & 1u)) >> 16);
}
__device__ __forceinline__ uint2 pack4bf(float4 f) {
    return make_uint2((unsigned)f2bf(f.x) | ((unsigned)f2bf(f.y) << 16),
                      (unsigned)f2bf(f.z) | ((unsigned)f2bf(f.w) << 16));
}

// ---------------------------------------------------------------------------
// Setup: front-end tables + 10 transposed bf16 weight matrices.
// wt16[m][col][i] = bf16(W_m[i][col]); m: 0..3 = ta q/k/v/o,
// 4..9 = sa w1,w2,wq,wk,wv,wo.
// ---------------------------------------------------------------------------
__global__ void k_setup(const float* __restrict__ je_w, const float* __restrict__ je_b,
                        const float* __restrict__ ve_w, const float* __restrict__ ve_b,
                        const float* __restrict__ joint_emb, const float* __restrict__ frame_emb,
                        const float* __restrict__ proj_w, const float* __restrict__ proj_b,
                        const float* __restrict__ twq, const float* __restrict__ twk,
                        const float* __restrict__ twv, const float* __restrict__ two,
                        const float* __restrict__ sw1, const float* __restrict__ sw2,
                        const float* __restrict__ swq, const float* __restrict__ swk,
                        const float* __restrict__ swv, const float* __restrict__ swo,
                        float* __restrict__ tab) {
    int e = threadIdx.x;  // 64 threads
    for (int c = 0; c < C_; ++c) {
        float aj = 0.f, av = 0.f;
        for (int i = 0; i < E_; ++i) {
            float p0 = proj_w[i * E_ + e];
            aj += je_w[c * E_ + i] * p0;
            av += ve_w[c * E_ + i] * p0;
        }
        tab[c * E_ + e] = aj;
        tab[192 + c * E_ + e] = av;
    }
    for (int v = 0; v < V_; ++v) {
        float s = 0.f;
        for (int i = 0; i < E_; ++i) s += joint_emb[v * E_ + i] * proj_w[(64 + i) * E_ + e];
        tab[384 + v * E_ + e] = s;
    }
    float bias = proj_b[e];
    for (int i = 0; i < E_; ++i) bias += (je_b[i] + ve_b[i]) * proj_w[i * E_ + e];
    for (int t = 0; t < T_; ++t) {
        float s = bias;
        for (int i = 0; i < E_; ++i) s += frame_emb[t * E_ + i] * proj_w[(128 + i) * E_ + e];
        tab[1280 + t * E_ + e] = s;
    }
    u16* wt = (u16*)(tab + 3200);
    const float* Ws[10] = {twq, twk, twv, two, sw1, sw2, swq, swk, swv, swo};
    for (int m = 0; m < 10; ++m) {
        const float* W = Ws[m];
        for (int i = 0; i < E_; ++i)
            wt[m * 4096 + e * 64 + i] = f2bf(W[i * E_ + e]);
    }
}

// ---------------------------------------------------------------------------
// Kernel 1: ONE WAVE per (n,t) tile. GCN + MHSA dense GEMMs via MFMA bf16;
// feat build / cosine adjacency / scores / softmax / PV stay f32.
// A-frag: row=lane&15, k=(lane>>4)*8+j; B-frag: col=lane&15 (pre-transposed W);
// C/D: col=lane&15, row=(lane>>4)*4+reg  [verified m89 / R10].
// ---------------------------------------------------------------------------
__global__ __launch_bounds__(64) void k_spatial(
    const float* __restrict__ xj, const float* __restrict__ xv,
    const float* __restrict__ tab, const u16* __restrict__ wt16,
    const float* __restrict__ b1, const float* __restrict__ b2,
    const float* __restrict__ bq, const float* __restrict__ bk,
    const float* __restrict__ bv, const float* __restrict__ bo,
    float* __restrict__ feat1) {
    int ntb = blockIdx.x;
    int n = ntb / T_;
    int t = ntb % T_;
    int tid = threadIdx.x;      // 0..63
    int l16 = tid & 15;
    int e4 = l16 << 2;
    int r4 = tid >> 4;          // 0..3
    int dcol = l16;             // MFMA C/D col, A row, B col
    int kgrp = r4;              // MFMA k-group; C row-group
    int trow4 = kgrp * 4;

    const u16* w1T = wt16 + 4 * 4096;
    const u16* w2T = wt16 + 5 * 4096;
    const u16* wqT = wt16 + 6 * 4096;
    const u16* wkT = wt16 + 7 * 4096;
    const u16* wvT = wt16 + 8 * 4096;
    const u16* woT = wt16 + 9 * 4096;

    int qr[4], qc[4];
#pragma unroll
    for (int j = 0; j < 4; ++j) {
        qr[j] = r4 + 4 * j;
        qc[j] = (qr[j] < V_) ? qr[j] : 0;
    }

    __shared__ __align__(16) float feat[V_][EP_];
    __shared__ __align__(16) float bufA[V_][EP_];
    __shared__ __align__(16) float bufB[V_][EP_];
    __shared__ float sc[H_][V_][SCV_];
    __shared__ float adj[V_][SCV_];
    __shared__ float xs[2][C_][V_];
    __shared__ float inv_nrm[V_];
    __shared__ __align__(16) u16 stA[16 * SW_];
    __shared__ __align__(16) u16 stB[16 * SW_];

    for (int o = tid; o < 2 * C_ * V_; o += 64) {
        int s = o / (C_ * V_);
        int rem = o % (C_ * V_);
        int c = rem / V_, v = rem % V_;
        const float* src = s ? xv : xj;
        xs[s][c][v] = src[((size_t)(n * C_ + c) * T_ + t) * V_ + v];
    }
    __syncthreads();

    // feat build (f32)
    {
        float4 F = f4_load(tab + 1280 + t * E_ + e4);
        float4 AJ[C_], AV[C_];
#pragma unroll
        for (int c = 0; c < C_; ++c) {
            AJ[c] = f4_load(tab + c * E_ + e4);
            AV[c] = f4_load(tab + 192 + c * E_ + e4);
        }
#pragma unroll
        for (int j = 0; j < 4; ++j) {
            int q = qr[j];
            if (q < V_) {
                float4 s = f4_add(F, f4_load(tab + 384 + q * E_ + e4));
#pragma unroll
                for (int c = 0; c < C_; ++c) {
                    s = f4_fma(xs[0][c][q], AJ[c], s);
                    s = f4_fma(xs[1][c][q], AV[c], s);
                }
                *(float4*)&feat[q][e4] = s;
            }
        }
    }
    __syncthreads();

    // row inverse norms + cosine adjacency + softmax (f32, unchanged)
    if (tid < V_) {
        float ss = 0.f;
#pragma unroll
        for (int j = 0; j < 16; ++j) { float4 f = f4_load(&feat[tid][4 * j]); ss += f4_dot(f, f); }
        inv_nrm[tid] = 1.0f / fmaxf(sqrtf(ss), 1e-12f);
    }
    __syncthreads();
    for (int o = tid; o < V_ * V_; o += 64) {
        int q = o / V_, k = o % V_;
        float s = 0.f;
#pragma unroll
        for (int j = 0; j < 16; ++j) s += f4_dot(f4_load(&feat[q][4 * j]), f4_load(&feat[k][4 * j]));
        adj[q][k] = s * inv_nrm[q] * inv_nrm[k];
    }
    __syncthreads();
    if (tid < V_) {
        float m = -1e30f;
        for (int k = 0; k < V_; ++k) m = fmaxf(m, adj[tid][k]);
        float sum = 0.f;
        for (int k = 0; k < V_; ++k) { float ex = expf(adj[tid][k] - m); adj[tid][k] = ex; sum += ex; }
        float inv = 1.0f / sum;
        for (int k = 0; k < V_; ++k) adj[tid][k] *= inv;
    }
    __syncthreads();

    // adj@feat (f32) -> stA bf16 (input to W1 MFMA)
    {
        float4 acc[4] = {f4_zero(), f4_zero(), f4_zero(), f4_zero()};
#pragma unroll
        for (int k = 0; k < V_; ++k) {
            float4 fv = f4_load(&feat[k][e4]);
#pragma unroll
            for (int j = 0; j < 4; ++j) acc[j] = f4_fma(adj[qc[j]][k], fv, acc[j]);
        }
#pragma unroll
        for (int j = 0; j < 4; ++j)
            if (qr[j] < V_) *(uint2*)&stA[qr[j] * SW_ + e4] = pack4bf(acc[j]);
    }
    __syncthreads();

    // W1 MFMA + relu -> stB bf16
    {
        bf16x8 a0 = *(bf16x8*)&stA[dcol * SW_ + kgrp * 8];
        bf16x8 a1 = *(bf16x8*)&stA[dcol * SW_ + 32 + kgrp * 8];
#pragma unroll
        for (int nt = 0; nt < 4; ++nt) {
            int col = nt * 16 + dcol;
            float bb = b1[col];
            f32x4 cc = (f32x4){bb, bb, bb, bb};
            cc = __builtin_amdgcn_mfma_f32_16x16x32_bf16(a0, *(const bf16x8*)&w1T[col * 64 + kgrp * 8], cc, 0, 0, 0);
            cc = __builtin_amdgcn_mfma_f32_16x16x32_bf16(a1, *(const bf16x8*)&w1T[col * 64 + 32 + kgrp * 8], cc, 0, 0, 0);
#pragma unroll
            for (int r = 0; r < 4; ++r) {
                int row = trow4 + r;
                if (row < V_) stB[row * SW_ + col] = f2bf(fmaxf(cc[r], 0.f));
            }
        }
    }
    __syncthreads();

    // W2 MFMA -> feat (f32 residual base) + stA bf16 (q/k/v input)
    {
        bf16x8 a0 = *(bf16x8*)&stB[dcol * SW_ + kgrp * 8];
        bf16x8 a1 = *(bf16x8*)&stB[dcol * SW_ + 32 + kgrp * 8];
#pragma unroll
        for (int nt = 0; nt < 4; ++nt) {
            int col = nt * 16 + dcol;
            float bb = b2[col];
            f32x4 cc = (f32x4){bb, bb, bb, bb};
            cc = __builtin_amdgcn_mfma_f32_16x16x32_bf16(a0, *(const bf16x8*)&w2T[col * 64 + kgrp * 8], cc, 0, 0, 0);
            cc = __builtin_amdgcn_mfma_f32_16x16x32_bf16(a1, *(const bf16x8*)&w2T[col * 64 + 32 + kgrp * 8], cc, 0, 0, 0);
#pragma unroll
            for (int r = 0; r < 4; ++r) {
                int row = trow4 + r;
                if (row < V_) {
                    feat[row][col] = cc[r];
                    stA[row * SW_ + col] = f2bf(cc[r]);
                }
            }
        }
    }
    __syncthreads();

    // Q,K MFMA from stA (A-frags kept live for V later)
    bf16x8 af0 = *(bf16x8*)&stA[dcol * SW_ + kgrp * 8];
    bf16x8 af1 = *(bf16x8*)&stA[dcol * SW_ + 32 + kgrp * 8];
    {
#pragma unroll
        for (int nt = 0; nt < 4; ++nt) {
            int col = nt * 16 + dcol;
            float bqs = bq[col], bks = bk[col];
            f32x4 cq = (f32x4){bqs, bqs, bqs, bqs};
            f32x4 ck = (f32x4){bks, bks, bks, bks};
            cq = __builtin_amdgcn_mfma_f32_16x16x32_bf16(af0, *(const bf16x8*)&wqT[col * 64 + kgrp * 8], cq, 0, 0, 0);
            cq = __builtin_amdgcn_mfma_f32_16x16x32_bf16(af1, *(const bf16x8*)&wqT[col * 64 + 32 + kgrp * 8], cq, 0, 0, 0);
            ck = __builtin_amdgcn_mfma_f32_16x16x32_bf16(af0, *(const bf16x8*)&wkT[col * 64 + kgrp * 8], ck, 0, 0, 0);
            ck = __builtin_amdgcn_mfma_f32_16x16x32_bf16(af1, *(const bf16x8*)&wkT[col * 64 + 32 + kgrp * 8], ck, 0, 0, 0);
#pragma unroll
            for (int r = 0; r < 4; ++r) {
                int row = trow4 + r;
                if (row < V_) { bufA[row][col] = cq[r]; bufB[row][col] = ck[r]; }
            }
        }
    }
    __syncthreads();

    // per-head scores (f32, unchanged)
    for (int o = tid; o < H_ * V_ * V_; o += 64) {
        int h = o / (V_ * V_); int r = o % (V_ * V_); int q = r / V_, k = r % V_;
        float s = 0.f;
#pragma unroll
        for (int j = 0; j < 4; ++j)
            s += f4_dot(f4_load(&bufA[q][h * 16 + 4 * j]), f4_load(&bufB[k][h * 16 + 4 * j]));
        sc[h][q][k] = s * 0.25f;  // 1/sqrt(16)
    }
    __syncthreads();
    if (tid < H_ * V_) {
        int h = tid / V_, q = tid % V_;
        float m = -1e30f;
        for (int k = 0; k < V_; ++k) m = fmaxf(m, sc[h][q][k]);
        float sum = 0.f;
        for (int k = 0; k < V_; ++k) { float ex = expf(sc[h][q][k] - m); sc[h][q][k] = ex; sum += ex; }
        float inv = 1.0f / sum;
        for (int k = 0; k < V_; ++k) sc[h][q][k] *= inv;
    }
    __syncthreads();

    // V MFMA (reuses af regs) -> bufA (q dead)
    {
#pragma unroll
        for (int nt = 0; nt < 4; ++nt) {
            int col = nt * 16 + dcol;
            float bvs = bv[col];
            f32x4 cv = (f32x4){bvs, bvs, bvs, bvs};
            cv = __builtin_amdgcn_mfma_f32_16x16x32_bf16(af0, *(const bf16x8*)&wvT[col * 64 + kgrp * 8], cv, 0, 0, 0);
            cv = __builtin_amdgcn_mfma_f32_16x16x32_bf16(af1, *(const bf16x8*)&wvT[col * 64 + 32 + kgrp * 8], cv, 0, 0, 0);
#pragma unroll
            for (int r = 0; r < 4; ++r) {
                int row = trow4 + r;
                if (row < V_) bufA[row][col] = cv[r];
            }
        }
    }
    __syncthreads();

    // PV (f32) -> stB bf16
    {
        int h = l16 >> 2;
        float4 acc[4] = {f4_zero(), f4_zero(), f4_zero(), f4_zero()};
#pragma unroll
        for (int k = 0; k < V_; ++k) {
            float4 v4 = f4_load(&bufA[k][e4]);
#pragma unroll
            for (int j = 0; j < 4; ++j) acc[j] = f4_fma(sc[h][qc[j]][k], v4, acc[j]);
        }
#pragma unroll
        for (int j = 0; j < 4; ++j)
            if (qr[j] < V_) *(uint2*)&stB[qr[j] * SW_ + e4] = pack4bf(acc[j]);
    }
    __syncthreads();

    // O MFMA + residual -> feat1
    {
        bf16x8 a0 = *(bf16x8*)&stB[dcol * SW_ + kgrp * 8];
        bf16x8 a1 = *(bf16x8*)&stB[dcol * SW_ + 32 + kgrp * 8];
        float* dst = feat1 + (size_t)ntb * (V_ * E_);
#pragma unroll
        for (int nt = 0; nt < 4; ++nt) {
            int col = nt * 16 + dcol;
            float bos = bo[col];
            f32x4 cc = (f32x4){bos, bos, bos, bos};
            cc = __builtin_amdgcn_mfma_f32_16x16x32_bf16(a0, *(const bf16x8*)&woT[col * 64 + kgrp * 8], cc, 0, 0, 0);
            cc = __builtin_amdgcn_mfma_f32_16x16x32_bf16(a1, *(const bf16x8*)&woT[col * 64 + 32 + kgrp * 8], cc, 0, 0, 0);
#pragma unroll
            for (int r = 0; r < 4; ++r) {
                int row = trow4 + r;
                if (row < V_) dst[row * E_ + col] = cc[r] + feat[row][col];
            }
        }
    }
}

// ---------------------------------------------------------------------------
// Kernel 2: ONE WAVE per (n,v) tile — unchanged from R10 (proven 843->).
// ---------------------------------------------------------------------------
__global__ __launch_bounds__(64) void k_temporal(
    const float* __restrict__ feat1,
    const u16* __restrict__ wt16,
    const float* __restrict__ bq, const float* __restrict__ bk,
    const float* __restrict__ bv, const float* __restrict__ bo,
    float* __restrict__ tmax) {
    int nv = blockIdx.x;
    int n = nv / V_;
    int v = nv % V_;
    int tid = threadIdx.x;      // 0..63
    int dcol = tid & 15;
    int kgrp = tid >> 4;
    int trow4 = kgrp * 4;

    const u16* wtq = wt16;
    const u16* wtk = wt16 + 4096;
    const u16* wtv = wt16 + 8192;
    const u16* wto = wt16 + 12288;

    __shared__ __align__(16) float smem[5040];
    u16*  ft16 = (u16*)&smem[0];       // [32][72] bf16
    u16*  ao16 = (u16*)&smem[1152];    // [32][72] bf16 attn-out
    float* Qh  = &smem[2304];          // [30][20]
    float* KTh = &smem[2904];          // [16][36]
    float* Vh  = &smem[3480];          // [30][16]
    float* scb = &smem[3960];          // [30][36]

    const float* fsrc = feat1 + ((size_t)n * T_ * V_ + v) * E_;

    for (int o = tid; o < T_ * 16; o += 64) {
        int t = o >> 4, c4i = (o & 15) << 2;
        float4 f = f4_load(fsrc + (size_t)t * V_ * E_ + c4i);
        *(uint2*)&ft16[t * 72 + c4i] = pack4bf(f);
    }
    __syncthreads();

    bf16x8 af[2][2];
#pragma unroll
    for (int mt = 0; mt < 2; ++mt)
#pragma unroll
        for (int ks = 0; ks < 2; ++ks)
            af[mt][ks] = *(bf16x8*)&ft16[(mt * 16 + dcol) * 72 + ks * 32 + kgrp * 8];

    bool sact = (tid < 2 * T_);
    int sq = sact ? (tid >> 1) : 0;
    int kbase = (tid & 1) * 15;

    for (int h = 0; h < H_; ++h) {
        {
            float bqs = bq[h * D_ + dcol];
            float bks = bk[h * D_ + dcol];
            float bvs = bv[h * D_ + dcol];
            f32x4 qacc[2], kacc[2], vacc[2];
#pragma unroll
            for (int mt = 0; mt < 2; ++mt) {
                qacc[mt] = (f32x4){bqs, bqs, bqs, bqs};
                kacc[mt] = (f32x4){bks, bks, bks, bks};
                vacc[mt] = (f32x4){bvs, bvs, bvs, bvs};
            }
#pragma unroll
            for (int ks = 0; ks < 2; ++ks) {
                int boff = (h * D_ + dcol) * 64 + ks * 32 + kgrp * 8;
                bf16x8 b_q = *(const bf16x8*)&wtq[boff];
                bf16x8 b_k = *(const bf16x8*)&wtk[boff];
                bf16x8 b_v = *(const bf16x8*)&wtv[boff];
#pragma unroll
                for (int mt = 0; mt < 2; ++mt) {
                    qacc[mt] = __builtin_amdgcn_mfma_f32_16x16x32_bf16(af[mt][ks], b_q, qacc[mt], 0, 0, 0);
                    kacc[mt] = __builtin_amdgcn_mfma_f32_16x16x32_bf16(af[mt][ks], b_k, kacc[mt], 0, 0, 0);
                    vacc[mt] = __builtin_amdgcn_mfma_f32_16x16x32_bf16(af[mt][ks], b_v, vacc[mt], 0, 0, 0);
                }
            }
#pragma unroll
            for (int mt = 0; mt < 2; ++mt)
#pragma unroll
                for (int r = 0; r < 4; ++r) {
                    int t = mt * 16 + trow4 + r;
                    if (t < T_) {
                        Qh[t * 20 + dcol] = qacc[mt][r];
                        KTh[dcol * 36 + t] = kacc[mt][r];
                        Vh[t * 16 + dcol] = vacc[mt][r];
                    }
                }
        }
        __syncthreads();

        for (int o = tid; o < 240; o += 64) {
            int q = o >> 3, k4 = o & 7;
            float4 a = f4_zero();
#pragma unroll
            for (int d = 0; d < D_; ++d)
                a = f4_fma(Qh[q * 20 + d], f4_load(&KTh[d * 36 + 4 * k4]), a);
            *(float4*)&scb[q * 36 + 4 * k4] = a;
        }
        __syncthreads();

        {
            float m = -1e30f;
#pragma unroll
            for (int k = 0; k < 15; ++k) m = fmaxf(m, scb[sq * 36 + kbase + k]);
            m = fmaxf(m, __shfl_xor(m, 1));
            float ex[15];
            float su = 0.f;
#pragma unroll
            for (int k = 0; k < 15; ++k) {
                ex[k] = __expf((scb[sq * 36 + kbase + k] - m) * 0.25f);
                su += ex[k];
            }
            su += __shfl_xor(su, 1);
            float iv = 1.f / su;
            if (sact) {
#pragma unroll
                for (int k = 0; k < 15; ++k) scb[sq * 36 + kbase + k] = ex[k] * iv;
            }
        }
        __syncthreads();

        for (int o = tid; o < 120; o += 64) {
            int q = o >> 2, cc = o & 3;
            float4 a = f4_zero();
#pragma unroll
            for (int k = 0; k < T_; ++k)
                a = f4_fma(scb[q * 36 + k], f4_load(&Vh[k * 16 + 4 * cc]), a);
            *(uint2*)&ao16[q * 72 + h * D_ + 4 * cc] = pack4bf(a);
        }
        __syncthreads();
    }

    {
        bf16x8 oa[2][2];
#pragma unroll
        for (int mt = 0; mt < 2; ++mt)
#pragma unroll
            for (int ks = 0; ks < 2; ++ks)
                oa[mt][ks] = *(bf16x8*)&ao16[(mt * 16 + dcol) * 72 + ks * 32 + kgrp * 8];

        float mxc[4];
#pragma unroll
        for (int nt = 0; nt < 4; ++nt) {
            float bos = bo[nt * 16 + dcol];
            f32x4 oacc[2];
            oacc[0] = (f32x4){bos, bos, bos, bos};
            oacc[1] = oacc[0];
#pragma unroll
            for (int ks = 0; ks < 2; ++ks) {
                bf16x8 bb = *(const bf16x8*)&wto[(nt * 16 + dcol) * 64 + ks * 32 + kgrp * 8];
#pragma unroll
                for (int mt = 0; mt < 2; ++mt)
                    oacc[mt] = __builtin_amdgcn_mfma_f32_16x16x32_bf16(oa[mt][ks], bb, oacc[mt], 0, 0, 0);
            }
            float m = -1e30f;
#pragma unroll
            for (int mt = 0; mt < 2; ++mt)
#pragma unroll
                for (int r = 0; r < 4; ++r) {
                    int t = mt * 16 + trow4 + r;
                    if (t < T_) {
                        float rr = oacc[mt][r] +
                                   fsrc[(size_t)t * V_ * E_ + nt * 16 + dcol];
                        m = fmaxf(m, rr);
                    }
                }
            mxc[nt] = m;
        }
#pragma unroll
        for (int nt = 0; nt < 4; ++nt) {
            mxc[nt] = fmaxf(mxc[nt], __shfl_xor(mxc[nt], 16));
            mxc[nt] = fmaxf(mxc[nt], __shfl_xor(mxc[nt], 32));
        }
        if (tid < 16) {
#pragma unroll
            for (int nt = 0; nt < 4; ++nt)
                tmax[(size_t)nv * E_ + nt * 16 + tid] = mxc[nt];
        }
    }
}

// ---------------------------------------------------------------------------
// Kernel 3: per n — max over V, then FC to 7 classes.
// ---------------------------------------------------------------------------
__global__ void k_pool_fc(const float* __restrict__ tmax,
                          const float* __restrict__ fc_w, const float* __restrict__ fc_b,
                          float* __restrict__ out) {
    int n = blockIdx.x;
    int tid = threadIdx.x;  // 64
    __shared__ float pooled[E_];
    float m = -1e30f;
    for (int v = 0; v < V_; ++v) m = fmaxf(m, tmax[((size_t)n * V_ + v) * E_ + tid]);
    pooled[tid] = m;
    __syncthreads();
    if (tid < NC_) {
        float s = fc_b[tid];
        for (int e = 0; e < E_; ++e) s += pooled[e] * fc_w[e * NC_ + tid];
        out[n * NC_ + tid] = s;
    }
}

extern "C" void kernel_launch(void* const* d_in, const int* in_sizes, int n_in,
                              void* d_out, int out_size, void* d_ws, size_t ws_size,
                              hipStream_t stream) {
    const float* xj        = (const float*)d_in[0];
    const float* xv        = (const float*)d_in[1];
    const float* je_w      = (const float*)d_in[2];
    const float* je_b      = (const float*)d_in[3];
    const float* ve_w      = (const float*)d_in[4];
    const float* ve_b      = (const float*)d_in[5];
    const float* joint_emb = (const float*)d_in[6];
    const float* frame_emb = (const float*)d_in[7];
    const float* proj_w    = (const float*)d_in[8];
    const float* proj_b    = (const float*)d_in[9];
    const float* gcn_w1    = (const float*)d_in[10];
    const float* gcn_b1    = (const float*)d_in[11];
    const float* gcn_w2    = (const float*)d_in[12];
    const float* gcn_b2    = (const float*)d_in[13];
    const float* sa_wq     = (const float*)d_in[14];
    const float* sa_bq     = (const float*)d_in[15];
    const float* sa_wk     = (const float*)d_in[16];
    const float* sa_bk     = (const float*)d_in[17];
    const float* sa_wv     = (const float*)d_in[18];
    const float* sa_bv     = (const float*)d_in[19];
    const float* sa_wo     = (const float*)d_in[20];
    const float* sa_bo     = (const float*)d_in[21];
    const float* ta_wq     = (const float*)d_in[22];
    const float* ta_bq     = (const float*)d_in[23];
    const float* ta_wk     = (const float*)d_in[24];
    const float* ta_bk     = (const float*)d_in[25];
    const float* ta_wv     = (const float*)d_in[26];
    const float* ta_bv     = (const float*)d_in[27];
    const float* ta_wo     = (const float*)d_in[28];
    const float* ta_bo     = (const float*)d_in[29];
    const float* fc_w      = (const float*)d_in[30];
    const float* fc_b      = (const float*)d_in[31];
    float* out = (float*)d_out;

    int N = in_sizes[0] / (C_ * T_ * V_);

    // ws layout (floats): tab[3200] | wt16 (10x4096 u16 = 20480 f) | tmax | feat1
    float* ws    = (float*)d_ws;
    float* tab   = ws;
    u16*   wt16  = (u16*)(ws + 3200);
    float* tmax  = ws + 3200 + 20480;
    float* feat1 = tmax + (size_t)N * V_ * E_;

    k_setup<<<1, 64, 0, stream>>>(je_w, je_b, ve_w, ve_b, joint_emb, frame_emb,
                                  proj_w, proj_b,
                                  ta_wq, ta_wk, ta_wv, ta_wo,
                                  gcn_w1, gcn_w2, sa_wq, sa_wk, sa_wv, sa_wo, tab);
    k_spatial<<<N * T_, 64, 0, stream>>>(xj, xv, tab, wt16,
                                         gcn_b1, gcn_b2,
                                         sa_bq, sa_bk, sa_bv, sa_bo, feat1);
    k_temporal<<<N * V_, 64, 0, stream>>>(feat1, wt16,
                                          ta_bq, ta_bk, ta_bv, ta_bo, tmax);
    k_pool_fc<<<N, 64, 0, stream>>>(tmax, fc_w, fc_b, out);
}

// Round 12
// 628.813 us; speedup vs baseline: 20.8217x; 1.1091x over previous
//
#include <hip/hip_runtime.h>
#include <math.h>

#define C_ 3
#define T_ 30
#define V_ 14
#define E_ 64
#define H_ 4
#define D_ 16
#define NC_ 7

#define EP_ 68   // padded row stride for [*,E] f32 LDS tiles
#define SW_ 72   // u16 row stride of bf16 [16][72] staging tiles

typedef unsigned short u16;
typedef __attribute__((ext_vector_type(8))) short bf16x8;   // 8 bf16 = 4 VGPR
typedef __attribute__((ext_vector_type(4))) float f32x4;
typedef __attribute__((ext_vector_type(16))) float f32x16;

__device__ __forceinline__ float4 f4_load(const float* p) {
    return *reinterpret_cast<const float4*>(p);
}
__device__ __forceinline__ float4 f4_zero() { return make_float4(0.f, 0.f, 0.f, 0.f); }
__device__ __forceinline__ float4 f4_add(float4 a, float4 b) {
    return make_float4(a.x + b.x, a.y + b.y, a.z + b.z, a.w + b.w);
}
__device__ __forceinline__ float4 f4_fma(float a, float4 b, float4 c) {
    c.x = fmaf(a, b.x, c.x); c.y = fmaf(a, b.y, c.y);
    c.z = fmaf(a, b.z, c.z); c.w = fmaf(a, b.w, c.w); return c;
}
__device__ __forceinline__ float f4_dot(float4 a, float4 b) {
    return a.x * b.x + a.y * b.y + a.z * b.z + a.w * b.w;
}
__device__ __forceinline__ u16 f2bf(float x) {   // RTNE f32 -> bf16
    unsigned u = __float_as_uint(x);
    return (u16)((u + 0x7FFFu + ((u >> 16) & 1u)) >> 16);
}
__device__ __forceinline__ uint2 pack4bf(float4 f) {
    return make_uint2((unsigned)f2bf(f.x) | ((unsigned)f2bf(f.y) << 16),
                      (unsigned)f2bf(f.z) | ((unsigned)f2bf(f.w) << 16));
}
__device__ __forceinline__ f32x16 f16z() {
    return (f32x16){0.f,0.f,0.f,0.f, 0.f,0.f,0.f,0.f, 0.f,0.f,0.f,0.f, 0.f,0.f,0.f,0.f};
}

// ---------------------------------------------------------------------------
// Setup: front-end tables + 10 transposed bf16 weight matrices.
// wt16[m][col][i] = bf16(W_m[i][col]); m: 0..3 = ta q/k/v/o,
// 4..9 = sa w1,w2,wq,wk,wv,wo.
// ---------------------------------------------------------------------------
__global__ void k_setup(const float* __restrict__ je_w, const float* __restrict__ je_b,
                        const float* __restrict__ ve_w, const float* __restrict__ ve_b,
                        const float* __restrict__ joint_emb, const float* __restrict__ frame_emb,
                        const float* __restrict__ proj_w, const float* __restrict__ proj_b,
                        const float* __restrict__ twq, const float* __restrict__ twk,
                        const float* __restrict__ twv, const float* __restrict__ two,
                        const float* __restrict__ sw1, const float* __restrict__ sw2,
                        const float* __restrict__ swq, const float* __restrict__ swk,
                        const float* __restrict__ swv, const float* __restrict__ swo,
                        float* __restrict__ tab) {
    int e = threadIdx.x;  // 64 threads
    for (int c = 0; c < C_; ++c) {
        float aj = 0.f, av = 0.f;
        for (int i = 0; i < E_; ++i) {
            float p0 = proj_w[i * E_ + e];
            aj += je_w[c * E_ + i] * p0;
            av += ve_w[c * E_ + i] * p0;
        }
        tab[c * E_ + e] = aj;
        tab[192 + c * E_ + e] = av;
    }
    for (int v = 0; v < V_; ++v) {
        float s = 0.f;
        for (int i = 0; i < E_; ++i) s += joint_emb[v * E_ + i] * proj_w[(64 + i) * E_ + e];
        tab[384 + v * E_ + e] = s;
    }
    float bias = proj_b[e];
    for (int i = 0; i < E_; ++i) bias += (je_b[i] + ve_b[i]) * proj_w[i * E_ + e];
    for (int t = 0; t < T_; ++t) {
        float s = bias;
        for (int i = 0; i < E_; ++i) s += frame_emb[t * E_ + i] * proj_w[(128 + i) * E_ + e];
        tab[1280 + t * E_ + e] = s;
    }
    u16* wt = (u16*)(tab + 3200);
    const float* Ws[10] = {twq, twk, twv, two, sw1, sw2, swq, swk, swv, swo};
    for (int m = 0; m < 10; ++m) {
        const float* W = Ws[m];
        for (int i = 0; i < E_; ++i)
            wt[m * 4096 + e * 64 + i] = f2bf(W[i * E_ + e]);
    }
}

// ---------------------------------------------------------------------------
// Kernel 1: ONE WAVE per (n,t) tile, fully MFMA-ized:
//  - adjacency raw dots: 2x mfma 16x16x32 (A=B=feat16 row-major; X@X^T trick)
//  - norms from the dot diagonal; adj softmax f32 -> adjs16 bf16 (k=14,15 zero)
//  - adj@feat: 2x mfma 32x32x16 (B = featT tile)
//  - W1, W2, Q/K/V, O: 16x16x32 (R11-verified recipe)
//  - scores & PV: block-diagonal 2-heads-per-MFMA 32x32x16; softmax f32
// 32x32 C/D: col=lane&31, row=(reg&3)+8*(reg>>2)+4*(lane>>5)  [m74/m101].
// ---------------------------------------------------------------------------
__global__ __launch_bounds__(64) void k_spatial(
    const float* __restrict__ xj, const float* __restrict__ xv,
    const float* __restrict__ tab, const u16* __restrict__ wt16,
    const float* __restrict__ b1, const float* __restrict__ b2,
    const float* __restrict__ bq, const float* __restrict__ bk,
    const float* __restrict__ bv, const float* __restrict__ bo,
    float* __restrict__ feat1) {
    int ntb = blockIdx.x;
    int n = ntb / T_;
    int t = ntb % T_;
    int tid = threadIdx.x;      // 0..63
    int dcol = tid & 15;        // 16x16 frag row/col select
    int kgrp = tid >> 4;        // 16x16 k-group / C row-group
    int trow4 = kgrp * 4;
    int e4 = dcol << 2;
    int r4 = kgrp;
    int l32 = tid & 31;         // 32x32 frag row/col select
    int half = tid >> 5;        // 32x32 k-half / row-offset

    const u16* w1T = wt16 + 4 * 4096;
    const u16* w2T = wt16 + 5 * 4096;
    const u16* wqT = wt16 + 6 * 4096;
    const u16* wkT = wt16 + 7 * 4096;
    const u16* wvT = wt16 + 8 * 4096;
    const u16* woT = wt16 + 9 * 4096;

    // f32 shared
    __shared__ __align__(16) float fres[V_][EP_];   // post-GCN feat (residual)
    __shared__ __align__(16) float scbP[1008];      // adjraw[14][18] aliases head
    __shared__ float xs[2][C_][V_];
    __shared__ float inv_nrm[V_];
    // u16 pools (aliased by phase)
    __shared__ __align__(16) u16 poolA[1152];  // feat16 -> g1out -> ao16
    __shared__ __align__(16) u16 poolB[1152];  // g1in -> qs16 -> ps16
    __shared__ __align__(16) u16 poolC[1152];  // fT16 -> qkvin
    __shared__ __align__(16) u16 poolD[1024];  // adjs16 -> ks16
    __shared__ __align__(16) u16 poolE[1024];  // vsT16

    u16* feat16 = poolA; u16* g1out = poolA; u16* ao16 = poolA;
    u16* g1in  = poolB;  u16* qs16  = poolB; u16* ps16 = poolB;
    u16* fT16  = poolC;  u16* qkvin = poolC;
    u16* adjs16 = poolD; u16* ks16  = poolD;
    u16* vsT16 = poolE;
    float* adjraw = scbP;        // [14][18]
    float* scb    = scbP;        // [4][14][18] (after adjraw dead)

    // stage x slices
    for (int o = tid; o < 2 * C_ * V_; o += 64) {
        int s = o / (C_ * V_);
        int rem = o % (C_ * V_);
        int c = rem / V_, v = rem % V_;
        const float* src = s ? xv : xj;
        xs[s][c][v] = src[((size_t)(n * C_ + c) * T_ + t) * V_ + v];
    }
    __syncthreads();

    // ph1: feat build (f32) -> feat16 (row-major bf16) + fT16 ([n][k] bf16)
    {
        float4 F = f4_load(tab + 1280 + t * E_ + e4);
        float4 AJ[C_], AV[C_];
#pragma unroll
        for (int c = 0; c < C_; ++c) {
            AJ[c] = f4_load(tab + c * E_ + e4);
            AV[c] = f4_load(tab + 192 + c * E_ + e4);
        }
#pragma unroll
        for (int j = 0; j < 4; ++j) {
            int q = r4 + 4 * j;
            if (q < V_) {
                float4 s = f4_add(F, f4_load(tab + 384 + q * E_ + e4));
#pragma unroll
                for (int c = 0; c < C_; ++c) {
                    s = f4_fma(xs[0][c][q], AJ[c], s);
                    s = f4_fma(xs[1][c][q], AV[c], s);
                }
                *(uint2*)&feat16[q * SW_ + e4] = pack4bf(s);
                fT16[(e4 + 0) * 16 + q] = f2bf(s.x);
                fT16[(e4 + 1) * 16 + q] = f2bf(s.y);
                fT16[(e4 + 2) * 16 + q] = f2bf(s.z);
                fT16[(e4 + 3) * 16 + q] = f2bf(s.w);
            }
        }
        // zero pad keys 14,15 of featT (0 x garbage = NaN guard)
        fT16[tid * 16 + 14] = 0;
        fT16[tid * 16 + 15] = 0;
    }
    __syncthreads();

    // ph2: adjacency raw dots via MFMA (A = B = feat16 fragment)
    {
        bf16x8 f0 = *(bf16x8*)&feat16[dcol * SW_ + kgrp * 8];
        bf16x8 f1 = *(bf16x8*)&feat16[dcol * SW_ + 32 + kgrp * 8];
        f32x4 d = (f32x4){0.f, 0.f, 0.f, 0.f};
        d = __builtin_amdgcn_mfma_f32_16x16x32_bf16(f0, f0, d, 0, 0, 0);
        d = __builtin_amdgcn_mfma_f32_16x16x32_bf16(f1, f1, d, 0, 0, 0);
#pragma unroll
        for (int r = 0; r < 4; ++r) {
            int row = trow4 + r;
            if (row < V_) adjraw[row * 18 + dcol] = d[r];
        }
    }
    __syncthreads();
    if (tid < V_) inv_nrm[tid] = 1.0f / fmaxf(sqrtf(adjraw[tid * 18 + tid]), 1e-12f);
    __syncthreads();
    // adjacency softmax (f32) -> adjs16 bf16 rows [14][16], k=14,15 zeroed
    if (tid < V_) {
        float c[V_];
        float iq = inv_nrm[tid];
        float m = -1e30f;
#pragma unroll
        for (int k = 0; k < V_; ++k) {
            c[k] = adjraw[tid * 18 + k] * iq * inv_nrm[k];
            m = fmaxf(m, c[k]);
        }
        float su = 0.f;
#pragma unroll
        for (int k = 0; k < V_; ++k) { c[k] = __expf(c[k] - m); su += c[k]; }
        float iv = 1.f / su;
#pragma unroll
        for (int k = 0; k < V_; ++k) adjs16[tid * 16 + k] = f2bf(c[k] * iv);
        adjs16[tid * 16 + 14] = 0;
        adjs16[tid * 16 + 15] = 0;
    }
    __syncthreads();

    // ph3: gcn1 = adj @ feat via 2x 32x32x16 (N tiles of 32) -> g1in bf16
    {
        bf16x8 aA = *(bf16x8*)&adjs16[l32 * 16 + half * 8];
#pragma unroll
        for (int nt = 0; nt < 2; ++nt) {
            bf16x8 bB = *(bf16x8*)&fT16[(nt * 32 + l32) * 16 + half * 8];
            f32x16 g = f16z();
            g = __builtin_amdgcn_mfma_f32_32x32x16_bf16(aA, bB, g, 0, 0, 0);
#pragma unroll
            for (int reg = 0; reg < 16; ++reg) {
                int row = (reg & 3) + 8 * (reg >> 2) + 4 * half;
                if (row < V_) g1in[row * SW_ + nt * 32 + l32] = f2bf(g[reg]);
            }
        }
    }
    __syncthreads();

    // ph4: W1 MFMA + relu -> g1out
    {
        bf16x8 a0 = *(bf16x8*)&g1in[dcol * SW_ + kgrp * 8];
        bf16x8 a1 = *(bf16x8*)&g1in[dcol * SW_ + 32 + kgrp * 8];
#pragma unroll
        for (int nt = 0; nt < 4; ++nt) {
            int col = nt * 16 + dcol;
            float bb = b1[col];
            f32x4 cc = (f32x4){bb, bb, bb, bb};
            cc = __builtin_amdgcn_mfma_f32_16x16x32_bf16(a0, *(const bf16x8*)&w1T[col * 64 + kgrp * 8], cc, 0, 0, 0);
            cc = __builtin_amdgcn_mfma_f32_16x16x32_bf16(a1, *(const bf16x8*)&w1T[col * 64 + 32 + kgrp * 8], cc, 0, 0, 0);
#pragma unroll
            for (int r = 0; r < 4; ++r) {
                int row = trow4 + r;
                if (row < V_) g1out[row * SW_ + col] = f2bf(fmaxf(cc[r], 0.f));
            }
        }
    }
    __syncthreads();

    // ph5: W2 MFMA -> fres f32 (residual) + qkvin bf16
    {
        bf16x8 a0 = *(bf16x8*)&g1out[dcol * SW_ + kgrp * 8];
        bf16x8 a1 = *(bf16x8*)&g1out[dcol * SW_ + 32 + kgrp * 8];
#pragma unroll
        for (int nt = 0; nt < 4; ++nt) {
            int col = nt * 16 + dcol;
            float bb = b2[col];
            f32x4 cc = (f32x4){bb, bb, bb, bb};
            cc = __builtin_amdgcn_mfma_f32_16x16x32_bf16(a0, *(const bf16x8*)&w2T[col * 64 + kgrp * 8], cc, 0, 0, 0);
            cc = __builtin_amdgcn_mfma_f32_16x16x32_bf16(a1, *(const bf16x8*)&w2T[col * 64 + 32 + kgrp * 8], cc, 0, 0, 0);
#pragma unroll
            for (int r = 0; r < 4; ++r) {
                int row = trow4 + r;
                if (row < V_) {
                    fres[row][col] = cc[r];
                    qkvin[row * SW_ + col] = f2bf(cc[r]);
                }
            }
        }
    }
    __syncthreads();

    // ph6: Q/K/V MFMA -> qs16/ks16 (A-style row tiles per head-pair), vsT16
    {
        bf16x8 a0 = *(bf16x8*)&qkvin[dcol * SW_ + kgrp * 8];
        bf16x8 a1 = *(bf16x8*)&qkvin[dcol * SW_ + 32 + kgrp * 8];
#pragma unroll
        for (int nt = 0; nt < 4; ++nt) {
            int col = nt * 16 + dcol;
            float bqs = bq[col], bks = bk[col], bvs = bv[col];
            f32x4 cq = (f32x4){bqs, bqs, bqs, bqs};
            f32x4 ck = (f32x4){bks, bks, bks, bks};
            f32x4 cv = (f32x4){bvs, bvs, bvs, bvs};
            cq = __builtin_amdgcn_mfma_f32_16x16x32_bf16(a0, *(const bf16x8*)&wqT[col * 64 + kgrp * 8], cq, 0, 0, 0);
            cq = __builtin_amdgcn_mfma_f32_16x16x32_bf16(a1, *(const bf16x8*)&wqT[col * 64 + 32 + kgrp * 8], cq, 0, 0, 0);
            ck = __builtin_amdgcn_mfma_f32_16x16x32_bf16(a0, *(const bf16x8*)&wkT[col * 64 + kgrp * 8], ck, 0, 0, 0);
            ck = __builtin_amdgcn_mfma_f32_16x16x32_bf16(a1, *(const bf16x8*)&wkT[col * 64 + 32 + kgrp * 8], ck, 0, 0, 0);
            cv = __builtin_amdgcn_mfma_f32_16x16x32_bf16(a0, *(const bf16x8*)&wvT[col * 64 + kgrp * 8], cv, 0, 0, 0);
            cv = __builtin_amdgcn_mfma_f32_16x16x32_bf16(a1, *(const bf16x8*)&wvT[col * 64 + 32 + kgrp * 8], cv, 0, 0, 0);
            int pair = nt >> 1, hw = nt & 1;
            u16* qsb = qs16 + pair * 512;
            u16* ksb = ks16 + pair * 512;
            u16* vtb = vsT16 + pair * 512;
#pragma unroll
            for (int r = 0; r < 4; ++r) {
                int row = trow4 + r;
                qsb[(hw * 16 + row) * 16 + dcol] = f2bf(cq[r]);
                ksb[(hw * 16 + row) * 16 + dcol] = f2bf(ck[r]);
                vtb[(hw * 16 + dcol) * 16 + row] = (row < V_) ? f2bf(cv[r]) : (u16)0;
            }
        }
    }
    __syncthreads();

    // ph7: scores, 2 heads per 32x32x16 MFMA (block-diagonal) -> scb f32
    {
#pragma unroll
        for (int pair = 0; pair < 2; ++pair) {
            bf16x8 aq = *(bf16x8*)&qs16[pair * 512 + l32 * 16 + half * 8];
            bf16x8 bk8 = *(bf16x8*)&ks16[pair * 512 + l32 * 16 + half * 8];
            f32x16 d = f16z();
            d = __builtin_amdgcn_mfma_f32_32x32x16_bf16(aq, bk8, d, 0, 0, 0);
            int kp = l32 & 15, hp = l32 >> 4;
            if (kp < V_) {
#pragma unroll
                for (int reg = 0; reg < 16; ++reg) {
                    int row = (reg & 3) + 8 * (reg >> 2) + 4 * half;
                    if ((row >> 4) == hp && (row & 15) < V_)
                        scb[(pair * 2 + hp) * 252 + (row & 15) * 18 + kp] = d[reg];
                }
            }
        }
    }
    __syncthreads();

    // ph8: attention softmax (f32, 0.25 scale in exp) -> ps16 bf16 (k 14,15 = 0)
    if (tid < H_ * V_) {
        int h = tid / V_, q = tid % V_;
        float p[V_];
        float m = -1e30f;
#pragma unroll
        for (int k = 0; k < V_; ++k) { p[k] = scb[h * 252 + q * 18 + k]; m = fmaxf(m, p[k]); }
        float su = 0.f;
#pragma unroll
        for (int k = 0; k < V_; ++k) { p[k] = __expf((p[k] - m) * 0.25f); su += p[k]; }
        float iv = 1.f / su;
        u16* psb = ps16 + (h >> 1) * 512;
        int rowp = (h & 1) * 16 + q;
#pragma unroll
        for (int k = 0; k < V_; ++k) psb[rowp * 16 + k] = f2bf(p[k] * iv);
        psb[rowp * 16 + 14] = 0;
        psb[rowp * 16 + 15] = 0;
    }
    __syncthreads();

    // ph9: PV, 2 heads per 32x32x16 MFMA -> ao16 bf16
    {
#pragma unroll
        for (int pair = 0; pair < 2; ++pair) {
            bf16x8 ap = *(bf16x8*)&ps16[pair * 512 + l32 * 16 + half * 8];
            bf16x8 bv8 = *(bf16x8*)&vsT16[pair * 512 + l32 * 16 + half * 8];
            f32x16 d = f16z();
            d = __builtin_amdgcn_mfma_f32_32x32x16_bf16(ap, bv8, d, 0, 0, 0);
            int np = l32 & 15, hp = l32 >> 4;
#pragma unroll
            for (int reg = 0; reg < 16; ++reg) {
                int row = (reg & 3) + 8 * (reg >> 2) + 4 * half;
                if ((row >> 4) == hp && (row & 15) < V_)
                    ao16[(row & 15) * SW_ + (pair * 2 + hp) * 16 + np] = f2bf(d[reg]);
            }
        }
    }
    __syncthreads();

    // ph10: O MFMA + residual -> feat1
    {
        bf16x8 a0 = *(bf16x8*)&ao16[dcol * SW_ + kgrp * 8];
        bf16x8 a1 = *(bf16x8*)&ao16[dcol * SW_ + 32 + kgrp * 8];
        float* dst = feat1 + (size_t)ntb * (V_ * E_);
#pragma unroll
        for (int nt = 0; nt < 4; ++nt) {
            int col = nt * 16 + dcol;
            float bos = bo[col];
            f32x4 cc = (f32x4){bos, bos, bos, bos};
            cc = __builtin_amdgcn_mfma_f32_16x16x32_bf16(a0, *(const bf16x8*)&woT[col * 64 + kgrp * 8], cc, 0, 0, 0);
            cc = __builtin_amdgcn_mfma_f32_16x16x32_bf16(a1, *(const bf16x8*)&woT[col * 64 + 32 + kgrp * 8], cc, 0, 0, 0);
#pragma unroll
            for (int r = 0; r < 4; ++r) {
                int row = trow4 + r;
                if (row < V_) dst[row * E_ + col] = cc[r] + fres[row][col];
            }
        }
    }
}

// ---------------------------------------------------------------------------
// Kernel 2: ONE WAVE per (n,v) tile — unchanged from R10/R11 (proven).
// ---------------------------------------------------------------------------
__global__ __launch_bounds__(64) void k_temporal(
    const float* __restrict__ feat1,
    const u16* __restrict__ wt16,
    const float* __restrict__ bq, const float* __restrict__ bk,
    const float* __restrict__ bv, const float* __restrict__ bo,
    float* __restrict__ tmax) {
    int nv = blockIdx.x;
    int n = nv / V_;
    int v = nv % V_;
    int tid = threadIdx.x;      // 0..63
    int dcol = tid & 15;
    int kgrp = tid >> 4;
    int trow4 = kgrp * 4;

    const u16* wtq = wt16;
    const u16* wtk = wt16 + 4096;
    const u16* wtv = wt16 + 8192;
    const u16* wto = wt16 + 12288;

    __shared__ __align__(16) float smem[5040];
    u16*  ft16 = (u16*)&smem[0];       // [32][72] bf16
    u16*  ao16 = (u16*)&smem[1152];    // [32][72] bf16 attn-out
    float* Qh  = &smem[2304];          // [30][20]
    float* KTh = &smem[2904];          // [16][36]
    float* Vh  = &smem[3480];          // [30][16]
    float* scb = &smem[3960];          // [30][36]

    const float* fsrc = feat1 + ((size_t)n * T_ * V_ + v) * E_;

    for (int o = tid; o < T_ * 16; o += 64) {
        int t = o >> 4, c4i = (o & 15) << 2;
        float4 f = f4_load(fsrc + (size_t)t * V_ * E_ + c4i);
        *(uint2*)&ft16[t * 72 + c4i] = pack4bf(f);
    }
    __syncthreads();

    bf16x8 af[2][2];
#pragma unroll
    for (int mt = 0; mt < 2; ++mt)
#pragma unroll
        for (int ks = 0; ks < 2; ++ks)
            af[mt][ks] = *(bf16x8*)&ft16[(mt * 16 + dcol) * 72 + ks * 32 + kgrp * 8];

    bool sact = (tid < 2 * T_);
    int sq = sact ? (tid >> 1) : 0;
    int kbase = (tid & 1) * 15;

    for (int h = 0; h < H_; ++h) {
        {
            float bqs = bq[h * D_ + dcol];
            float bks = bk[h * D_ + dcol];
            float bvs = bv[h * D_ + dcol];
            f32x4 qacc[2], kacc[2], vacc[2];
#pragma unroll
            for (int mt = 0; mt < 2; ++mt) {
                qacc[mt] = (f32x4){bqs, bqs, bqs, bqs};
                kacc[mt] = (f32x4){bks, bks, bks, bks};
                vacc[mt] = (f32x4){bvs, bvs, bvs, bvs};
            }
#pragma unroll
            for (int ks = 0; ks < 2; ++ks) {
                int boff = (h * D_ + dcol) * 64 + ks * 32 + kgrp * 8;
                bf16x8 b_q = *(const bf16x8*)&wtq[boff];
                bf16x8 b_k = *(const bf16x8*)&wtk[boff];
                bf16x8 b_v = *(const bf16x8*)&wtv[boff];
#pragma unroll
                for (int mt = 0; mt < 2; ++mt) {
                    qacc[mt] = __builtin_amdgcn_mfma_f32_16x16x32_bf16(af[mt][ks], b_q, qacc[mt], 0, 0, 0);
                    kacc[mt] = __builtin_amdgcn_mfma_f32_16x16x32_bf16(af[mt][ks], b_k, kacc[mt], 0, 0, 0);
                    vacc[mt] = __builtin_amdgcn_mfma_f32_16x16x32_bf16(af[mt][ks], b_v, vacc[mt], 0, 0, 0);
                }
            }
#pragma unroll
            for (int mt = 0; mt < 2; ++mt)
#pragma unroll
                for (int r = 0; r < 4; ++r) {
                    int t = mt * 16 + trow4 + r;
                    if (t < T_) {
                        Qh[t * 20 + dcol] = qacc[mt][r];
                        KTh[dcol * 36 + t] = kacc[mt][r];
                        Vh[t * 16 + dcol] = vacc[mt][r];
                    }
                }
        }
        __syncthreads();

        for (int o = tid; o < 240; o += 64) {
            int q = o >> 3, k4 = o & 7;
            float4 a = f4_zero();
#pragma unroll
            for (int d = 0; d < D_; ++d)
                a = f4_fma(Qh[q * 20 + d], f4_load(&KTh[d * 36 + 4 * k4]), a);
            *(float4*)&scb[q * 36 + 4 * k4] = a;
        }
        __syncthreads();

        {
            float m = -1e30f;
#pragma unroll
            for (int k = 0; k < 15; ++k) m = fmaxf(m, scb[sq * 36 + kbase + k]);
            m = fmaxf(m, __shfl_xor(m, 1));
            float ex[15];
            float su = 0.f;
#pragma unroll
            for (int k = 0; k < 15; ++k) {
                ex[k] = __expf((scb[sq * 36 + kbase + k] - m) * 0.25f);
                su += ex[k];
            }
            su += __shfl_xor(su, 1);
            float iv = 1.f / su;
            if (sact) {
#pragma unroll
                for (int k = 0; k < 15; ++k) scb[sq * 36 + kbase + k] = ex[k] * iv;
            }
        }
        __syncthreads();

        for (int o = tid; o < 120; o += 64) {
            int q = o >> 2, cc = o & 3;
            float4 a = f4_zero();
#pragma unroll
            for (int k = 0; k < T_; ++k)
                a = f4_fma(scb[q * 36 + k], f4_load(&Vh[k * 16 + 4 * cc]), a);
            *(uint2*)&ao16[q * 72 + h * D_ + 4 * cc] = pack4bf(a);
        }
        __syncthreads();
    }

    {
        bf16x8 oa[2][2];
#pragma unroll
        for (int mt = 0; mt < 2; ++mt)
#pragma unroll
            for (int ks = 0; ks < 2; ++ks)
                oa[mt][ks] = *(bf16x8*)&ao16[(mt * 16 + dcol) * 72 + ks * 32 + kgrp * 8];

        float mxc[4];
#pragma unroll
        for (int nt = 0; nt < 4; ++nt) {
            float bos = bo[nt * 16 + dcol];
            f32x4 oacc[2];
            oacc[0] = (f32x4){bos, bos, bos, bos};
            oacc[1] = oacc[0];
#pragma unroll
            for (int ks = 0; ks < 2; ++ks) {
                bf16x8 bb = *(const bf16x8*)&wto[(nt * 16 + dcol) * 64 + ks * 32 + kgrp * 8];
#pragma unroll
                for (int mt = 0; mt < 2; ++mt)
                    oacc[mt] = __builtin_amdgcn_mfma_f32_16x16x32_bf16(oa[mt][ks], bb, oacc[mt], 0, 0, 0);
            }
            float m = -1e30f;
#pragma unroll
            for (int mt = 0; mt < 2; ++mt)
#pragma unroll
                for (int r = 0; r < 4; ++r) {
                    int t = mt * 16 + trow4 + r;
                    if (t < T_) {
                        float rr = oacc[mt][r] +
                                   fsrc[(size_t)t * V_ * E_ + nt * 16 + dcol];
                        m = fmaxf(m, rr);
                    }
                }
            mxc[nt] = m;
        }
#pragma unroll
        for (int nt = 0; nt < 4; ++nt) {
            mxc[nt] = fmaxf(mxc[nt], __shfl_xor(mxc[nt], 16));
            mxc[nt] = fmaxf(mxc[nt], __shfl_xor(mxc[nt], 32));
        }
        if (tid < 16) {
#pragma unroll
            for (int nt = 0; nt < 4; ++nt)
                tmax[(size_t)nv * E_ + nt * 16 + tid] = mxc[nt];
        }
    }
}

// ---------------------------------------------------------------------------
// Kernel 3: per n — max over V, then FC to 7 classes.
// ---------------------------------------------------------------------------
__global__ void k_pool_fc(const float* __restrict__ tmax,
                          const float* __restrict__ fc_w, const float* __restrict__ fc_b,
                          float* __restrict__ out) {
    int n = blockIdx.x;
    int tid = threadIdx.x;  // 64
    __shared__ float pooled[E_];
    float m = -1e30f;
    for (int v = 0; v < V_; ++v) m = fmaxf(m, tmax[((size_t)n * V_ + v) * E_ + tid]);
    pooled[tid] = m;
    __syncthreads();
    if (tid < NC_) {
        float s = fc_b[tid];
        for (int e = 0; e < E_; ++e) s += pooled[e] * fc_w[e * NC_ + tid];
        out[n * NC_ + tid] = s;
    }
}

extern "C" void kernel_launch(void* const* d_in, const int* in_sizes, int n_in,
                              void* d_out, int out_size, void* d_ws, size_t ws_size,
                              hipStream_t stream) {
    const float* xj        = (const float*)d_in[0];
    const float* xv        = (const float*)d_in[1];
    const float* je_w      = (const float*)d_in[2];
    const float* je_b      = (const float*)d_in[3];
    const float* ve_w      = (const float*)d_in[4];
    const float* ve_b      = (const float*)d_in[5];
    const float* joint_emb = (const float*)d_in[6];
    const float* frame_emb = (const float*)d_in[7];
    const float* proj_w    = (const float*)d_in[8];
    const float* proj_b    = (const float*)d_in[9];
    const float* gcn_w1    = (const float*)d_in[10];
    const float* gcn_b1    = (const float*)d_in[11];
    const float* gcn_w2    = (const float*)d_in[12];
    const float* gcn_b2    = (const float*)d_in[13];
    const float* sa_wq     = (const float*)d_in[14];
    const float* sa_bq     = (const float*)d_in[15];
    const float* sa_wk     = (const float*)d_in[16];
    const float* sa_bk     = (const float*)d_in[17];
    const float* sa_wv     = (const float*)d_in[18];
    const float* sa_bv     = (const float*)d_in[19];
    const float* sa_wo     = (const float*)d_in[20];
    const float* sa_bo     = (const float*)d_in[21];
    const float* ta_wq     = (const float*)d_in[22];
    const float* ta_bq     = (const float*)d_in[23];
    const float* ta_wk     = (const float*)d_in[24];
    const float* ta_bk     = (const float*)d_in[25];
    const float* ta_wv     = (const float*)d_in[26];
    const float* ta_bv     = (const float*)d_in[27];
    const float* ta_wo     = (const float*)d_in[28];
    const float* ta_bo     = (const float*)d_in[29];
    const float* fc_w      = (const float*)d_in[30];
    const float* fc_b      = (const float*)d_in[31];
    float* out = (float*)d_out;

    int N = in_sizes[0] / (C_ * T_ * V_);

    // ws layout (floats): tab[3200] | wt16 (10x4096 u16 = 20480 f) | tmax | feat1
    float* ws    = (float*)d_ws;
    float* tab   = ws;
    u16*   wt16  = (u16*)(ws + 3200);
    float* tmax  = ws + 3200 + 20480;
    float* feat1 = tmax + (size_t)N * V_ * E_;

    k_setup<<<1, 64, 0, stream>>>(je_w, je_b, ve_w, ve_b, joint_emb, frame_emb,
                                  proj_w, proj_b,
                                  ta_wq, ta_wk, ta_wv, ta_wo,
                                  gcn_w1, gcn_w2, sa_wq, sa_wk, sa_wv, sa_wo, tab);
    k_spatial<<<N * T_, 64, 0, stream>>>(xj, xv, tab, wt16,
                                         gcn_b1, gcn_b2,
                                         sa_bq, sa_bk, sa_bv, sa_bo, feat1);
    k_temporal<<<N * V_, 64, 0, stream>>>(feat1, wt16,
                                          ta_bq, ta_bk, ta_bv, ta_bo, tmax);
    k_pool_fc<<<N, 64, 0, stream>>>(tmax, fc_w, fc_b, out);
}

// Round 13
// 499.228 us; speedup vs baseline: 26.2264x; 1.2596x over previous
//
#include <hip/hip_runtime.h>
#include <math.h>

#define C_ 3
#define T_ 30
#define V_ 14
#define E_ 64
#define H_ 4
#define D_ 16
#define NC_ 7

#define EP_ 68   // padded row stride for [*,E] f32 LDS tiles
#define SW_ 72   // u16 row stride of bf16 [16][72] staging tiles

typedef unsigned short u16;
typedef __attribute__((ext_vector_type(8))) short bf16x8;   // 8 bf16 = 4 VGPR
typedef __attribute__((ext_vector_type(4))) float f32x4;
typedef __attribute__((ext_vector_type(16))) float f32x16;

__device__ __forceinline__ float4 f4_load(const float* p) {
    return *reinterpret_cast<const float4*>(p);
}
__device__ __forceinline__ float4 f4_zero() { return make_float4(0.f, 0.f, 0.f, 0.f); }
__device__ __forceinline__ float4 f4_add(float4 a, float4 b) {
    return make_float4(a.x + b.x, a.y + b.y, a.z + b.z, a.w + b.w);
}
__device__ __forceinline__ float4 f4_fma(float a, float4 b, float4 c) {
    c.x = fmaf(a, b.x, c.x); c.y = fmaf(a, b.y, c.y);
    c.z = fmaf(a, b.z, c.z); c.w = fmaf(a, b.w, c.w); return c;
}
__device__ __forceinline__ float f4_dot(float4 a, float4 b) {
    return a.x * b.x + a.y * b.y + a.z * b.z + a.w * b.w;
}
__device__ __forceinline__ u16 f2bf(float x) {   // RTNE f32 -> bf16
    unsigned u = __float_as_uint(x);
    return (u16)((u + 0x7FFFu + ((u >> 16) & 1u)) >> 16);
}
__device__ __forceinline__ uint2 pack4bf(float4 f) {
    return make_uint2((unsigned)f2bf(f.x) | ((unsigned)f2bf(f.y) << 16),
                      (unsigned)f2bf(f.z) | ((unsigned)f2bf(f.w) << 16));
}
__device__ __forceinline__ f32x16 f16z() {
    return (f32x16){0.f,0.f,0.f,0.f, 0.f,0.f,0.f,0.f, 0.f,0.f,0.f,0.f, 0.f,0.f,0.f,0.f};
}

// ---------------------------------------------------------------------------
// Setup: front-end tables + 10 transposed bf16 weight matrices.
// ---------------------------------------------------------------------------
__global__ void k_setup(const float* __restrict__ je_w, const float* __restrict__ je_b,
                        const float* __restrict__ ve_w, const float* __restrict__ ve_b,
                        const float* __restrict__ joint_emb, const float* __restrict__ frame_emb,
                        const float* __restrict__ proj_w, const float* __restrict__ proj_b,
                        const float* __restrict__ twq, const float* __restrict__ twk,
                        const float* __restrict__ twv, const float* __restrict__ two,
                        const float* __restrict__ sw1, const float* __restrict__ sw2,
                        const float* __restrict__ swq, const float* __restrict__ swk,
                        const float* __restrict__ swv, const float* __restrict__ swo,
                        float* __restrict__ tab) {
    int e = threadIdx.x;  // 64 threads
    for (int c = 0; c < C_; ++c) {
        float aj = 0.f, av = 0.f;
        for (int i = 0; i < E_; ++i) {
            float p0 = proj_w[i * E_ + e];
            aj += je_w[c * E_ + i] * p0;
            av += ve_w[c * E_ + i] * p0;
        }
        tab[c * E_ + e] = aj;
        tab[192 + c * E_ + e] = av;
    }
    for (int v = 0; v < V_; ++v) {
        float s = 0.f;
        for (int i = 0; i < E_; ++i) s += joint_emb[v * E_ + i] * proj_w[(64 + i) * E_ + e];
        tab[384 + v * E_ + e] = s;
    }
    float bias = proj_b[e];
    for (int i = 0; i < E_; ++i) bias += (je_b[i] + ve_b[i]) * proj_w[i * E_ + e];
    for (int t = 0; t < T_; ++t) {
        float s = bias;
        for (int i = 0; i < E_; ++i) s += frame_emb[t * E_ + i] * proj_w[(128 + i) * E_ + e];
        tab[1280 + t * E_ + e] = s;
    }
    u16* wt = (u16*)(tab + 3200);
    const float* Ws[10] = {twq, twk, twv, two, sw1, sw2, swq, swk, swv, swo};
    for (int m = 0; m < 10; ++m) {
        const float* W = Ws[m];
        for (int i = 0; i < E_; ++i)
            wt[m * 4096 + e * 64 + i] = f2bf(W[i * E_ + e]);
    }
}

// ---------------------------------------------------------------------------
// Kernel 1: ONE WAVE per (n,t) tile, fully MFMA-ized (unchanged from R12).
// ---------------------------------------------------------------------------
__global__ __launch_bounds__(64) void k_spatial(
    const float* __restrict__ xj, const float* __restrict__ xv,
    const float* __restrict__ tab, const u16* __restrict__ wt16,
    const float* __restrict__ b1, const float* __restrict__ b2,
    const float* __restrict__ bq, const float* __restrict__ bk,
    const float* __restrict__ bv, const float* __restrict__ bo,
    float* __restrict__ feat1) {
    int ntb = blockIdx.x;
    int n = ntb / T_;
    int t = ntb % T_;
    int tid = threadIdx.x;      // 0..63
    int dcol = tid & 15;
    int kgrp = tid >> 4;
    int trow4 = kgrp * 4;
    int e4 = dcol << 2;
    int r4 = kgrp;
    int l32 = tid & 31;
    int half = tid >> 5;

    const u16* w1T = wt16 + 4 * 4096;
    const u16* w2T = wt16 + 5 * 4096;
    const u16* wqT = wt16 + 6 * 4096;
    const u16* wkT = wt16 + 7 * 4096;
    const u16* wvT = wt16 + 8 * 4096;
    const u16* woT = wt16 + 9 * 4096;

    __shared__ __align__(16) float fres[V_][EP_];
    __shared__ __align__(16) float scbP[1008];
    __shared__ float xs[2][C_][V_];
    __shared__ float inv_nrm[V_];
    __shared__ __align__(16) u16 poolA[1152];
    __shared__ __align__(16) u16 poolB[1152];
    __shared__ __align__(16) u16 poolC[1152];
    __shared__ __align__(16) u16 poolD[1024];
    __shared__ __align__(16) u16 poolE[1024];

    u16* feat16 = poolA; u16* g1out = poolA; u16* ao16 = poolA;
    u16* g1in  = poolB;  u16* qs16  = poolB; u16* ps16 = poolB;
    u16* fT16  = poolC;  u16* qkvin = poolC;
    u16* adjs16 = poolD; u16* ks16  = poolD;
    u16* vsT16 = poolE;
    float* adjraw = scbP;
    float* scb    = scbP;

    for (int o = tid; o < 2 * C_ * V_; o += 64) {
        int s = o / (C_ * V_);
        int rem = o % (C_ * V_);
        int c = rem / V_, v = rem % V_;
        const float* src = s ? xv : xj;
        xs[s][c][v] = src[((size_t)(n * C_ + c) * T_ + t) * V_ + v];
    }
    __syncthreads();

    // ph1: feat build -> feat16 + fT16
    {
        float4 F = f4_load(tab + 1280 + t * E_ + e4);
        float4 AJ[C_], AV[C_];
#pragma unroll
        for (int c = 0; c < C_; ++c) {
            AJ[c] = f4_load(tab + c * E_ + e4);
            AV[c] = f4_load(tab + 192 + c * E_ + e4);
        }
#pragma unroll
        for (int j = 0; j < 4; ++j) {
            int q = r4 + 4 * j;
            if (q < V_) {
                float4 s = f4_add(F, f4_load(tab + 384 + q * E_ + e4));
#pragma unroll
                for (int c = 0; c < C_; ++c) {
                    s = f4_fma(xs[0][c][q], AJ[c], s);
                    s = f4_fma(xs[1][c][q], AV[c], s);
                }
                *(uint2*)&feat16[q * SW_ + e4] = pack4bf(s);
                fT16[(e4 + 0) * 16 + q] = f2bf(s.x);
                fT16[(e4 + 1) * 16 + q] = f2bf(s.y);
                fT16[(e4 + 2) * 16 + q] = f2bf(s.z);
                fT16[(e4 + 3) * 16 + q] = f2bf(s.w);
            }
        }
        fT16[tid * 16 + 14] = 0;
        fT16[tid * 16 + 15] = 0;
    }
    __syncthreads();

    // ph2: adjacency raw dots via MFMA (X@X^T)
    {
        bf16x8 f0 = *(bf16x8*)&feat16[dcol * SW_ + kgrp * 8];
        bf16x8 f1 = *(bf16x8*)&feat16[dcol * SW_ + 32 + kgrp * 8];
        f32x4 d = (f32x4){0.f, 0.f, 0.f, 0.f};
        d = __builtin_amdgcn_mfma_f32_16x16x32_bf16(f0, f0, d, 0, 0, 0);
        d = __builtin_amdgcn_mfma_f32_16x16x32_bf16(f1, f1, d, 0, 0, 0);
#pragma unroll
        for (int r = 0; r < 4; ++r) {
            int row = trow4 + r;
            if (row < V_) adjraw[row * 18 + dcol] = d[r];
        }
    }
    __syncthreads();
    if (tid < V_) inv_nrm[tid] = 1.0f / fmaxf(sqrtf(adjraw[tid * 18 + tid]), 1e-12f);
    __syncthreads();
    if (tid < V_) {
        float c[V_];
        float iq = inv_nrm[tid];
        float m = -1e30f;
#pragma unroll
        for (int k = 0; k < V_; ++k) {
            c[k] = adjraw[tid * 18 + k] * iq * inv_nrm[k];
            m = fmaxf(m, c[k]);
        }
        float su = 0.f;
#pragma unroll
        for (int k = 0; k < V_; ++k) { c[k] = __expf(c[k] - m); su += c[k]; }
        float iv = 1.f / su;
#pragma unroll
        for (int k = 0; k < V_; ++k) adjs16[tid * 16 + k] = f2bf(c[k] * iv);
        adjs16[tid * 16 + 14] = 0;
        adjs16[tid * 16 + 15] = 0;
    }
    __syncthreads();

    // ph3: gcn1 = adj @ feat via 2x 32x32x16
    {
        bf16x8 aA = *(bf16x8*)&adjs16[l32 * 16 + half * 8];
#pragma unroll
        for (int nt = 0; nt < 2; ++nt) {
            bf16x8 bB = *(bf16x8*)&fT16[(nt * 32 + l32) * 16 + half * 8];
            f32x16 g = f16z();
            g = __builtin_amdgcn_mfma_f32_32x32x16_bf16(aA, bB, g, 0, 0, 0);
#pragma unroll
            for (int reg = 0; reg < 16; ++reg) {
                int row = (reg & 3) + 8 * (reg >> 2) + 4 * half;
                if (row < V_) g1in[row * SW_ + nt * 32 + l32] = f2bf(g[reg]);
            }
        }
    }
    __syncthreads();

    // ph4: W1 + relu
    {
        bf16x8 a0 = *(bf16x8*)&g1in[dcol * SW_ + kgrp * 8];
        bf16x8 a1 = *(bf16x8*)&g1in[dcol * SW_ + 32 + kgrp * 8];
#pragma unroll
        for (int nt = 0; nt < 4; ++nt) {
            int col = nt * 16 + dcol;
            float bb = b1[col];
            f32x4 cc = (f32x4){bb, bb, bb, bb};
            cc = __builtin_amdgcn_mfma_f32_16x16x32_bf16(a0, *(const bf16x8*)&w1T[col * 64 + kgrp * 8], cc, 0, 0, 0);
            cc = __builtin_amdgcn_mfma_f32_16x16x32_bf16(a1, *(const bf16x8*)&w1T[col * 64 + 32 + kgrp * 8], cc, 0, 0, 0);
#pragma unroll
            for (int r = 0; r < 4; ++r) {
                int row = trow4 + r;
                if (row < V_) g1out[row * SW_ + col] = f2bf(fmaxf(cc[r], 0.f));
            }
        }
    }
    __syncthreads();

    // ph5: W2 -> fres + qkvin
    {
        bf16x8 a0 = *(bf16x8*)&g1out[dcol * SW_ + kgrp * 8];
        bf16x8 a1 = *(bf16x8*)&g1out[dcol * SW_ + 32 + kgrp * 8];
#pragma unroll
        for (int nt = 0; nt < 4; ++nt) {
            int col = nt * 16 + dcol;
            float bb = b2[col];
            f32x4 cc = (f32x4){bb, bb, bb, bb};
            cc = __builtin_amdgcn_mfma_f32_16x16x32_bf16(a0, *(const bf16x8*)&w2T[col * 64 + kgrp * 8], cc, 0, 0, 0);
            cc = __builtin_amdgcn_mfma_f32_16x16x32_bf16(a1, *(const bf16x8*)&w2T[col * 64 + 32 + kgrp * 8], cc, 0, 0, 0);
#pragma unroll
            for (int r = 0; r < 4; ++r) {
                int row = trow4 + r;
                if (row < V_) {
                    fres[row][col] = cc[r];
                    qkvin[row * SW_ + col] = f2bf(cc[r]);
                }
            }
        }
    }
    __syncthreads();

    // ph6: Q/K/V -> qs16/ks16/vsT16 per head-pair
    {
        bf16x8 a0 = *(bf16x8*)&qkvin[dcol * SW_ + kgrp * 8];
        bf16x8 a1 = *(bf16x8*)&qkvin[dcol * SW_ + 32 + kgrp * 8];
#pragma unroll
        for (int nt = 0; nt < 4; ++nt) {
            int col = nt * 16 + dcol;
            float bqs = bq[col], bks = bk[col], bvs = bv[col];
            f32x4 cq = (f32x4){bqs, bqs, bqs, bqs};
            f32x4 ck = (f32x4){bks, bks, bks, bks};
            f32x4 cv = (f32x4){bvs, bvs, bvs, bvs};
            cq = __builtin_amdgcn_mfma_f32_16x16x32_bf16(a0, *(const bf16x8*)&wqT[col * 64 + kgrp * 8], cq, 0, 0, 0);
            cq = __builtin_amdgcn_mfma_f32_16x16x32_bf16(a1, *(const bf16x8*)&wqT[col * 64 + 32 + kgrp * 8], cq, 0, 0, 0);
            ck = __builtin_amdgcn_mfma_f32_16x16x32_bf16(a0, *(const bf16x8*)&wkT[col * 64 + kgrp * 8], ck, 0, 0, 0);
            ck = __builtin_amdgcn_mfma_f32_16x16x32_bf16(a1, *(const bf16x8*)&wkT[col * 64 + 32 + kgrp * 8], ck, 0, 0, 0);
            cv = __builtin_amdgcn_mfma_f32_16x16x32_bf16(a0, *(const bf16x8*)&wvT[col * 64 + kgrp * 8], cv, 0, 0, 0);
            cv = __builtin_amdgcn_mfma_f32_16x16x32_bf16(a1, *(const bf16x8*)&wvT[col * 64 + 32 + kgrp * 8], cv, 0, 0, 0);
            int pair = nt >> 1, hw = nt & 1;
            u16* qsb = qs16 + pair * 512;
            u16* ksb = ks16 + pair * 512;
            u16* vtb = vsT16 + pair * 512;
#pragma unroll
            for (int r = 0; r < 4; ++r) {
                int row = trow4 + r;
                qsb[(hw * 16 + row) * 16 + dcol] = f2bf(cq[r]);
                ksb[(hw * 16 + row) * 16 + dcol] = f2bf(ck[r]);
                vtb[(hw * 16 + dcol) * 16 + row] = (row < V_) ? f2bf(cv[r]) : (u16)0;
            }
        }
    }
    __syncthreads();

    // ph7: scores 2-heads-per-MFMA
    {
#pragma unroll
        for (int pair = 0; pair < 2; ++pair) {
            bf16x8 aq = *(bf16x8*)&qs16[pair * 512 + l32 * 16 + half * 8];
            bf16x8 bk8 = *(bf16x8*)&ks16[pair * 512 + l32 * 16 + half * 8];
            f32x16 d = f16z();
            d = __builtin_amdgcn_mfma_f32_32x32x16_bf16(aq, bk8, d, 0, 0, 0);
            int kp = l32 & 15, hp = l32 >> 4;
            if (kp < V_) {
#pragma unroll
                for (int reg = 0; reg < 16; ++reg) {
                    int row = (reg & 3) + 8 * (reg >> 2) + 4 * half;
                    if ((row >> 4) == hp && (row & 15) < V_)
                        scb[(pair * 2 + hp) * 252 + (row & 15) * 18 + kp] = d[reg];
                }
            }
        }
    }
    __syncthreads();

    // ph8: attention softmax
    if (tid < H_ * V_) {
        int h = tid / V_, q = tid % V_;
        float p[V_];
        float m = -1e30f;
#pragma unroll
        for (int k = 0; k < V_; ++k) { p[k] = scb[h * 252 + q * 18 + k]; m = fmaxf(m, p[k]); }
        float su = 0.f;
#pragma unroll
        for (int k = 0; k < V_; ++k) { p[k] = __expf((p[k] - m) * 0.25f); su += p[k]; }
        float iv = 1.f / su;
        u16* psb = ps16 + (h >> 1) * 512;
        int rowp = (h & 1) * 16 + q;
#pragma unroll
        for (int k = 0; k < V_; ++k) psb[rowp * 16 + k] = f2bf(p[k] * iv);
        psb[rowp * 16 + 14] = 0;
        psb[rowp * 16 + 15] = 0;
    }
    __syncthreads();

    // ph9: PV 2-heads-per-MFMA
    {
#pragma unroll
        for (int pair = 0; pair < 2; ++pair) {
            bf16x8 ap = *(bf16x8*)&ps16[pair * 512 + l32 * 16 + half * 8];
            bf16x8 bv8 = *(bf16x8*)&vsT16[pair * 512 + l32 * 16 + half * 8];
            f32x16 d = f16z();
            d = __builtin_amdgcn_mfma_f32_32x32x16_bf16(ap, bv8, d, 0, 0, 0);
            int np = l32 & 15, hp = l32 >> 4;
#pragma unroll
            for (int reg = 0; reg < 16; ++reg) {
                int row = (reg & 3) + 8 * (reg >> 2) + 4 * half;
                if ((row >> 4) == hp && (row & 15) < V_)
                    ao16[(row & 15) * SW_ + (pair * 2 + hp) * 16 + np] = f2bf(d[reg]);
            }
        }
    }
    __syncthreads();

    // ph10: O + residual
    {
        bf16x8 a0 = *(bf16x8*)&ao16[dcol * SW_ + kgrp * 8];
        bf16x8 a1 = *(bf16x8*)&ao16[dcol * SW_ + 32 + kgrp * 8];
        float* dst = feat1 + (size_t)ntb * (V_ * E_);
#pragma unroll
        for (int nt = 0; nt < 4; ++nt) {
            int col = nt * 16 + dcol;
            float bos = bo[col];
            f32x4 cc = (f32x4){bos, bos, bos, bos};
            cc = __builtin_amdgcn_mfma_f32_16x16x32_bf16(a0, *(const bf16x8*)&woT[col * 64 + kgrp * 8], cc, 0, 0, 0);
            cc = __builtin_amdgcn_mfma_f32_16x16x32_bf16(a1, *(const bf16x8*)&woT[col * 64 + 32 + kgrp * 8], cc, 0, 0, 0);
#pragma unroll
            for (int r = 0; r < 4; ++r) {
                int row = trow4 + r;
                if (row < V_) dst[row * E_ + col] = cc[r] + fres[row][col];
            }
        }
    }
}

// ---------------------------------------------------------------------------
// Kernel 2: ONE WAVE per (n,v) tile. QKV/O proj via 16x16x32 MFMA (R10),
// NEW: scores = 1x 32x32x16 MFMA / head; PV = 2x 32x32x16 MFMA / head.
// Softmax stays f32 (2 lanes per row). 3 barriers per head preserved by
// moving V-proj into the softmax phase (disjoint buffers).
// LDS (f32 slots): ft16[32][72](1152) | ao16[32][72](1152) | qs16[32][16](256)
//  | ks16[32][16](256) | vT16[16][32](256) | ps16[32][32](512) | scb[30][36](1080)
// = 4664 f = 18.7 KB -> 8 blocks/CU.
// ---------------------------------------------------------------------------
__global__ __launch_bounds__(64) void k_temporal(
    const float* __restrict__ feat1,
    const u16* __restrict__ wt16,
    const float* __restrict__ bq, const float* __restrict__ bk,
    const float* __restrict__ bv, const float* __restrict__ bo,
    float* __restrict__ tmax) {
    int nv = blockIdx.x;
    int n = nv / V_;
    int v = nv % V_;
    int tid = threadIdx.x;      // 0..63
    int dcol = tid & 15;
    int kgrp = tid >> 4;
    int trow4 = kgrp * 4;
    int l32 = tid & 31;
    int half = tid >> 5;

    const u16* wtq = wt16;
    const u16* wtk = wt16 + 4096;
    const u16* wtv = wt16 + 8192;
    const u16* wto = wt16 + 12288;

    __shared__ __align__(16) float smem[4664];
    u16*  ft16 = (u16*)&smem[0];       // [32][72] bf16
    u16*  ao16 = (u16*)&smem[1152];    // [32][72] bf16 attn-out
    u16*  qs16 = (u16*)&smem[2304];    // [32][16] Q of head h (A-frag layout)
    u16*  ks16 = (u16*)&smem[2560];    // [32][16] K row-major (B-frag layout)
    u16*  vT16 = (u16*)&smem[2816];    // [16][32] V^T (d-major; k pads zeroed)
    u16*  ps16 = (u16*)&smem[3072];    // [32][32] probs bf16 (k pads zeroed)
    float* scb = &smem[3584];          // [30][36] scores f32

    const float* fsrc = feat1 + ((size_t)n * T_ * V_ + v) * E_;

    // ph1: bf16 copy of tile
    for (int o = tid; o < T_ * 16; o += 64) {
        int t = o >> 4, c4i = (o & 15) << 2;
        float4 f = f4_load(fsrc + (size_t)t * V_ * E_ + c4i);
        *(uint2*)&ft16[t * 72 + c4i] = pack4bf(f);
    }
    __syncthreads();

    // persistent A-frags of ft
    bf16x8 af[2][2];
#pragma unroll
    for (int mt = 0; mt < 2; ++mt)
#pragma unroll
        for (int ks = 0; ks < 2; ++ks)
            af[mt][ks] = *(bf16x8*)&ft16[(mt * 16 + dcol) * 72 + ks * 32 + kgrp * 8];

    bool sact = (tid < 2 * T_);
    int sq = sact ? (tid >> 1) : 0;
    int kbase = (tid & 1) * 15;

    for (int h = 0; h < H_; ++h) {
        // P1: Q,K projections (MFMA) -> qs16, ks16
        {
            float bqs = bq[h * D_ + dcol];
            float bks = bk[h * D_ + dcol];
            f32x4 qacc[2], kacc[2];
#pragma unroll
            for (int mt = 0; mt < 2; ++mt) {
                qacc[mt] = (f32x4){bqs, bqs, bqs, bqs};
                kacc[mt] = (f32x4){bks, bks, bks, bks};
            }
#pragma unroll
            for (int ks = 0; ks < 2; ++ks) {
                int boff = (h * D_ + dcol) * 64 + ks * 32 + kgrp * 8;
                bf16x8 b_q = *(const bf16x8*)&wtq[boff];
                bf16x8 b_k = *(const bf16x8*)&wtk[boff];
#pragma unroll
                for (int mt = 0; mt < 2; ++mt) {
                    qacc[mt] = __builtin_amdgcn_mfma_f32_16x16x32_bf16(af[mt][ks], b_q, qacc[mt], 0, 0, 0);
                    kacc[mt] = __builtin_amdgcn_mfma_f32_16x16x32_bf16(af[mt][ks], b_k, kacc[mt], 0, 0, 0);
                }
            }
#pragma unroll
            for (int mt = 0; mt < 2; ++mt)
#pragma unroll
                for (int r = 0; r < 4; ++r) {
                    int t = mt * 16 + trow4 + r;   // 0..31
                    qs16[t * 16 + dcol] = f2bf(qacc[mt][r]);
                    ks16[t * 16 + dcol] = f2bf(kacc[mt][r]);
                }
        }
        __syncthreads();

        // P2: scores = one 32x32x16 MFMA -> scb f32
        {
            bf16x8 aq = *(bf16x8*)&qs16[l32 * 16 + half * 8];
            bf16x8 bk8 = *(bf16x8*)&ks16[l32 * 16 + half * 8];
            f32x16 d = f16z();
            d = __builtin_amdgcn_mfma_f32_32x32x16_bf16(aq, bk8, d, 0, 0, 0);
            if (l32 < T_) {
#pragma unroll
                for (int reg = 0; reg < 16; ++reg) {
                    int row = (reg & 3) + 8 * (reg >> 2) + 4 * half;
                    if (row < T_) scb[row * 36 + l32] = d[reg];
                }
            }
        }
        __syncthreads();

        // P3: softmax (f32, 2 lanes/row) -> ps16 bf16 ; V projection -> vT16
        {
            float m = -1e30f;
#pragma unroll
            for (int k = 0; k < 15; ++k) m = fmaxf(m, scb[sq * 36 + kbase + k]);
            m = fmaxf(m, __shfl_xor(m, 1));
            float ex[15];
            float su = 0.f;
#pragma unroll
            for (int k = 0; k < 15; ++k) {
                ex[k] = __expf((scb[sq * 36 + kbase + k] - m) * 0.25f);
                su += ex[k];
            }
            su += __shfl_xor(su, 1);
            float iv = 1.f / su;
            if (sact) {
#pragma unroll
                for (int k = 0; k < 15; ++k) ps16[sq * 32 + kbase + k] = f2bf(ex[k] * iv);
                if (kbase) { ps16[sq * 32 + 30] = 0; ps16[sq * 32 + 31] = 0; }
            }
        }
        {
            float bvs = bv[h * D_ + dcol];
            f32x4 vacc[2];
            vacc[0] = (f32x4){bvs, bvs, bvs, bvs};
            vacc[1] = vacc[0];
#pragma unroll
            for (int ks = 0; ks < 2; ++ks) {
                int boff = (h * D_ + dcol) * 64 + ks * 32 + kgrp * 8;
                bf16x8 b_v = *(const bf16x8*)&wtv[boff];
#pragma unroll
                for (int mt = 0; mt < 2; ++mt)
                    vacc[mt] = __builtin_amdgcn_mfma_f32_16x16x32_bf16(af[mt][ks], b_v, vacc[mt], 0, 0, 0);
            }
#pragma unroll
            for (int mt = 0; mt < 2; ++mt)
#pragma unroll
                for (int r = 0; r < 4; ++r) {
                    int t = mt * 16 + trow4 + r;
                    vT16[dcol * 32 + t] = (t < T_) ? f2bf(vacc[mt][r]) : (u16)0;
                }
        }
        __syncthreads();

        // P4: PV = two 32x32x16 MFMAs -> ao16 (no trailing barrier; next P1
        // writes disjoint qs/ks buffers)
        {
            bf16x8 ap0 = *(bf16x8*)&ps16[l32 * 32 + half * 8];
            bf16x8 ap1 = *(bf16x8*)&ps16[l32 * 32 + 16 + half * 8];
            bf16x8 bv0 = *(bf16x8*)&vT16[(l32 & 15) * 32 + half * 8];
            bf16x8 bv1 = *(bf16x8*)&vT16[(l32 & 15) * 32 + 16 + half * 8];
            f32x16 d = f16z();
            d = __builtin_amdgcn_mfma_f32_32x32x16_bf16(ap0, bv0, d, 0, 0, 0);
            d = __builtin_amdgcn_mfma_f32_32x32x16_bf16(ap1, bv1, d, 0, 0, 0);
            if (l32 < 16) {
#pragma unroll
                for (int reg = 0; reg < 16; ++reg) {
                    int row = (reg & 3) + 8 * (reg >> 2) + 4 * half;
                    if (row < T_) ao16[row * 72 + h * D_ + l32] = f2bf(d[reg]);
                }
            }
        }
    }
    __syncthreads();

    // O projection + residual + T-max
    {
        bf16x8 oa[2][2];
#pragma unroll
        for (int mt = 0; mt < 2; ++mt)
#pragma unroll
            for (int ks = 0; ks < 2; ++ks)
                oa[mt][ks] = *(bf16x8*)&ao16[(mt * 16 + dcol) * 72 + ks * 32 + kgrp * 8];

        float mxc[4];
#pragma unroll
        for (int nt = 0; nt < 4; ++nt) {
            float bos = bo[nt * 16 + dcol];
            f32x4 oacc[2];
            oacc[0] = (f32x4){bos, bos, bos, bos};
            oacc[1] = oacc[0];
#pragma unroll
            for (int ks = 0; ks < 2; ++ks) {
                bf16x8 bb = *(const bf16x8*)&wto[(nt * 16 + dcol) * 64 + ks * 32 + kgrp * 8];
#pragma unroll
                for (int mt = 0; mt < 2; ++mt)
                    oacc[mt] = __builtin_amdgcn_mfma_f32_16x16x32_bf16(oa[mt][ks], bb, oacc[mt], 0, 0, 0);
            }
            float m = -1e30f;
#pragma unroll
            for (int mt = 0; mt < 2; ++mt)
#pragma unroll
                for (int r = 0; r < 4; ++r) {
                    int t = mt * 16 + trow4 + r;
                    if (t < T_) {
                        float rr = oacc[mt][r] +
                                   fsrc[(size_t)t * V_ * E_ + nt * 16 + dcol];
                        m = fmaxf(m, rr);
                    }
                }
            mxc[nt] = m;
        }
#pragma unroll
        for (int nt = 0; nt < 4; ++nt) {
            mxc[nt] = fmaxf(mxc[nt], __shfl_xor(mxc[nt], 16));
            mxc[nt] = fmaxf(mxc[nt], __shfl_xor(mxc[nt], 32));
        }
        if (tid < 16) {
#pragma unroll
            for (int nt = 0; nt < 4; ++nt)
                tmax[(size_t)nv * E_ + nt * 16 + tid] = mxc[nt];
        }
    }
}

// ---------------------------------------------------------------------------
// Kernel 3: per n — max over V, then FC to 7 classes.
// ---------------------------------------------------------------------------
__global__ void k_pool_fc(const float* __restrict__ tmax,
                          const float* __restrict__ fc_w, const float* __restrict__ fc_b,
                          float* __restrict__ out) {
    int n = blockIdx.x;
    int tid = threadIdx.x;  // 64
    __shared__ float pooled[E_];
    float m = -1e30f;
    for (int v = 0; v < V_; ++v) m = fmaxf(m, tmax[((size_t)n * V_ + v) * E_ + tid]);
    pooled[tid] = m;
    __syncthreads();
    if (tid < NC_) {
        float s = fc_b[tid];
        for (int e = 0; e < E_; ++e) s += pooled[e] * fc_w[e * NC_ + tid];
        out[n * NC_ + tid] = s;
    }
}

extern "C" void kernel_launch(void* const* d_in, const int* in_sizes, int n_in,
                              void* d_out, int out_size, void* d_ws, size_t ws_size,
                              hipStream_t stream) {
    const float* xj        = (const float*)d_in[0];
    const float* xv        = (const float*)d_in[1];
    const float* je_w      = (const float*)d_in[2];
    const float* je_b      = (const float*)d_in[3];
    const float* ve_w      = (const float*)d_in[4];
    const float* ve_b      = (const float*)d_in[5];
    const float* joint_emb = (const float*)d_in[6];
    const float* frame_emb = (const float*)d_in[7];
    const float* proj_w    = (const float*)d_in[8];
    const float* proj_b    = (const float*)d_in[9];
    const float* gcn_w1    = (const float*)d_in[10];
    const float* gcn_b1    = (const float*)d_in[11];
    const float* gcn_w2    = (const float*)d_in[12];
    const float* gcn_b2    = (const float*)d_in[13];
    const float* sa_wq     = (const float*)d_in[14];
    const float* sa_bq     = (const float*)d_in[15];
    const float* sa_wk     = (const float*)d_in[16];
    const float* sa_bk     = (const float*)d_in[17];
    const float* sa_wv     = (const float*)d_in[18];
    const float* sa_bv     = (const float*)d_in[19];
    const float* sa_wo     = (const float*)d_in[20];
    const float* sa_bo     = (const float*)d_in[21];
    const float* ta_wq     = (const float*)d_in[22];
    const float* ta_bq     = (const float*)d_in[23];
    const float* ta_wk     = (const float*)d_in[24];
    const float* ta_bk     = (const float*)d_in[25];
    const float* ta_wv     = (const float*)d_in[26];
    const float* ta_bv     = (const float*)d_in[27];
    const float* ta_wo     = (const float*)d_in[28];
    const float* ta_bo     = (const float*)d_in[29];
    const float* fc_w      = (const float*)d_in[30];
    const float* fc_b      = (const float*)d_in[31];
    float* out = (float*)d_out;

    int N = in_sizes[0] / (C_ * T_ * V_);

    // ws layout (floats): tab[3200] | wt16 (10x4096 u16 = 20480 f) | tmax | feat1
    float* ws    = (float*)d_ws;
    float* tab   = ws;
    u16*   wt16  = (u16*)(ws + 3200);
    float* tmax  = ws + 3200 + 20480;
    float* feat1 = tmax + (size_t)N * V_ * E_;

    k_setup<<<1, 64, 0, stream>>>(je_w, je_b, ve_w, ve_b, joint_emb, frame_emb,
                                  proj_w, proj_b,
                                  ta_wq, ta_wk, ta_wv, ta_wo,
                                  gcn_w1, gcn_w2, sa_wq, sa_wk, sa_wv, sa_wo, tab);
    k_spatial<<<N * T_, 64, 0, stream>>>(xj, xv, tab, wt16,
                                         gcn_b1, gcn_b2,
                                         sa_bq, sa_bk, sa_bv, sa_bo, feat1);
    k_temporal<<<N * V_, 64, 0, stream>>>(feat1, wt16,
                                          ta_bq, ta_bk, ta_bv, ta_bo, tmax);
    k_pool_fc<<<N, 64, 0, stream>>>(tmax, fc_w, fc_b, out);
}

// Round 14
// 473.980 us; speedup vs baseline: 27.6234x; 1.0533x over previous
//
#include <hip/hip_runtime.h>
#include <math.h>

#define C_ 3
#define T_ 30
#define V_ 14
#define E_ 64
#define H_ 4
#define D_ 16
#define NC_ 7

#define EP_ 66   // padded row stride for fres f32 tile
#define SW_ 72   // u16 row stride of bf16 [*][72] staging tiles (2-way banks, 16B-aligned)
#define SV_ 20   // u16 row stride of small frag tiles (2-way banks, 8B-aligned)

typedef unsigned short u16;
typedef __attribute__((ext_vector_type(8))) short bf16x8;   // 8 bf16 = 4 VGPR
typedef __attribute__((ext_vector_type(4))) short bf16x4;   // 4 bf16 = 2 VGPR
typedef __attribute__((ext_vector_type(4))) float f32x4;
typedef __attribute__((ext_vector_type(16))) float f32x16;

__device__ __forceinline__ float4 f4_load(const float* p) {
    return *reinterpret_cast<const float4*>(p);
}
__device__ __forceinline__ float4 f4_zero() { return make_float4(0.f, 0.f, 0.f, 0.f); }
__device__ __forceinline__ float4 f4_add(float4 a, float4 b) {
    return make_float4(a.x + b.x, a.y + b.y, a.z + b.z, a.w + b.w);
}
__device__ __forceinline__ float4 f4_fma(float a, float4 b, float4 c) {
    c.x = fmaf(a, b.x, c.x); c.y = fmaf(a, b.y, c.y);
    c.z = fmaf(a, b.z, c.z); c.w = fmaf(a, b.w, c.w); return c;
}
__device__ __forceinline__ u16 f2bf(float x) {   // RTNE f32 -> bf16
    unsigned u = __float_as_uint(x);
    return (u16)((u + 0x7FFFu + ((u >> 16) & 1u)) >> 16);
}
__device__ __forceinline__ uint2 pack4bf(float4 f) {
    return make_uint2((unsigned)f2bf(f.x) | ((unsigned)f2bf(f.y) << 16),
                      (unsigned)f2bf(f.z) | ((unsigned)f2bf(f.w) << 16));
}
__device__ __forceinline__ f32x16 f16z() {
    return (f32x16){0.f,0.f,0.f,0.f, 0.f,0.f,0.f,0.f, 0.f,0.f,0.f,0.f, 0.f,0.f,0.f,0.f};
}
// fragment load from 8B-aligned (not 16B) rows: two ds_read_b64
__device__ __forceinline__ bf16x8 ld_frag8(const u16* p) {
    bf16x4 lo = *(const bf16x4*)p;
    bf16x4 hi = *(const bf16x4*)(p + 4);
    return __builtin_shufflevector(lo, hi, 0, 1, 2, 3, 4, 5, 6, 7);
}

// ---------------------------------------------------------------------------
// Setup (11 blocks): block 0 = front-end tables; blocks 1..10 = one transposed
// bf16 weight matrix each. wt16[m][col][i] = bf16(W_m[i][col]);
// m: 0..3 = ta q/k/v/o, 4..9 = sa w1,w2,wq,wk,wv,wo.
// ---------------------------------------------------------------------------
__global__ void k_setup(const float* __restrict__ je_w, const float* __restrict__ je_b,
                        const float* __restrict__ ve_w, const float* __restrict__ ve_b,
                        const float* __restrict__ joint_emb, const float* __restrict__ frame_emb,
                        const float* __restrict__ proj_w, const float* __restrict__ proj_b,
                        const float* __restrict__ twq, const float* __restrict__ twk,
                        const float* __restrict__ twv, const float* __restrict__ two,
                        const float* __restrict__ sw1, const float* __restrict__ sw2,
                        const float* __restrict__ swq, const float* __restrict__ swk,
                        const float* __restrict__ swv, const float* __restrict__ swo,
                        float* __restrict__ tab) {
    int e = threadIdx.x;  // 64 threads
    int b = blockIdx.x;
    if (b > 0) {
        int m = b - 1;
        const float* Ws[10] = {twq, twk, twv, two, sw1, sw2, swq, swk, swv, swo};
        const float* W = Ws[m];
        u16* wt = (u16*)(tab + 3200);
        for (int i = 0; i < E_; ++i)
            wt[m * 4096 + e * 64 + i] = f2bf(W[i * E_ + e]);
        return;
    }
    for (int c = 0; c < C_; ++c) {
        float aj = 0.f, av = 0.f;
        for (int i = 0; i < E_; ++i) {
            float p0 = proj_w[i * E_ + e];
            aj += je_w[c * E_ + i] * p0;
            av += ve_w[c * E_ + i] * p0;
        }
        tab[c * E_ + e] = aj;
        tab[192 + c * E_ + e] = av;
    }
    for (int v = 0; v < V_; ++v) {
        float s = 0.f;
        for (int i = 0; i < E_; ++i) s += joint_emb[v * E_ + i] * proj_w[(64 + i) * E_ + e];
        tab[384 + v * E_ + e] = s;
    }
    float bias = proj_b[e];
    for (int i = 0; i < E_; ++i) bias += (je_b[i] + ve_b[i]) * proj_w[i * E_ + e];
    for (int t = 0; t < T_; ++t) {
        float s = bias;
        for (int i = 0; i < E_; ++i) s += frame_emb[t * E_ + i] * proj_w[(128 + i) * E_ + e];
        tab[1280 + t * E_ + e] = s;
    }
}

// ---------------------------------------------------------------------------
// Kernel 1: ONE WAVE per (n,t) tile, fully MFMA-ized (R12 structure) with
// bank-conflict-free small tiles (stride SV_=20 u16, b64-pair fragment loads).
// ---------------------------------------------------------------------------
__global__ __launch_bounds__(64) void k_spatial(
    const float* __restrict__ xj, const float* __restrict__ xv,
    const float* __restrict__ tab, const u16* __restrict__ wt16,
    const float* __restrict__ b1, const float* __restrict__ b2,
    const float* __restrict__ bq, const float* __restrict__ bk,
    const float* __restrict__ bv, const float* __restrict__ bo,
    float* __restrict__ feat1) {
    int ntb = blockIdx.x;
    int n = ntb / T_;
    int t = ntb % T_;
    int tid = threadIdx.x;      // 0..63
    int dcol = tid & 15;
    int kgrp = tid >> 4;
    int trow4 = kgrp * 4;
    int e4 = dcol << 2;
    int r4 = kgrp;
    int l32 = tid & 31;
    int half = tid >> 5;

    const u16* w1T = wt16 + 4 * 4096;
    const u16* w2T = wt16 + 5 * 4096;
    const u16* wqT = wt16 + 6 * 4096;
    const u16* wkT = wt16 + 7 * 4096;
    const u16* wvT = wt16 + 8 * 4096;
    const u16* woT = wt16 + 9 * 4096;

    __shared__ __align__(16) float fres[V_][EP_];
    __shared__ __align__(16) float scbP[1008];
    __shared__ float inv_nrm[V_];
    __shared__ __align__(16) u16 poolA[1152];
    __shared__ __align__(16) u16 poolB[1280];
    __shared__ __align__(16) u16 poolC[1280];
    __shared__ __align__(16) u16 poolD[1280];
    __shared__ __align__(16) u16 poolE[1280];

    u16* feat16 = poolA; u16* g1out = poolA; u16* ao16 = poolA;
    u16* g1in  = poolB;  u16* qs16  = poolB; u16* ps16 = poolB;
    u16* fT16  = poolC;  u16* qkvin = poolC;
    u16* adjs16 = poolD; u16* ks16  = poolD;
    u16* vsT16 = poolE;
    float* xs = (float*)poolE;   // [2][3][14] alias; dead before ph6 writes poolE
    float* adjraw = scbP;
    float* scb    = scbP;

    for (int o = tid; o < 2 * C_ * V_; o += 64) {
        int s = o / (C_ * V_);
        int rem = o % (C_ * V_);
        int c = rem / V_, v = rem % V_;
        const float* src = s ? xv : xj;
        xs[(s * C_ + c) * V_ + v] = src[((size_t)(n * C_ + c) * T_ + t) * V_ + v];
    }
    __syncthreads();

    // ph1: feat build -> feat16 (SW_ rows) + fT16 (SV_ rows, transposed)
    {
        float4 F = f4_load(tab + 1280 + t * E_ + e4);
        float4 AJ[C_], AV[C_];
#pragma unroll
        for (int c = 0; c < C_; ++c) {
            AJ[c] = f4_load(tab + c * E_ + e4);
            AV[c] = f4_load(tab + 192 + c * E_ + e4);
        }
#pragma unroll
        for (int j = 0; j < 4; ++j) {
            int q = r4 + 4 * j;
            if (q < V_) {
                float4 s = f4_add(F, f4_load(tab + 384 + q * E_ + e4));
#pragma unroll
                for (int c = 0; c < C_; ++c) {
                    s = f4_fma(xs[(0 * C_ + c) * V_ + q], AJ[c], s);
                    s = f4_fma(xs[(1 * C_ + c) * V_ + q], AV[c], s);
                }
                *(uint2*)&feat16[q * SW_ + e4] = pack4bf(s);
                fT16[(e4 + 0) * SV_ + q] = f2bf(s.x);
                fT16[(e4 + 1) * SV_ + q] = f2bf(s.y);
                fT16[(e4 + 2) * SV_ + q] = f2bf(s.z);
                fT16[(e4 + 3) * SV_ + q] = f2bf(s.w);
            }
        }
        fT16[tid * SV_ + 14] = 0;
        fT16[tid * SV_ + 15] = 0;
    }
    __syncthreads();

    // ph2: adjacency raw dots via MFMA (X@X^T)
    {
        bf16x8 f0 = *(bf16x8*)&feat16[dcol * SW_ + kgrp * 8];
        bf16x8 f1 = *(bf16x8*)&feat16[dcol * SW_ + 32 + kgrp * 8];
        f32x4 d = (f32x4){0.f, 0.f, 0.f, 0.f};
        d = __builtin_amdgcn_mfma_f32_16x16x32_bf16(f0, f0, d, 0, 0, 0);
        d = __builtin_amdgcn_mfma_f32_16x16x32_bf16(f1, f1, d, 0, 0, 0);
#pragma unroll
        for (int r = 0; r < 4; ++r) {
            int row = trow4 + r;
            if (row < V_) adjraw[row * 18 + dcol] = d[r];
        }
    }
    __syncthreads();
    if (tid < V_) inv_nrm[tid] = 1.0f / fmaxf(sqrtf(adjraw[tid * 18 + tid]), 1e-12f);
    __syncthreads();
    if (tid < V_) {
        float c[V_];
        float iq = inv_nrm[tid];
        float m = -1e30f;
#pragma unroll
        for (int k = 0; k < V_; ++k) {
            c[k] = adjraw[tid * 18 + k] * iq * inv_nrm[k];
            m = fmaxf(m, c[k]);
        }
        float su = 0.f;
#pragma unroll
        for (int k = 0; k < V_; ++k) { c[k] = __expf(c[k] - m); su += c[k]; }
        float iv = 1.f / su;
#pragma unroll
        for (int k = 0; k < V_; ++k) adjs16[tid * SV_ + k] = f2bf(c[k] * iv);
        adjs16[tid * SV_ + 14] = 0;
        adjs16[tid * SV_ + 15] = 0;
    }
    __syncthreads();

    // ph3: gcn1 = adj @ feat via 2x 32x32x16
    {
        bf16x8 aA = ld_frag8(&adjs16[l32 * SV_ + half * 8]);
#pragma unroll
        for (int nt = 0; nt < 2; ++nt) {
            bf16x8 bB = ld_frag8(&fT16[(nt * 32 + l32) * SV_ + half * 8]);
            f32x16 g = f16z();
            g = __builtin_amdgcn_mfma_f32_32x32x16_bf16(aA, bB, g, 0, 0, 0);
#pragma unroll
            for (int reg = 0; reg < 16; ++reg) {
                int row = (reg & 3) + 8 * (reg >> 2) + 4 * half;
                if (row < V_) g1in[row * SW_ + nt * 32 + l32] = f2bf(g[reg]);
            }
        }
    }
    __syncthreads();

    // ph4: W1 + relu
    {
        bf16x8 a0 = *(bf16x8*)&g1in[dcol * SW_ + kgrp * 8];
        bf16x8 a1 = *(bf16x8*)&g1in[dcol * SW_ + 32 + kgrp * 8];
#pragma unroll
        for (int nt = 0; nt < 4; ++nt) {
            int col = nt * 16 + dcol;
            float bb = b1[col];
            f32x4 cc = (f32x4){bb, bb, bb, bb};
            cc = __builtin_amdgcn_mfma_f32_16x16x32_bf16(a0, *(const bf16x8*)&w1T[col * 64 + kgrp * 8], cc, 0, 0, 0);
            cc = __builtin_amdgcn_mfma_f32_16x16x32_bf16(a1, *(const bf16x8*)&w1T[col * 64 + 32 + kgrp * 8], cc, 0, 0, 0);
#pragma unroll
            for (int r = 0; r < 4; ++r) {
                int row = trow4 + r;
                if (row < V_) g1out[row * SW_ + col] = f2bf(fmaxf(cc[r], 0.f));
            }
        }
    }
    __syncthreads();

    // ph5: W2 -> fres + qkvin
    {
        bf16x8 a0 = *(bf16x8*)&g1out[dcol * SW_ + kgrp * 8];
        bf16x8 a1 = *(bf16x8*)&g1out[dcol * SW_ + 32 + kgrp * 8];
#pragma unroll
        for (int nt = 0; nt < 4; ++nt) {
            int col = nt * 16 + dcol;
            float bb = b2[col];
            f32x4 cc = (f32x4){bb, bb, bb, bb};
            cc = __builtin_amdgcn_mfma_f32_16x16x32_bf16(a0, *(const bf16x8*)&w2T[col * 64 + kgrp * 8], cc, 0, 0, 0);
            cc = __builtin_amdgcn_mfma_f32_16x16x32_bf16(a1, *(const bf16x8*)&w2T[col * 64 + 32 + kgrp * 8], cc, 0, 0, 0);
#pragma unroll
            for (int r = 0; r < 4; ++r) {
                int row = trow4 + r;
                if (row < V_) {
                    fres[row][col] = cc[r];
                    qkvin[row * SW_ + col] = f2bf(cc[r]);
                }
            }
        }
    }
    __syncthreads();

    // ph6: Q/K/V -> qs16/ks16/vsT16 per head-pair (SV_ rows)
    {
        bf16x8 a0 = *(bf16x8*)&qkvin[dcol * SW_ + kgrp * 8];
        bf16x8 a1 = *(bf16x8*)&qkvin[dcol * SW_ + 32 + kgrp * 8];
#pragma unroll
        for (int nt = 0; nt < 4; ++nt) {
            int col = nt * 16 + dcol;
            float bqs = bq[col], bks = bk[col], bvs = bv[col];
            f32x4 cq = (f32x4){bqs, bqs, bqs, bqs};
            f32x4 ck = (f32x4){bks, bks, bks, bks};
            f32x4 cv = (f32x4){bvs, bvs, bvs, bvs};
            cq = __builtin_amdgcn_mfma_f32_16x16x32_bf16(a0, *(const bf16x8*)&wqT[col * 64 + kgrp * 8], cq, 0, 0, 0);
            cq = __builtin_amdgcn_mfma_f32_16x16x32_bf16(a1, *(const bf16x8*)&wqT[col * 64 + 32 + kgrp * 8], cq, 0, 0, 0);
            ck = __builtin_amdgcn_mfma_f32_16x16x32_bf16(a0, *(const bf16x8*)&wkT[col * 64 + kgrp * 8], ck, 0, 0, 0);
            ck = __builtin_amdgcn_mfma_f32_16x16x32_bf16(a1, *(const bf16x8*)&wkT[col * 64 + 32 + kgrp * 8], ck, 0, 0, 0);
            cv = __builtin_amdgcn_mfma_f32_16x16x32_bf16(a0, *(const bf16x8*)&wvT[col * 64 + kgrp * 8], cv, 0, 0, 0);
            cv = __builtin_amdgcn_mfma_f32_16x16x32_bf16(a1, *(const bf16x8*)&wvT[col * 64 + 32 + kgrp * 8], cv, 0, 0, 0);
            int pair = nt >> 1, hw = nt & 1;
            u16* qsb = qs16 + pair * 640;
            u16* ksb = ks16 + pair * 640;
            u16* vtb = vsT16 + pair * 640;
#pragma unroll
            for (int r = 0; r < 4; ++r) {
                int row = trow4 + r;
                qsb[(hw * 16 + row) * SV_ + dcol] = f2bf(cq[r]);
                ksb[(hw * 16 + row) * SV_ + dcol] = f2bf(ck[r]);
                vtb[(hw * 16 + dcol) * SV_ + row] = (row < V_) ? f2bf(cv[r]) : (u16)0;
            }
        }
    }
    __syncthreads();

    // ph7: scores 2-heads-per-MFMA
    {
#pragma unroll
        for (int pair = 0; pair < 2; ++pair) {
            bf16x8 aq = ld_frag8(&qs16[pair * 640 + l32 * SV_ + half * 8]);
            bf16x8 bk8 = ld_frag8(&ks16[pair * 640 + l32 * SV_ + half * 8]);
            f32x16 d = f16z();
            d = __builtin_amdgcn_mfma_f32_32x32x16_bf16(aq, bk8, d, 0, 0, 0);
            int kp = l32 & 15, hp = l32 >> 4;
            if (kp < V_) {
#pragma unroll
                for (int reg = 0; reg < 16; ++reg) {
                    int row = (reg & 3) + 8 * (reg >> 2) + 4 * half;
                    if ((row >> 4) == hp && (row & 15) < V_)
                        scb[(pair * 2 + hp) * 252 + (row & 15) * 18 + kp] = d[reg];
                }
            }
        }
    }
    __syncthreads();

    // ph8: attention softmax -> ps16 (SV_ rows)
    if (tid < H_ * V_) {
        int h = tid / V_, q = tid % V_;
        float p[V_];
        float m = -1e30f;
#pragma unroll
        for (int k = 0; k < V_; ++k) { p[k] = scb[h * 252 + q * 18 + k]; m = fmaxf(m, p[k]); }
        float su = 0.f;
#pragma unroll
        for (int k = 0; k < V_; ++k) { p[k] = __expf((p[k] - m) * 0.25f); su += p[k]; }
        float iv = 1.f / su;
        u16* psb = ps16 + (h >> 1) * 640;
        int rowp = (h & 1) * 16 + q;
#pragma unroll
        for (int k = 0; k < V_; ++k) psb[rowp * SV_ + k] = f2bf(p[k] * iv);
        psb[rowp * SV_ + 14] = 0;
        psb[rowp * SV_ + 15] = 0;
    }
    __syncthreads();

    // ph9: PV 2-heads-per-MFMA
    {
#pragma unroll
        for (int pair = 0; pair < 2; ++pair) {
            bf16x8 ap = ld_frag8(&ps16[pair * 640 + l32 * SV_ + half * 8]);
            bf16x8 bv8 = ld_frag8(&vsT16[pair * 640 + l32 * SV_ + half * 8]);
            f32x16 d = f16z();
            d = __builtin_amdgcn_mfma_f32_32x32x16_bf16(ap, bv8, d, 0, 0, 0);
            int np = l32 & 15, hp = l32 >> 4;
#pragma unroll
            for (int reg = 0; reg < 16; ++reg) {
                int row = (reg & 3) + 8 * (reg >> 2) + 4 * half;
                if ((row >> 4) == hp && (row & 15) < V_)
                    ao16[(row & 15) * SW_ + (pair * 2 + hp) * 16 + np] = f2bf(d[reg]);
            }
        }
    }
    __syncthreads();

    // ph10: O + residual
    {
        bf16x8 a0 = *(bf16x8*)&ao16[dcol * SW_ + kgrp * 8];
        bf16x8 a1 = *(bf16x8*)&ao16[dcol * SW_ + 32 + kgrp * 8];
        float* dst = feat1 + (size_t)ntb * (V_ * E_);
#pragma unroll
        for (int nt = 0; nt < 4; ++nt) {
            int col = nt * 16 + dcol;
            float bos = bo[col];
            f32x4 cc = (f32x4){bos, bos, bos, bos};
            cc = __builtin_amdgcn_mfma_f32_16x16x32_bf16(a0, *(const bf16x8*)&woT[col * 64 + kgrp * 8], cc, 0, 0, 0);
            cc = __builtin_amdgcn_mfma_f32_16x16x32_bf16(a1, *(const bf16x8*)&woT[col * 64 + 32 + kgrp * 8], cc, 0, 0, 0);
#pragma unroll
            for (int r = 0; r < 4; ++r) {
                int row = trow4 + r;
                if (row < V_) dst[row * E_ + col] = cc[r] + fres[row][col];
            }
        }
    }
}

// ---------------------------------------------------------------------------
// Kernel 2: ONE WAVE per (n,v) tile (R13 structure), small tiles restrided:
// qs16/ks16 [32][20], vT16 [16][36], ps16 [32][36] -> 2-way banks.
// ---------------------------------------------------------------------------
__global__ __launch_bounds__(64) void k_temporal(
    const float* __restrict__ feat1,
    const u16* __restrict__ wt16,
    const float* __restrict__ bq, const float* __restrict__ bk,
    const float* __restrict__ bv, const float* __restrict__ bo,
    float* __restrict__ tmax) {
    int nv = blockIdx.x;
    int n = nv / V_;
    int v = nv % V_;
    int tid = threadIdx.x;      // 0..63
    int dcol = tid & 15;
    int kgrp = tid >> 4;
    int trow4 = kgrp * 4;
    int l32 = tid & 31;
    int half = tid >> 5;

    const u16* wtq = wt16;
    const u16* wtk = wt16 + 4096;
    const u16* wtv = wt16 + 8192;
    const u16* wto = wt16 + 12288;

    __shared__ __align__(16) float smem[4888];
    u16*  ft16 = (u16*)&smem[0];       // [32][72] bf16
    u16*  ao16 = (u16*)&smem[1152];    // [32][72] bf16 attn-out
    u16*  qs16 = (u16*)&smem[2304];    // [32][20]
    u16*  ks16 = (u16*)&smem[2624];    // [32][20]
    u16*  vT16 = (u16*)&smem[2944];    // [16][36] V^T (k pads zeroed)
    u16*  ps16 = (u16*)&smem[3232];    // [32][36] probs (k 30,31 zeroed)
    float* scb = &smem[3808];          // [30][36] scores f32

    const float* fsrc = feat1 + ((size_t)n * T_ * V_ + v) * E_;

    // ph1: bf16 copy of tile
    for (int o = tid; o < T_ * 16; o += 64) {
        int t = o >> 4, c4i = (o & 15) << 2;
        float4 f = f4_load(fsrc + (size_t)t * V_ * E_ + c4i);
        *(uint2*)&ft16[t * 72 + c4i] = pack4bf(f);
    }
    __syncthreads();

    // persistent A-frags of ft
    bf16x8 af[2][2];
#pragma unroll
    for (int mt = 0; mt < 2; ++mt)
#pragma unroll
        for (int ks = 0; ks < 2; ++ks)
            af[mt][ks] = *(bf16x8*)&ft16[(mt * 16 + dcol) * 72 + ks * 32 + kgrp * 8];

    bool sact = (tid < 2 * T_);
    int sq = sact ? (tid >> 1) : 0;
    int kbase = (tid & 1) * 15;

    for (int h = 0; h < H_; ++h) {
        // P1: Q,K projections (MFMA)
        {
            float bqs = bq[h * D_ + dcol];
            float bks = bk[h * D_ + dcol];
            f32x4 qacc[2], kacc[2];
#pragma unroll
            for (int mt = 0; mt < 2; ++mt) {
                qacc[mt] = (f32x4){bqs, bqs, bqs, bqs};
                kacc[mt] = (f32x4){bks, bks, bks, bks};
            }
#pragma unroll
            for (int ks = 0; ks < 2; ++ks) {
                int boff = (h * D_ + dcol) * 64 + ks * 32 + kgrp * 8;
                bf16x8 b_q = *(const bf16x8*)&wtq[boff];
                bf16x8 b_k = *(const bf16x8*)&wtk[boff];
#pragma unroll
                for (int mt = 0; mt < 2; ++mt) {
                    qacc[mt] = __builtin_amdgcn_mfma_f32_16x16x32_bf16(af[mt][ks], b_q, qacc[mt], 0, 0, 0);
                    kacc[mt] = __builtin_amdgcn_mfma_f32_16x16x32_bf16(af[mt][ks], b_k, kacc[mt], 0, 0, 0);
                }
            }
#pragma unroll
            for (int mt = 0; mt < 2; ++mt)
#pragma unroll
                for (int r = 0; r < 4; ++r) {
                    int t = mt * 16 + trow4 + r;   // 0..31
                    qs16[t * SV_ + dcol] = f2bf(qacc[mt][r]);
                    ks16[t * SV_ + dcol] = f2bf(kacc[mt][r]);
                }
        }
        __syncthreads();

        // P2: scores = one 32x32x16 MFMA -> scb f32
        {
            bf16x8 aq = ld_frag8(&qs16[l32 * SV_ + half * 8]);
            bf16x8 bk8 = ld_frag8(&ks16[l32 * SV_ + half * 8]);
            f32x16 d = f16z();
            d = __builtin_amdgcn_mfma_f32_32x32x16_bf16(aq, bk8, d, 0, 0, 0);
            if (l32 < T_) {
#pragma unroll
                for (int reg = 0; reg < 16; ++reg) {
                    int row = (reg & 3) + 8 * (reg >> 2) + 4 * half;
                    if (row < T_) scb[row * 36 + l32] = d[reg];
                }
            }
        }
        __syncthreads();

        // P3: softmax (f32, 2 lanes/row) -> ps16 ; V projection -> vT16
        {
            float m = -1e30f;
#pragma unroll
            for (int k = 0; k < 15; ++k) m = fmaxf(m, scb[sq * 36 + kbase + k]);
            m = fmaxf(m, __shfl_xor(m, 1));
            float ex[15];
            float su = 0.f;
#pragma unroll
            for (int k = 0; k < 15; ++k) {
                ex[k] = __expf((scb[sq * 36 + kbase + k] - m) * 0.25f);
                su += ex[k];
            }
            su += __shfl_xor(su, 1);
            float iv = 1.f / su;
            if (sact) {
#pragma unroll
                for (int k = 0; k < 15; ++k) ps16[sq * 36 + kbase + k] = f2bf(ex[k] * iv);
                if (kbase) { ps16[sq * 36 + 30] = 0; ps16[sq * 36 + 31] = 0; }
            }
        }
        {
            float bvs = bv[h * D_ + dcol];
            f32x4 vacc[2];
            vacc[0] = (f32x4){bvs, bvs, bvs, bvs};
            vacc[1] = vacc[0];
#pragma unroll
            for (int ks = 0; ks < 2; ++ks) {
                int boff = (h * D_ + dcol) * 64 + ks * 32 + kgrp * 8;
                bf16x8 b_v = *(const bf16x8*)&wtv[boff];
#pragma unroll
                for (int mt = 0; mt < 2; ++mt)
                    vacc[mt] = __builtin_amdgcn_mfma_f32_16x16x32_bf16(af[mt][ks], b_v, vacc[mt], 0, 0, 0);
            }
#pragma unroll
            for (int mt = 0; mt < 2; ++mt)
#pragma unroll
                for (int r = 0; r < 4; ++r) {
                    int t = mt * 16 + trow4 + r;
                    vT16[dcol * 36 + t] = (t < T_) ? f2bf(vacc[mt][r]) : (u16)0;
                }
        }
        __syncthreads();

        // P4: PV = two 32x32x16 MFMAs -> ao16
        {
            bf16x8 ap0 = ld_frag8(&ps16[l32 * 36 + half * 8]);
            bf16x8 ap1 = ld_frag8(&ps16[l32 * 36 + 16 + half * 8]);
            bf16x8 bv0 = ld_frag8(&vT16[(l32 & 15) * 36 + half * 8]);
            bf16x8 bv1 = ld_frag8(&vT16[(l32 & 15) * 36 + 16 + half * 8]);
            f32x16 d = f16z();
            d = __builtin_amdgcn_mfma_f32_32x32x16_bf16(ap0, bv0, d, 0, 0, 0);
            d = __builtin_amdgcn_mfma_f32_32x32x16_bf16(ap1, bv1, d, 0, 0, 0);
            if (l32 < 16) {
#pragma unroll
                for (int reg = 0; reg < 16; ++reg) {
                    int row = (reg & 3) + 8 * (reg >> 2) + 4 * half;
                    if (row < T_) ao16[row * 72 + h * D_ + l32] = f2bf(d[reg]);
                }
            }
        }
    }
    __syncthreads();

    // O projection + residual + T-max
    {
        bf16x8 oa[2][2];
#pragma unroll
        for (int mt = 0; mt < 2; ++mt)
#pragma unroll
            for (int ks = 0; ks < 2; ++ks)
                oa[mt][ks] = *(bf16x8*)&ao16[(mt * 16 + dcol) * 72 + ks * 32 + kgrp * 8];

        float mxc[4];
#pragma unroll
        for (int nt = 0; nt < 4; ++nt) {
            float bos = bo[nt * 16 + dcol];
            f32x4 oacc[2];
            oacc[0] = (f32x4){bos, bos, bos, bos};
            oacc[1] = oacc[0];
#pragma unroll
            for (int ks = 0; ks < 2; ++ks) {
                bf16x8 bb = *(const bf16x8*)&wto[(nt * 16 + dcol) * 64 + ks * 32 + kgrp * 8];
#pragma unroll
                for (int mt = 0; mt < 2; ++mt)
                    oacc[mt] = __builtin_amdgcn_mfma_f32_16x16x32_bf16(oa[mt][ks], bb, oacc[mt], 0, 0, 0);
            }
            float m = -1e30f;
#pragma unroll
            for (int mt = 0; mt < 2; ++mt)
#pragma unroll
                for (int r = 0; r < 4; ++r) {
                    int t = mt * 16 + trow4 + r;
                    if (t < T_) {
                        float rr = oacc[mt][r] +
                                   fsrc[(size_t)t * V_ * E_ + nt * 16 + dcol];
                        m = fmaxf(m, rr);
                    }
                }
            mxc[nt] = m;
        }
#pragma unroll
        for (int nt = 0; nt < 4; ++nt) {
            mxc[nt] = fmaxf(mxc[nt], __shfl_xor(mxc[nt], 16));
            mxc[nt] = fmaxf(mxc[nt], __shfl_xor(mxc[nt], 32));
        }
        if (tid < 16) {
#pragma unroll
            for (int nt = 0; nt < 4; ++nt)
                tmax[(size_t)nv * E_ + nt * 16 + tid] = mxc[nt];
        }
    }
}

// ---------------------------------------------------------------------------
// Kernel 3: per n — max over V, then FC to 7 classes.
// ---------------------------------------------------------------------------
__global__ void k_pool_fc(const float* __restrict__ tmax,
                          const float* __restrict__ fc_w, const float* __restrict__ fc_b,
                          float* __restrict__ out) {
    int n = blockIdx.x;
    int tid = threadIdx.x;  // 64
    __shared__ float pooled[E_];
    float m = -1e30f;
    for (int v = 0; v < V_; ++v) m = fmaxf(m, tmax[((size_t)n * V_ + v) * E_ + tid]);
    pooled[tid] = m;
    __syncthreads();
    if (tid < NC_) {
        float s = fc_b[tid];
        for (int e = 0; e < E_; ++e) s += pooled[e] * fc_w[e * NC_ + tid];
        out[n * NC_ + tid] = s;
    }
}

extern "C" void kernel_launch(void* const* d_in, const int* in_sizes, int n_in,
                              void* d_out, int out_size, void* d_ws, size_t ws_size,
                              hipStream_t stream) {
    const float* xj        = (const float*)d_in[0];
    const float* xv        = (const float*)d_in[1];
    const float* je_w      = (const float*)d_in[2];
    const float* je_b      = (const float*)d_in[3];
    const float* ve_w      = (const float*)d_in[4];
    const float* ve_b      = (const float*)d_in[5];
    const float* joint_emb = (const float*)d_in[6];
    const float* frame_emb = (const float*)d_in[7];
    const float* proj_w    = (const float*)d_in[8];
    const float* proj_b    = (const float*)d_in[9];
    const float* gcn_w1    = (const float*)d_in[10];
    const float* gcn_b1    = (const float*)d_in[11];
    const float* gcn_w2    = (const float*)d_in[12];
    const float* gcn_b2    = (const float*)d_in[13];
    const float* sa_wq     = (const float*)d_in[14];
    const float* sa_bq     = (const float*)d_in[15];
    const float* sa_wk     = (const float*)d_in[16];
    const float* sa_bk     = (const float*)d_in[17];
    const float* sa_wv     = (const float*)d_in[18];
    const float* sa_bv     = (const float*)d_in[19];
    const float* sa_wo     = (const float*)d_in[20];
    const float* sa_bo     = (const float*)d_in[21];
    const float* ta_wq     = (const float*)d_in[22];
    const float* ta_bq     = (const float*)d_in[23];
    const float* ta_wk     = (const float*)d_in[24];
    const float* ta_bk     = (const float*)d_in[25];
    const float* ta_wv     = (const float*)d_in[26];
    const float* ta_bv     = (const float*)d_in[27];
    const float* ta_wo     = (const float*)d_in[28];
    const float* ta_bo     = (const float*)d_in[29];
    const float* fc_w      = (const float*)d_in[30];
    const float* fc_b      = (const float*)d_in[31];
    float* out = (float*)d_out;

    int N = in_sizes[0] / (C_ * T_ * V_);

    // ws layout (floats): tab[3200] | wt16 (10x4096 u16 = 20480 f) | tmax | feat1
    float* ws    = (float*)d_ws;
    float* tab   = ws;
    u16*   wt16  = (u16*)(ws + 3200);
    float* tmax  = ws + 3200 + 20480;
    float* feat1 = tmax + (size_t)N * V_ * E_;

    k_setup<<<11, 64, 0, stream>>>(je_w, je_b, ve_w, ve_b, joint_emb, frame_emb,
                                   proj_w, proj_b,
                                   ta_wq, ta_wk, ta_wv, ta_wo,
                                   gcn_w1, gcn_w2, sa_wq, sa_wk, sa_wv, sa_wo, tab);
    k_spatial<<<N * T_, 64, 0, stream>>>(xj, xv, tab, wt16,
                                         gcn_b1, gcn_b2,
                                         sa_bq, sa_bk, sa_bv, sa_bo, feat1);
    k_temporal<<<N * V_, 64, 0, stream>>>(feat1, wt16,
                                          ta_bq, ta_bk, ta_bv, ta_bo, tmax);
    k_pool_fc<<<N, 64, 0, stream>>>(tmax, fc_w, fc_b, out);
}

// Round 15
// 416.457 us; speedup vs baseline: 31.4389x; 1.1381x over previous
//
#include <hip/hip_runtime.h>
#include <math.h>

#define C_ 3
#define T_ 30
#define V_ 14
#define E_ 64
#define H_ 4
#define D_ 16
#define NC_ 7

#define SW_ 72   // u16 row stride of bf16 [*][72] staging tiles
#define SV_ 20   // u16 row stride of small frag tiles (2-way banks)

typedef unsigned short u16;
typedef __attribute__((ext_vector_type(8))) short bf16x8;   // 8 bf16 = 4 VGPR
typedef __attribute__((ext_vector_type(4))) short bf16x4;   // 4 bf16 = 2 VGPR
typedef __attribute__((ext_vector_type(4))) float f32x4;
typedef __attribute__((ext_vector_type(16))) float f32x16;

__device__ __forceinline__ float4 f4_load(const float* p) {
    return *reinterpret_cast<const float4*>(p);
}
__device__ __forceinline__ float4 f4_add(float4 a, float4 b) {
    return make_float4(a.x + b.x, a.y + b.y, a.z + b.z, a.w + b.w);
}
__device__ __forceinline__ float4 f4_fma(float a, float4 b, float4 c) {
    c.x = fmaf(a, b.x, c.x); c.y = fmaf(a, b.y, c.y);
    c.z = fmaf(a, b.z, c.z); c.w = fmaf(a, b.w, c.w); return c;
}
__device__ __forceinline__ u16 f2bf(float x) {   // RTNE f32 -> bf16
    unsigned u = __float_as_uint(x);
    return (u16)((u + 0x7FFFu + ((u >> 16) & 1u)) >> 16);
}
__device__ __forceinline__ uint2 pack4bf(float4 f) {
    return make_uint2((unsigned)f2bf(f.x) | ((unsigned)f2bf(f.y) << 16),
                      (unsigned)f2bf(f.z) | ((unsigned)f2bf(f.w) << 16));
}
__device__ __forceinline__ f32x16 f16z() {
    return (f32x16){0.f,0.f,0.f,0.f, 0.f,0.f,0.f,0.f, 0.f,0.f,0.f,0.f, 0.f,0.f,0.f,0.f};
}
// fragment load from 8B-aligned rows: two ds_read_b64
__device__ __forceinline__ bf16x8 ld_frag8(const u16* p) {
    bf16x4 lo = *(const bf16x4*)p;
    bf16x4 hi = *(const bf16x4*)(p + 4);
    return __builtin_shufflevector(lo, hi, 0, 1, 2, 3, 4, 5, 6, 7);
}

// ---------------------------------------------------------------------------
// Setup (11 blocks): block 0 = front-end tables; blocks 1..10 = one transposed
// bf16 weight matrix each. wt16[m][col][i] = bf16(W_m[i][col]);
// m: 0..3 = ta q/k/v/o, 4..9 = sa w1,w2,wq,wk,wv,wo.
// ---------------------------------------------------------------------------
__global__ void k_setup(const float* __restrict__ je_w, const float* __restrict__ je_b,
                        const float* __restrict__ ve_w, const float* __restrict__ ve_b,
                        const float* __restrict__ joint_emb, const float* __restrict__ frame_emb,
                        const float* __restrict__ proj_w, const float* __restrict__ proj_b,
                        const float* __restrict__ twq, const float* __restrict__ twk,
                        const float* __restrict__ twv, const float* __restrict__ two,
                        const float* __restrict__ sw1, const float* __restrict__ sw2,
                        const float* __restrict__ swq, const float* __restrict__ swk,
                        const float* __restrict__ swv, const float* __restrict__ swo,
                        float* __restrict__ tab) {
    int e = threadIdx.x;  // 64 threads
    int b = blockIdx.x;
    if (b > 0) {
        int m = b - 1;
        const float* Ws[10] = {twq, twk, twv, two, sw1, sw2, swq, swk, swv, swo};
        const float* W = Ws[m];
        u16* wt = (u16*)(tab + 3200);
        for (int i = 0; i < E_; ++i)
            wt[m * 4096 + e * 64 + i] = f2bf(W[i * E_ + e]);
        return;
    }
    for (int c = 0; c < C_; ++c) {
        float aj = 0.f, av = 0.f;
        for (int i = 0; i < E_; ++i) {
            float p0 = proj_w[i * E_ + e];
            aj += je_w[c * E_ + i] * p0;
            av += ve_w[c * E_ + i] * p0;
        }
        tab[c * E_ + e] = aj;
        tab[192 + c * E_ + e] = av;
    }
    for (int v = 0; v < V_; ++v) {
        float s = 0.f;
        for (int i = 0; i < E_; ++i) s += joint_emb[v * E_ + i] * proj_w[(64 + i) * E_ + e];
        tab[384 + v * E_ + e] = s;
    }
    float bias = proj_b[e];
    for (int i = 0; i < E_; ++i) bias += (je_b[i] + ve_b[i]) * proj_w[i * E_ + e];
    for (int t = 0; t < T_; ++t) {
        float s = bias;
        for (int i = 0; i < E_; ++i) s += frame_emb[t * E_ + i] * proj_w[(128 + i) * E_ + e];
        tab[1280 + t * E_ + e] = s;
    }
}

// ---------------------------------------------------------------------------
// Kernel 1: ONE WAVE per (n,t) tile, fully MFMA-ized (R14 arithmetic) with a
// single aliased LDS arena (12.9 KB -> 12 blocks/CU) and the GCN residual
// held in registers. Aliasing is strictly cross-phase (barriers between).
//   R0 @0    (1152): feat16 / g1out / ao16        ([16][72])
//   R1 @1152 (1280): fT16 [64][20] / qkvin [16][72]
//   R2 @2432 (1280): adjraw f32 / g1in [16][72] / qs16 2x640 / ps16 2x640
//   scb f32 (2016 u16) @0 spans R0+R1 (live ph7-ph8 only)
//   R3 @3712 (1280): adjs16 / ks16 2x640
//   R4 @4992 (1280): vsT16 2x640
//   xs  f32 @6272 (168) ; inv_nrm f32 @6440 (32)   total 6472 u16 = 12944 B
// ---------------------------------------------------------------------------
__global__ __launch_bounds__(64) void k_spatial(
    const float* __restrict__ xj, const float* __restrict__ xv,
    const float* __restrict__ tab, const u16* __restrict__ wt16,
    const float* __restrict__ b1, const float* __restrict__ b2,
    const float* __restrict__ bq, const float* __restrict__ bk,
    const float* __restrict__ bv, const float* __restrict__ bo,
    float* __restrict__ feat1) {
    int ntb = blockIdx.x;
    int n = ntb / T_;
    int t = ntb % T_;
    int tid = threadIdx.x;      // 0..63
    int dcol = tid & 15;
    int kgrp = tid >> 4;
    int trow4 = kgrp * 4;
    int e4 = dcol << 2;
    int r4 = kgrp;
    int l32 = tid & 31;
    int half = tid >> 5;

    const u16* w1T = wt16 + 4 * 4096;
    const u16* w2T = wt16 + 5 * 4096;
    const u16* wqT = wt16 + 6 * 4096;
    const u16* wkT = wt16 + 7 * 4096;
    const u16* wvT = wt16 + 8 * 4096;
    const u16* woT = wt16 + 9 * 4096;

    __shared__ __align__(16) u16 sm[6472];
    u16* feat16 = sm;                       // ph1-2
    u16* g1out  = sm;                       // ph4-5
    u16* ao16   = sm;                       // ph9-10
    u16* fT16   = sm + 1152;                // ph1-3
    u16* qkvin  = sm + 1152;                // ph5-6
    float* adjraw = (float*)(sm + 2432);    // ph2-softmax  [14][18]
    u16* g1in   = sm + 2432;                // ph3-4
    u16* qs16   = sm + 2432;                // ph6-7  2x640
    u16* ps16   = sm + 2432;                // ph8-9  2x640
    float* scb  = (float*)sm;               // ph7-8  [4][14][18] f32
    u16* adjs16 = sm + 3712;                // softmax-ph3  [32][20] (rows>=14 garbage)
    u16* ks16   = sm + 3712;                // ph6-7  2x640
    u16* vsT16  = sm + 4992;                // ph6,9  2x640
    float* xs      = (float*)(sm + 6272);   // [84]
    float* inv_nrm = (float*)(sm + 6440);   // [14]

    for (int o = tid; o < 2 * C_ * V_; o += 64) {
        int s = o / (C_ * V_);
        int rem = o % (C_ * V_);
        int c = rem / V_, v = rem % V_;
        const float* src = s ? xv : xj;
        xs[(s * C_ + c) * V_ + v] = src[((size_t)(n * C_ + c) * T_ + t) * V_ + v];
    }
    __syncthreads();

    // ph1: feat build -> feat16 (SW_ rows) + fT16 (SV_ rows, transposed)
    {
        float4 F = f4_load(tab + 1280 + t * E_ + e4);
        float4 AJ[C_], AV[C_];
#pragma unroll
        for (int c = 0; c < C_; ++c) {
            AJ[c] = f4_load(tab + c * E_ + e4);
            AV[c] = f4_load(tab + 192 + c * E_ + e4);
        }
#pragma unroll
        for (int j = 0; j < 4; ++j) {
            int q = r4 + 4 * j;
            if (q < V_) {
                float4 s = f4_add(F, f4_load(tab + 384 + q * E_ + e4));
#pragma unroll
                for (int c = 0; c < C_; ++c) {
                    s = f4_fma(xs[(0 * C_ + c) * V_ + q], AJ[c], s);
                    s = f4_fma(xs[(1 * C_ + c) * V_ + q], AV[c], s);
                }
                *(uint2*)&feat16[q * SW_ + e4] = pack4bf(s);
                fT16[(e4 + 0) * SV_ + q] = f2bf(s.x);
                fT16[(e4 + 1) * SV_ + q] = f2bf(s.y);
                fT16[(e4 + 2) * SV_ + q] = f2bf(s.z);
                fT16[(e4 + 3) * SV_ + q] = f2bf(s.w);
            }
        }
        fT16[tid * SV_ + 14] = 0;
        fT16[tid * SV_ + 15] = 0;
    }
    __syncthreads();

    // ph2: adjacency raw dots via MFMA (X@X^T)
    {
        bf16x8 f0 = *(bf16x8*)&feat16[dcol * SW_ + kgrp * 8];
        bf16x8 f1 = *(bf16x8*)&feat16[dcol * SW_ + 32 + kgrp * 8];
        f32x4 d = (f32x4){0.f, 0.f, 0.f, 0.f};
        d = __builtin_amdgcn_mfma_f32_16x16x32_bf16(f0, f0, d, 0, 0, 0);
        d = __builtin_amdgcn_mfma_f32_16x16x32_bf16(f1, f1, d, 0, 0, 0);
#pragma unroll
        for (int r = 0; r < 4; ++r) {
            int row = trow4 + r;
            if (row < V_) adjraw[row * 18 + dcol] = d[r];
        }
    }
    __syncthreads();
    if (tid < V_) inv_nrm[tid] = 1.0f / fmaxf(sqrtf(adjraw[tid * 18 + tid]), 1e-12f);
    __syncthreads();
    if (tid < V_) {
        float c[V_];
        float iq = inv_nrm[tid];
        float m = -1e30f;
#pragma unroll
        for (int k = 0; k < V_; ++k) {
            c[k] = adjraw[tid * 18 + k] * iq * inv_nrm[k];
            m = fmaxf(m, c[k]);
        }
        float su = 0.f;
#pragma unroll
        for (int k = 0; k < V_; ++k) { c[k] = __expf(c[k] - m); su += c[k]; }
        float iv = 1.f / su;
#pragma unroll
        for (int k = 0; k < V_; ++k) adjs16[tid * SV_ + k] = f2bf(c[k] * iv);
        adjs16[tid * SV_ + 14] = 0;
        adjs16[tid * SV_ + 15] = 0;
    }
    __syncthreads();

    // ph3: gcn1 = adj @ feat via 2x 32x32x16 -> g1in
    {
        bf16x8 aA = ld_frag8(&adjs16[l32 * SV_ + half * 8]);
#pragma unroll
        for (int nt = 0; nt < 2; ++nt) {
            bf16x8 bB = ld_frag8(&fT16[(nt * 32 + l32) * SV_ + half * 8]);
            f32x16 g = f16z();
            g = __builtin_amdgcn_mfma_f32_32x32x16_bf16(aA, bB, g, 0, 0, 0);
#pragma unroll
            for (int reg = 0; reg < 16; ++reg) {
                int row = (reg & 3) + 8 * (reg >> 2) + 4 * half;
                if (row < V_) g1in[row * SW_ + nt * 32 + l32] = f2bf(g[reg]);
            }
        }
    }
    __syncthreads();

    // ph4: W1 + relu -> g1out
    {
        bf16x8 a0 = *(bf16x8*)&g1in[dcol * SW_ + kgrp * 8];
        bf16x8 a1 = *(bf16x8*)&g1in[dcol * SW_ + 32 + kgrp * 8];
#pragma unroll
        for (int nt = 0; nt < 4; ++nt) {
            int col = nt * 16 + dcol;
            float bb = b1[col];
            f32x4 cc = (f32x4){bb, bb, bb, bb};
            cc = __builtin_amdgcn_mfma_f32_16x16x32_bf16(a0, *(const bf16x8*)&w1T[col * 64 + kgrp * 8], cc, 0, 0, 0);
            cc = __builtin_amdgcn_mfma_f32_16x16x32_bf16(a1, *(const bf16x8*)&w1T[col * 64 + 32 + kgrp * 8], cc, 0, 0, 0);
#pragma unroll
            for (int r = 0; r < 4; ++r) {
                int row = trow4 + r;
                if (row < V_) g1out[row * SW_ + col] = f2bf(fmaxf(cc[r], 0.f));
            }
        }
    }
    __syncthreads();

    // ph5: W2 -> fresr (REGISTERS, f32 residual) + qkvin bf16
    f32x4 fresr[4];
    {
        bf16x8 a0 = *(bf16x8*)&g1out[dcol * SW_ + kgrp * 8];
        bf16x8 a1 = *(bf16x8*)&g1out[dcol * SW_ + 32 + kgrp * 8];
#pragma unroll
        for (int nt = 0; nt < 4; ++nt) {
            int col = nt * 16 + dcol;
            float bb = b2[col];
            f32x4 cc = (f32x4){bb, bb, bb, bb};
            cc = __builtin_amdgcn_mfma_f32_16x16x32_bf16(a0, *(const bf16x8*)&w2T[col * 64 + kgrp * 8], cc, 0, 0, 0);
            cc = __builtin_amdgcn_mfma_f32_16x16x32_bf16(a1, *(const bf16x8*)&w2T[col * 64 + 32 + kgrp * 8], cc, 0, 0, 0);
            fresr[nt] = cc;
#pragma unroll
            for (int r = 0; r < 4; ++r) {
                int row = trow4 + r;
                if (row < V_) qkvin[row * SW_ + col] = f2bf(cc[r]);
            }
        }
    }
    __syncthreads();

    // ph6: Q/K/V -> qs16/ks16/vsT16 per head-pair (SV_ rows)
    {
        bf16x8 a0 = *(bf16x8*)&qkvin[dcol * SW_ + kgrp * 8];
        bf16x8 a1 = *(bf16x8*)&qkvin[dcol * SW_ + 32 + kgrp * 8];
#pragma unroll
        for (int nt = 0; nt < 4; ++nt) {
            int col = nt * 16 + dcol;
            float bqs = bq[col], bks = bk[col], bvs = bv[col];
            f32x4 cq = (f32x4){bqs, bqs, bqs, bqs};
            f32x4 ck = (f32x4){bks, bks, bks, bks};
            f32x4 cv = (f32x4){bvs, bvs, bvs, bvs};
            cq = __builtin_amdgcn_mfma_f32_16x16x32_bf16(a0, *(const bf16x8*)&wqT[col * 64 + kgrp * 8], cq, 0, 0, 0);
            cq = __builtin_amdgcn_mfma_f32_16x16x32_bf16(a1, *(const bf16x8*)&wqT[col * 64 + 32 + kgrp * 8], cq, 0, 0, 0);
            ck = __builtin_amdgcn_mfma_f32_16x16x32_bf16(a0, *(const bf16x8*)&wkT[col * 64 + kgrp * 8], ck, 0, 0, 0);
            ck = __builtin_amdgcn_mfma_f32_16x16x32_bf16(a1, *(const bf16x8*)&wkT[col * 64 + 32 + kgrp * 8], ck, 0, 0, 0);
            cv = __builtin_amdgcn_mfma_f32_16x16x32_bf16(a0, *(const bf16x8*)&wvT[col * 64 + kgrp * 8], cv, 0, 0, 0);
            cv = __builtin_amdgcn_mfma_f32_16x16x32_bf16(a1, *(const bf16x8*)&wvT[col * 64 + 32 + kgrp * 8], cv, 0, 0, 0);
            int pair = nt >> 1, hw = nt & 1;
            u16* qsb = qs16 + pair * 640;
            u16* ksb = ks16 + pair * 640;
            u16* vtb = vsT16 + pair * 640;
#pragma unroll
            for (int r = 0; r < 4; ++r) {
                int row = trow4 + r;
                qsb[(hw * 16 + row) * SV_ + dcol] = f2bf(cq[r]);
                ksb[(hw * 16 + row) * SV_ + dcol] = f2bf(ck[r]);
                vtb[(hw * 16 + dcol) * SV_ + row] = (row < V_) ? f2bf(cv[r]) : (u16)0;
            }
        }
    }
    __syncthreads();

    // ph7: scores 2-heads-per-MFMA -> scb f32 (aliases R0+R1, now dead)
    {
#pragma unroll
        for (int pair = 0; pair < 2; ++pair) {
            bf16x8 aq = ld_frag8(&qs16[pair * 640 + l32 * SV_ + half * 8]);
            bf16x8 bk8 = ld_frag8(&ks16[pair * 640 + l32 * SV_ + half * 8]);
            f32x16 d = f16z();
            d = __builtin_amdgcn_mfma_f32_32x32x16_bf16(aq, bk8, d, 0, 0, 0);
            int kp = l32 & 15, hp = l32 >> 4;
            if (kp < V_) {
#pragma unroll
                for (int reg = 0; reg < 16; ++reg) {
                    int row = (reg & 3) + 8 * (reg >> 2) + 4 * half;
                    if ((row >> 4) == hp && (row & 15) < V_)
                        scb[(pair * 2 + hp) * 252 + (row & 15) * 18 + kp] = d[reg];
                }
            }
        }
    }
    __syncthreads();

    // ph8: attention softmax -> ps16 (aliases qs16, dead)
    if (tid < H_ * V_) {
        int h = tid / V_, q = tid % V_;
        float p[V_];
        float m = -1e30f;
#pragma unroll
        for (int k = 0; k < V_; ++k) { p[k] = scb[h * 252 + q * 18 + k]; m = fmaxf(m, p[k]); }
        float su = 0.f;
#pragma unroll
        for (int k = 0; k < V_; ++k) { p[k] = __expf((p[k] - m) * 0.25f); su += p[k]; }
        float iv = 1.f / su;
        u16* psb = ps16 + (h >> 1) * 640;
        int rowp = (h & 1) * 16 + q;
#pragma unroll
        for (int k = 0; k < V_; ++k) psb[rowp * SV_ + k] = f2bf(p[k] * iv);
        psb[rowp * SV_ + 14] = 0;
        psb[rowp * SV_ + 15] = 0;
    }
    __syncthreads();

    // ph9: PV 2-heads-per-MFMA -> ao16 (aliases scb head, dead)
    {
#pragma unroll
        for (int pair = 0; pair < 2; ++pair) {
            bf16x8 ap = ld_frag8(&ps16[pair * 640 + l32 * SV_ + half * 8]);
            bf16x8 bv8 = ld_frag8(&vsT16[pair * 640 + l32 * SV_ + half * 8]);
            f32x16 d = f16z();
            d = __builtin_amdgcn_mfma_f32_32x32x16_bf16(ap, bv8, d, 0, 0, 0);
            int np = l32 & 15, hp = l32 >> 4;
#pragma unroll
            for (int reg = 0; reg < 16; ++reg) {
                int row = (reg & 3) + 8 * (reg >> 2) + 4 * half;
                if ((row >> 4) == hp && (row & 15) < V_)
                    ao16[(row & 15) * SW_ + (pair * 2 + hp) * 16 + np] = f2bf(d[reg]);
            }
        }
    }
    __syncthreads();

    // ph10: O + residual (from registers) -> feat1
    {
        bf16x8 a0 = *(bf16x8*)&ao16[dcol * SW_ + kgrp * 8];
        bf16x8 a1 = *(bf16x8*)&ao16[dcol * SW_ + 32 + kgrp * 8];
        float* dst = feat1 + (size_t)ntb * (V_ * E_);
#pragma unroll
        for (int nt = 0; nt < 4; ++nt) {
            int col = nt * 16 + dcol;
            float bos = bo[col];
            f32x4 cc = (f32x4){bos, bos, bos, bos};
            cc = __builtin_amdgcn_mfma_f32_16x16x32_bf16(a0, *(const bf16x8*)&woT[col * 64 + kgrp * 8], cc, 0, 0, 0);
            cc = __builtin_amdgcn_mfma_f32_16x16x32_bf16(a1, *(const bf16x8*)&woT[col * 64 + 32 + kgrp * 8], cc, 0, 0, 0);
#pragma unroll
            for (int r = 0; r < 4; ++r) {
                int row = trow4 + r;
                if (row < V_) dst[row * E_ + col] = cc[r] + fresr[nt][r];
            }
        }
    }
}

// ---------------------------------------------------------------------------
// Kernel 2: ONE WAVE per (n,v) tile (R14 arithmetic) with aliased arena:
// scb f32 overlays ft16 (dead after persistent A-frag load). 15.2 KB LDS.
//   T0 @0    (2304): ft16 [32][72] -> scb f32 [30][36]
//   T1 @2304 (2304): ao16 [32][72]
//   T2 @4608 (640):  qs16 [32][20]   T3 @5248 (640): ks16 [32][20]
//   T4 @5888 (576):  vT16 [16][36]   T5 @6464 (1152): ps16 [32][36]
// ---------------------------------------------------------------------------
__global__ __launch_bounds__(64) void k_temporal(
    const float* __restrict__ feat1,
    const u16* __restrict__ wt16,
    const float* __restrict__ bq, const float* __restrict__ bk,
    const float* __restrict__ bv, const float* __restrict__ bo,
    float* __restrict__ tmax) {
    int nv = blockIdx.x;
    int n = nv / V_;
    int v = nv % V_;
    int tid = threadIdx.x;      // 0..63
    int dcol = tid & 15;
    int kgrp = tid >> 4;
    int trow4 = kgrp * 4;
    int l32 = tid & 31;
    int half = tid >> 5;

    const u16* wtq = wt16;
    const u16* wtk = wt16 + 4096;
    const u16* wtv = wt16 + 8192;
    const u16* wto = wt16 + 12288;

    __shared__ __align__(16) u16 smt[7616];
    u16*  ft16 = smt;                  // ph1 only (A-frags cached in regs)
    float* scb = (float*)smt;          // [30][36] f32, per-head P2-P3
    u16*  ao16 = smt + 2304;           // [32][72]
    u16*  qs16 = smt + 4608;           // [32][20]
    u16*  ks16 = smt + 5248;           // [32][20]
    u16*  vT16 = smt + 5888;           // [16][36]
    u16*  ps16 = smt + 6464;           // [32][36]

    const float* fsrc = feat1 + ((size_t)n * T_ * V_ + v) * E_;

    // ph1: bf16 copy of tile
    for (int o = tid; o < T_ * 16; o += 64) {
        int t = o >> 4, c4i = (o & 15) << 2;
        float4 f = f4_load(fsrc + (size_t)t * V_ * E_ + c4i);
        *(uint2*)&ft16[t * 72 + c4i] = pack4bf(f);
    }
    __syncthreads();

    // persistent A-frags of ft (ft16 dead afterward; scb may overlay)
    bf16x8 af[2][2];
#pragma unroll
    for (int mt = 0; mt < 2; ++mt)
#pragma unroll
        for (int ks = 0; ks < 2; ++ks)
            af[mt][ks] = *(bf16x8*)&ft16[(mt * 16 + dcol) * 72 + ks * 32 + kgrp * 8];

    bool sact = (tid < 2 * T_);
    int sq = sact ? (tid >> 1) : 0;
    int kbase = (tid & 1) * 15;

    for (int h = 0; h < H_; ++h) {
        // P1: Q,K projections (MFMA) -> qs16, ks16
        {
            float bqs = bq[h * D_ + dcol];
            float bks = bk[h * D_ + dcol];
            f32x4 qacc[2], kacc[2];
#pragma unroll
            for (int mt = 0; mt < 2; ++mt) {
                qacc[mt] = (f32x4){bqs, bqs, bqs, bqs};
                kacc[mt] = (f32x4){bks, bks, bks, bks};
            }
#pragma unroll
            for (int ks = 0; ks < 2; ++ks) {
                int boff = (h * D_ + dcol) * 64 + ks * 32 + kgrp * 8;
                bf16x8 b_q = *(const bf16x8*)&wtq[boff];
                bf16x8 b_k = *(const bf16x8*)&wtk[boff];
#pragma unroll
                for (int mt = 0; mt < 2; ++mt) {
                    qacc[mt] = __builtin_amdgcn_mfma_f32_16x16x32_bf16(af[mt][ks], b_q, qacc[mt], 0, 0, 0);
                    kacc[mt] = __builtin_amdgcn_mfma_f32_16x16x32_bf16(af[mt][ks], b_k, kacc[mt], 0, 0, 0);
                }
            }
#pragma unroll
            for (int mt = 0; mt < 2; ++mt)
#pragma unroll
                for (int r = 0; r < 4; ++r) {
                    int t = mt * 16 + trow4 + r;   // 0..31
                    qs16[t * SV_ + dcol] = f2bf(qacc[mt][r]);
                    ks16[t * SV_ + dcol] = f2bf(kacc[mt][r]);
                }
        }
        __syncthreads();

        // P2: scores = one 32x32x16 MFMA -> scb f32 (overlays dead ft16)
        {
            bf16x8 aq = ld_frag8(&qs16[l32 * SV_ + half * 8]);
            bf16x8 bk8 = ld_frag8(&ks16[l32 * SV_ + half * 8]);
            f32x16 d = f16z();
            d = __builtin_amdgcn_mfma_f32_32x32x16_bf16(aq, bk8, d, 0, 0, 0);
            if (l32 < T_) {
#pragma unroll
                for (int reg = 0; reg < 16; ++reg) {
                    int row = (reg & 3) + 8 * (reg >> 2) + 4 * half;
                    if (row < T_) scb[row * 36 + l32] = d[reg];
                }
            }
        }
        __syncthreads();

        // P3: softmax (f32, 2 lanes/row) -> ps16 ; V projection -> vT16
        {
            float m = -1e30f;
#pragma unroll
            for (int k = 0; k < 15; ++k) m = fmaxf(m, scb[sq * 36 + kbase + k]);
            m = fmaxf(m, __shfl_xor(m, 1));
            float ex[15];
            float su = 0.f;
#pragma unroll
            for (int k = 0; k < 15; ++k) {
                ex[k] = __expf((scb[sq * 36 + kbase + k] - m) * 0.25f);
                su += ex[k];
            }
            su += __shfl_xor(su, 1);
            float iv = 1.f / su;
            if (sact) {
#pragma unroll
                for (int k = 0; k < 15; ++k) ps16[sq * 36 + kbase + k] = f2bf(ex[k] * iv);
                if (kbase) { ps16[sq * 36 + 30] = 0; ps16[sq * 36 + 31] = 0; }
            }
        }
        {
            float bvs = bv[h * D_ + dcol];
            f32x4 vacc[2];
            vacc[0] = (f32x4){bvs, bvs, bvs, bvs};
            vacc[1] = vacc[0];
#pragma unroll
            for (int ks = 0; ks < 2; ++ks) {
                int boff = (h * D_ + dcol) * 64 + ks * 32 + kgrp * 8;
                bf16x8 b_v = *(const bf16x8*)&wtv[boff];
#pragma unroll
                for (int mt = 0; mt < 2; ++mt)
                    vacc[mt] = __builtin_amdgcn_mfma_f32_16x16x32_bf16(af[mt][ks], b_v, vacc[mt], 0, 0, 0);
            }
#pragma unroll
            for (int mt = 0; mt < 2; ++mt)
#pragma unroll
                for (int r = 0; r < 4; ++r) {
                    int t = mt * 16 + trow4 + r;
                    vT16[dcol * 36 + t] = (t < T_) ? f2bf(vacc[mt][r]) : (u16)0;
                }
        }
        __syncthreads();

        // P4: PV = two 32x32x16 MFMAs -> ao16 (no trailing barrier)
        {
            bf16x8 ap0 = ld_frag8(&ps16[l32 * 36 + half * 8]);
            bf16x8 ap1 = ld_frag8(&ps16[l32 * 36 + 16 + half * 8]);
            bf16x8 bv0 = ld_frag8(&vT16[(l32 & 15) * 36 + half * 8]);
            bf16x8 bv1 = ld_frag8(&vT16[(l32 & 15) * 36 + 16 + half * 8]);
            f32x16 d = f16z();
            d = __builtin_amdgcn_mfma_f32_32x32x16_bf16(ap0, bv0, d, 0, 0, 0);
            d = __builtin_amdgcn_mfma_f32_32x32x16_bf16(ap1, bv1, d, 0, 0, 0);
            if (l32 < 16) {
#pragma unroll
                for (int reg = 0; reg < 16; ++reg) {
                    int row = (reg & 3) + 8 * (reg >> 2) + 4 * half;
                    if (row < T_) ao16[row * 72 + h * D_ + l32] = f2bf(d[reg]);
                }
            }
        }
    }
    __syncthreads();

    // O projection + residual + T-max
    {
        bf16x8 oa[2][2];
#pragma unroll
        for (int mt = 0; mt < 2; ++mt)
#pragma unroll
            for (int ks = 0; ks < 2; ++ks)
                oa[mt][ks] = *(bf16x8*)&ao16[(mt * 16 + dcol) * 72 + ks * 32 + kgrp * 8];

        float mxc[4];
#pragma unroll
        for (int nt = 0; nt < 4; ++nt) {
            float bos = bo[nt * 16 + dcol];
            f32x4 oacc[2];
            oacc[0] = (f32x4){bos, bos, bos, bos};
            oacc[1] = oacc[0];
#pragma unroll
            for (int ks = 0; ks < 2; ++ks) {
                bf16x8 bb = *(const bf16x8*)&wto[(nt * 16 + dcol) * 64 + ks * 32 + kgrp * 8];
#pragma unroll
                for (int mt = 0; mt < 2; ++mt)
                    oacc[mt] = __builtin_amdgcn_mfma_f32_16x16x32_bf16(oa[mt][ks], bb, oacc[mt], 0, 0, 0);
            }
            float m = -1e30f;
#pragma unroll
            for (int mt = 0; mt < 2; ++mt)
#pragma unroll
                for (int r = 0; r < 4; ++r) {
                    int t = mt * 16 + trow4 + r;
                    if (t < T_) {
                        float rr = oacc[mt][r] +
                                   fsrc[(size_t)t * V_ * E_ + nt * 16 + dcol];
                        m = fmaxf(m, rr);
                    }
                }
            mxc[nt] = m;
        }
#pragma unroll
        for (int nt = 0; nt < 4; ++nt) {
            mxc[nt] = fmaxf(mxc[nt], __shfl_xor(mxc[nt], 16));
            mxc[nt] = fmaxf(mxc[nt], __shfl_xor(mxc[nt], 32));
        }
        if (tid < 16) {
#pragma unroll
            for (int nt = 0; nt < 4; ++nt)
                tmax[(size_t)nv * E_ + nt * 16 + tid] = mxc[nt];
        }
    }
}

// ---------------------------------------------------------------------------
// Kernel 3: per n — max over V, then FC to 7 classes.
// ---------------------------------------------------------------------------
__global__ void k_pool_fc(const float* __restrict__ tmax,
                          const float* __restrict__ fc_w, const float* __restrict__ fc_b,
                          float* __restrict__ out) {
    int n = blockIdx.x;
    int tid = threadIdx.x;  // 64
    __shared__ float pooled[E_];
    float m = -1e30f;
    for (int v = 0; v < V_; ++v) m = fmaxf(m, tmax[((size_t)n * V_ + v) * E_ + tid]);
    pooled[tid] = m;
    __syncthreads();
    if (tid < NC_) {
        float s = fc_b[tid];
        for (int e = 0; e < E_; ++e) s += pooled[e] * fc_w[e * NC_ + tid];
        out[n * NC_ + tid] = s;
    }
}

extern "C" void kernel_launch(void* const* d_in, const int* in_sizes, int n_in,
                              void* d_out, int out_size, void* d_ws, size_t ws_size,
                              hipStream_t stream) {
    const float* xj        = (const float*)d_in[0];
    const float* xv        = (const float*)d_in[1];
    const float* je_w      = (const float*)d_in[2];
    const float* je_b      = (const float*)d_in[3];
    const float* ve_w      = (const float*)d_in[4];
    const float* ve_b      = (const float*)d_in[5];
    const float* joint_emb = (const float*)d_in[6];
    const float* frame_emb = (const float*)d_in[7];
    const float* proj_w    = (const float*)d_in[8];
    const float* proj_b    = (const float*)d_in[9];
    const float* gcn_w1    = (const float*)d_in[10];
    const float* gcn_b1    = (const float*)d_in[11];
    const float* gcn_w2    = (const float*)d_in[12];
    const float* gcn_b2    = (const float*)d_in[13];
    const float* sa_wq     = (const float*)d_in[14];
    const float* sa_bq     = (const float*)d_in[15];
    const float* sa_wk     = (const float*)d_in[16];
    const float* sa_bk     = (const float*)d_in[17];
    const float* sa_wv     = (const float*)d_in[18];
    const float* sa_bv     = (const float*)d_in[19];
    const float* sa_wo     = (const float*)d_in[20];
    const float* sa_bo     = (const float*)d_in[21];
    const float* ta_wq     = (const float*)d_in[22];
    const float* ta_bq     = (const float*)d_in[23];
    const float* ta_wk     = (const float*)d_in[24];
    const float* ta_bk     = (const float*)d_in[25];
    const float* ta_wv     = (const float*)d_in[26];
    const float* ta_bv     = (const float*)d_in[27];
    const float* ta_wo     = (const float*)d_in[28];
    const float* ta_bo     = (const float*)d_in[29];
    const float* fc_w      = (const float*)d_in[30];
    const float* fc_b      = (const float*)d_in[31];
    float* out = (float*)d_out;

    int N = in_sizes[0] / (C_ * T_ * V_);

    // ws layout (floats): tab[3200] | wt16 (10x4096 u16 = 20480 f) | tmax | feat1
    float* ws    = (float*)d_ws;
    float* tab   = ws;
    u16*   wt16  = (u16*)(ws + 3200);
    float* tmax  = ws + 3200 + 20480;
    float* feat1 = tmax + (size_t)N * V_ * E_;

    k_setup<<<11, 64, 0, stream>>>(je_w, je_b, ve_w, ve_b, joint_emb, frame_emb,
                                   proj_w, proj_b,
                                   ta_wq, ta_wk, ta_wv, ta_wo,
                                   gcn_w1, gcn_w2, sa_wq, sa_wk, sa_wv, sa_wo, tab);
    k_spatial<<<N * T_, 64, 0, stream>>>(xj, xv, tab, wt16,
                                         gcn_b1, gcn_b2,
                                         sa_bq, sa_bk, sa_bv, sa_bo, feat1);
    k_temporal<<<N * V_, 64, 0, stream>>>(feat1, wt16,
                                          ta_bq, ta_bk, ta_bv, ta_bo, tmax);
    k_pool_fc<<<N, 64, 0, stream>>>(tmax, fc_w, fc_b, out);
}